// Round 15
// baseline (503.752 us; speedup 1.0000x reference)
//
#include <hip/hip_runtime.h>
#include <hip/hip_bf16.h>
#include <cfloat>

static constexpr int NBAT = 16;
static constexpr int NPT  = 2048;
static constexpr int NSEG = 4;     // pass2 n-split segments

typedef _Float16 f16;
typedef _Float16 f16x8 __attribute__((ext_vector_type(8)));
typedef float    f32x4 __attribute__((ext_vector_type(4)));

static __device__ __forceinline__ f32x4 mfma16(f16x8 a, f16x8 b, f32x4 c){
  return __builtin_amdgcn_mfma_f32_16x16x32_f16(a, b, c, 0, 0, 0);
}
// MFMA 16x16x32 f16 layouts (gfx950, e2e-verified by round-4 pass):
//  A[16r x 32k]: lane l -> row l&15, k = (l>>4)*8 + j (16B contiguous)
//  B[32k x 16c]: lane l -> col l&15, k = (l>>4)*8 + j (16B contiguous)
//  D[16r x 16c]: lane l -> col l&15, rows (l>>4)*4 + i

// ---- weight arena offsets (halfs) ----
static constexpr long OFF_M1W1 = 0;              // [128][128]
static constexpr long OFF_M2W0A= 16384;          // [128][128] (cols 0..127 of [128][256])
static constexpr long OFF_M2W1 = 32768;          // [128][128]
static constexpr long OFF_M3W0 = 49152;          // [512][384]
static constexpr long OFF_M3W1 = 245760;         // [1024][512]
static constexpr long OFF_SA   = 770048;         // per-L: wq[32][128], wv[128][128], wt[128][128]
static constexpr long SA_STRIDE= 36864;
static constexpr long WTOT     = OFF_SA + 3*SA_STRIDE;   // 880,640 halfs

// ---------------------------------------------------------------------------
// weight fp32 -> fp16 conversion into arena (one launch)
// ---------------------------------------------------------------------------
__global__ __launch_bounds__(256) void k_wconv(
    const float* m1w1, const float* m2w0, const float* m2w1,
    const float* m3w0, const float* m3w1,
    const float* wq0, const float* wv0, const float* wt0,
    const float* wq1, const float* wv1, const float* wt1,
    const float* wq2, const float* wv2, const float* wt2,
    f16* W)
{
  long t = (long)blockIdx.x*256 + threadIdx.x;
  if (t >= WTOT) return;
  float v;
  if      (t < OFF_M2W0A) v = m1w1[t];
  else if (t < OFF_M2W1) { long u = t-OFF_M2W0A; v = m2w0[(u>>7)*256 + (u&127)]; }
  else if (t < OFF_M3W0)  v = m2w1[t-OFF_M2W1];
  else if (t < OFF_M3W1)  v = m3w0[t-OFF_M3W0];
  else if (t < OFF_SA)    v = m3w1[t-OFF_M3W1];
  else {
    long u = t - OFF_SA; int L = (int)(u / SA_STRIDE); long r = u % SA_STRIDE;
    const float* wq = (L==0)?wq0:(L==1)?wq1:wq2;
    const float* wv = (L==0)?wv0:(L==1)?wv1:wv2;
    const float* wt = (L==0)?wt0:(L==1)?wt1:wt2;
    if (r < 4096) v = wq[r]; else if (r < 20480) v = wv[r-4096]; else v = wt[r-20480];
  }
  W[t] = (f16)v;
}

// ---------------------------------------------------------------------------
// mlp1 layer0 (K=3): h1T[b][n][o] = relu(b0[o] + sum_c w0[o][c]*in[b][n][c])
// ---------------------------------------------------------------------------
__global__ __launch_bounds__(256) void k_mlp1aT(const float* __restrict__ in,
                                                const float* __restrict__ w0,
                                                const float* __restrict__ b0,
                                                f16* __restrict__ h1T)
{
  long idx = (long)blockIdx.x*256 + threadIdx.x;
  int og = idx & 31; long bn = idx >> 5;
  const float* ip = in + bn*3;
  float x0=ip[0], x1=ip[1], x2=ip[2];
  f16* op = h1T + bn*128 + og*4;
  #pragma unroll
  for (int i=0;i<4;++i){
    int o = og*4+i;
    float v = b0[o] + w0[o*3]*x0 + w0[o*3+1]*x1 + w0[o*3+2]*x2;
    op[i] = (f16)fmaxf(v, 0.f);
  }
}

// ---------------------------------------------------------------------------
// generic transposed conv GEMM: OUTT[b][n][ocol+o] = act(bias + sum_k XT[b][n][k]*W[o][k])
// ---------------------------------------------------------------------------
template<int OT, bool RELU, bool B2D>
__global__ __launch_bounds__(256) void gemmT(
    const f16* __restrict__ W, const float* __restrict__ bias,
    const float* __restrict__ bias2d,
    const f16* __restrict__ XT, int xrs,
    f16* __restrict__ OUT, int ors, int ocol, int K)
{
  __shared__ __align__(16) f16 Xs[64][72];
  __shared__ __align__(16) f16 Wsh[OT][72];
  const int b  = blockIdx.z;
  const int n0 = blockIdx.x * 64;
  const int o0 = blockIdx.y * OT;
  const int tid = threadIdx.x, lane = tid & 63, w = tid >> 6;
  const int lr = lane & 15, lg = lane >> 4;
  constexpr int NSUB = (OT==64)?2:1;
  const int wn = (OT==64)? (w>>1) : w;
  const int wo = (OT==64)? (w&1) : 0;
  const int nbase = wn*(16*NSUB);
  const f16* Xb = XT + (long)b*NPT*xrs;
  f32x4 acc[NSUB][2];
  #pragma unroll
  for (int ni=0;ni<NSUB;++ni){ acc[ni][0]=(f32x4){0,0,0,0}; acc[ni][1]=(f32x4){0,0,0,0}; }

  for (int k0=0; k0<K; k0+=64){
    #pragma unroll
    for (int g = tid; g < 512; g += 256){
      int r = g>>3, s = g&7;
      *(float4*)&Xs[r][s*8] = *(const float4*)(Xb + (long)(n0+r)*xrs + k0 + s*8);
    }
    for (int g = tid; g < OT*8; g += 256){
      int r = g>>3, s = g&7;
      *(float4*)&Wsh[r][s*8] = *(const float4*)(W + (long)(o0+r)*K + k0 + s*8);
    }
    __syncthreads();
    #pragma unroll
    for (int ks=0; ks<2; ++ks){
      f16x8 a[NSUB], bf[2];
      #pragma unroll
      for (int ni=0;ni<NSUB;++ni) a[ni] = *(const f16x8*)&Xs[nbase + ni*16 + lr][ks*32 + lg*8];
      #pragma unroll
      for (int oi=0;oi<2;++oi)   bf[oi] = *(const f16x8*)&Wsh[wo*32 + oi*16 + lr][ks*32 + lg*8];
      #pragma unroll
      for (int ni=0;ni<NSUB;++ni)
        #pragma unroll
        for (int oi=0;oi<2;++oi) acc[ni][oi] = mfma16(a[ni], bf[oi], acc[ni][oi]);
    }
    __syncthreads();
  }
  #pragma unroll
  for (int ni=0;ni<NSUB;++ni)
    #pragma unroll
    for (int oi=0;oi<2;++oi){
      const int oc = o0 + wo*32 + oi*16 + lr;
      float bi = bias ? bias[oc] : 0.f;
      if constexpr (B2D) bi += bias2d[b*128 + oc];
      #pragma unroll
      for (int i=0;i<4;++i){
        const int nn = n0 + nbase + ni*16 + lg*4 + i;
        float v = acc[ni][oi][i] + bi;
        if constexpr (RELU) v = fmaxf(v, 0.f);
        OUT[(long)b*NPT*ors + (long)nn*ors + ocol + oc] = (f16)v;
      }
    }
}

// ---------------------------------------------------------------------------
// 128x128-tile GEMM (4 waves as 2x2, each wave 64x64, acc[4][4]):
// __launch_bounds__(256,4): cap regs at 128/thread -> 4 blocks/CU.
// ---------------------------------------------------------------------------
template<bool RELU>
__global__ __launch_bounds__(256, 4) void gemm128(
    const f16* __restrict__ W, const float* __restrict__ bias,
    const f16* __restrict__ XT, int xrs,
    f16* __restrict__ OUT, int ors, int K)
{
  __shared__ __align__(16) f16 Xs[128][72];
  __shared__ __align__(16) f16 Wsh[128][72];
  const int b  = blockIdx.z;
  const int n0 = blockIdx.x * 128;
  const int o0 = blockIdx.y * 128;
  const int tid = threadIdx.x, lane = tid & 63, w = tid >> 6;
  const int lr = lane & 15, lg = lane >> 4;
  const int wn = w >> 1, wo = w & 1;
  const f16* Xb = XT + (long)b*NPT*xrs;
  f32x4 acc[4][4];
  #pragma unroll
  for (int ni=0;ni<4;++ni)
    #pragma unroll
    for (int oi=0;oi<4;++oi) acc[ni][oi] = (f32x4){0,0,0,0};

  for (int k0=0; k0<K; k0+=64){
    #pragma unroll
    for (int g = tid; g < 1024; g += 256){
      int r = g>>3, s = g&7;
      *(float4*)&Xs[r][s*8]  = *(const float4*)(Xb + (long)(n0+r)*xrs + k0 + s*8);
      *(float4*)&Wsh[r][s*8] = *(const float4*)(W + (long)(o0+r)*K + k0 + s*8);
    }
    __syncthreads();
    #pragma unroll
    for (int ks=0; ks<2; ++ks){
      f16x8 a[4], bf[4];
      #pragma unroll
      for (int ni=0;ni<4;++ni) a[ni]  = *(const f16x8*)&Xs[wn*64 + ni*16 + lr][ks*32 + lg*8];
      #pragma unroll
      for (int oi=0;oi<4;++oi) bf[oi] = *(const f16x8*)&Wsh[wo*64 + oi*16 + lr][ks*32 + lg*8];
      #pragma unroll
      for (int ni=0;ni<4;++ni)
        #pragma unroll
        for (int oi=0;oi<4;++oi) acc[ni][oi] = mfma16(a[ni], bf[oi], acc[ni][oi]);
    }
    __syncthreads();
  }
  #pragma unroll
  for (int ni=0;ni<4;++ni)
    #pragma unroll
    for (int oi=0;oi<4;++oi){
      const int oc = o0 + wo*64 + oi*16 + lr;
      const float bi = bias[oc];
      #pragma unroll
      for (int i=0;i<4;++i){
        const int nn = n0 + wn*64 + ni*16 + lg*4 + i;
        float v = acc[ni][oi][i] + bi;
        if constexpr (RELU) v = fmaxf(v, 0.f);
        OUT[(long)b*NPT*ors + (long)nn*ors + oc] = (f16)v;
      }
    }
}

// ---------------------------------------------------------------------------
// mlp3 layer1 with fused max, 128x128 tile. grid (16, 8, B). K=512.
// ---------------------------------------------------------------------------
__global__ __launch_bounds__(256, 4) void k_gemmax128(
    const f16* __restrict__ W, const float* __restrict__ bias,
    const f16* __restrict__ XT, float* __restrict__ part)
{
  __shared__ __align__(16) f16 Xs[128][72];
  __shared__ __align__(16) f16 Wsh[128][72];
  __shared__ float red[2][128];
  const int b  = blockIdx.z;
  const int n0 = blockIdx.x * 128;
  const int o0 = blockIdx.y * 128;
  const int tid = threadIdx.x, lane = tid & 63, w = tid >> 6;
  const int lr = lane & 15, lg = lane >> 4;
  const int wn = w >> 1, wo = w & 1;
  const f16* Xb = XT + (long)b*NPT*512;
  f32x4 acc[4][4];
  #pragma unroll
  for (int ni=0;ni<4;++ni)
    #pragma unroll
    for (int oi=0;oi<4;++oi) acc[ni][oi] = (f32x4){0,0,0,0};

  for (int k0=0; k0<512; k0+=64){
    #pragma unroll
    for (int g = tid; g < 1024; g += 256){
      int r = g>>3, s = g&7;
      *(float4*)&Xs[r][s*8]  = *(const float4*)(Xb + (long)(n0+r)*512 + k0 + s*8);
      *(float4*)&Wsh[r][s*8] = *(const float4*)(W + (long)(o0+r)*512 + k0 + s*8);
    }
    __syncthreads();
    #pragma unroll
    for (int ks=0; ks<2; ++ks){
      f16x8 a[4], bf[4];
      #pragma unroll
      for (int ni=0;ni<4;++ni) a[ni]  = *(const f16x8*)&Xs[wn*64 + ni*16 + lr][ks*32 + lg*8];
      #pragma unroll
      for (int oi=0;oi<4;++oi) bf[oi] = *(const f16x8*)&Wsh[wo*64 + oi*16 + lr][ks*32 + lg*8];
      #pragma unroll
      for (int ni=0;ni<4;++ni)
        #pragma unroll
        for (int oi=0;oi<4;++oi) acc[ni][oi] = mfma16(a[ni], bf[oi], acc[ni][oi]);
    }
    __syncthreads();
  }
  #pragma unroll
  for (int oi=0;oi<4;++oi){
    const int oc128 = wo*64 + oi*16 + lr;
    const float bi = bias[o0 + oc128];
    float mv = -1e30f;
    #pragma unroll
    for (int ni=0;ni<4;++ni)
      #pragma unroll
      for (int i=0;i<4;++i) mv = fmaxf(mv, acc[ni][oi][i] + bi);
    mv = fmaxf(mv, __shfl_xor(mv, 16, 64));
    mv = fmaxf(mv, __shfl_xor(mv, 32, 64));
    if (lg == 0) red[wn][oc128] = mv;
  }
  __syncthreads();
  if (tid < 128)
    part[((long)b*1024 + o0 + tid)*16 + blockIdx.x] = fmaxf(red[0][tid], red[1][tid]);
}

// ---------------------------------------------------------------------------
// v GEMM: v16[b][c][n] = bv[c] + sum_k Wv[c][k]*XT[b][n][k]  (c rows, n cols)
// ---------------------------------------------------------------------------
__global__ __launch_bounds__(256) void vgemm(
    const f16* __restrict__ Wv, const float* __restrict__ bv,
    const f16* __restrict__ XT, f16* __restrict__ v16)
{
  __shared__ __align__(16) f16 Xs[64][72];
  __shared__ __align__(16) f16 Wsh[64][72];
  const int b  = blockIdx.z;
  const int n0 = blockIdx.x * 64;
  const int c0 = blockIdx.y * 64;
  const int tid = threadIdx.x, lane = tid & 63, w = tid >> 6;
  const int lr = lane & 15, lg = lane >> 4;
  const int wc = w>>1, wn = w&1;
  const f16* Xb = XT + (long)b*NPT*128;
  f32x4 acc[2][2];
  #pragma unroll
  for (int ci=0;ci<2;++ci){ acc[ci][0]=(f32x4){0,0,0,0}; acc[ci][1]=(f32x4){0,0,0,0}; }

  for (int k0=0; k0<128; k0+=64){
    #pragma unroll
    for (int g = tid; g < 512; g += 256){
      int r = g>>3, s = g&7;
      *(float4*)&Xs[r][s*8]  = *(const float4*)(Xb + (long)(n0+r)*128 + k0 + s*8);
      *(float4*)&Wsh[r][s*8] = *(const float4*)(Wv + (long)(c0+r)*128 + k0 + s*8);
    }
    __syncthreads();
    #pragma unroll
    for (int ks=0; ks<2; ++ks){
      f16x8 a[2], bf[2];
      #pragma unroll
      for (int ci=0;ci<2;++ci) a[ci] = *(const f16x8*)&Wsh[wc*32 + ci*16 + lr][ks*32 + lg*8];
      #pragma unroll
      for (int ni=0;ni<2;++ni) bf[ni] = *(const f16x8*)&Xs[wn*32 + ni*16 + lr][ks*32 + lg*8];
      #pragma unroll
      for (int ci=0;ci<2;++ci)
        #pragma unroll
        for (int ni=0;ni<2;++ni) acc[ci][ni] = mfma16(a[ci], bf[ni], acc[ci][ni]);
    }
    __syncthreads();
  }
  #pragma unroll
  for (int ci=0;ci<2;++ci)
    #pragma unroll
    for (int i=0;i<4;++i){
      const int c = c0 + wc*32 + ci*16 + lg*4 + i;
      const float bi = bv[c];
      #pragma unroll
      for (int ni=0;ni<2;++ni){
        const int n = n0 + wn*32 + ni*16 + lr;
        v16[(long)b*128*NPT + (long)c*NPT + n] = (f16)(acc[ci][ni][i] + bi);
      }
    }
}

// ---------------------------------------------------------------------------
// rowstats via MFMA: rmax/rsum over m of e[m,n] (symmetric e) per col n.
// ---------------------------------------------------------------------------
__global__ __launch_bounds__(256) void k_rowstats2(const f16* __restrict__ qT,
                                                   float* __restrict__ rmax,
                                                   float* __restrict__ rsum)
{
  const int b = blockIdx.y, n0 = blockIdx.x*64;
  const int tid = threadIdx.x, lane = tid & 63, w = tid >> 6;
  const int lr = lane & 15, lg = lane >> 4;
  const f16* qb = qT + (long)b*NPT*32;
  const f16x8 bfr = *(const f16x8*)(qb + (long)(n0 + w*16 + lr)*32 + lg*8);
  float mx = -1e30f, sm = 0.f;
  for (int m0=0; m0<NPT; m0+=32){
    f16x8 af0 = *(const f16x8*)(qb + (long)(m0+lr)*32 + lg*8);
    f16x8 af1 = *(const f16x8*)(qb + (long)(m0+16+lr)*32 + lg*8);
    f32x4 e0 = mfma16(af0, bfr, (f32x4){0,0,0,0});
    f32x4 e1 = mfma16(af1, bfr, (f32x4){0,0,0,0});
    float t0 = fmaxf(fmaxf(e0[0],e0[1]), fmaxf(e0[2],e0[3]));
    float t1 = fmaxf(fmaxf(e1[0],e1[1]), fmaxf(e1[2],e1[3]));
    float nm = fmaxf(mx, fmaxf(t0, t1));
    sm *= __expf(mx - nm);
    mx = nm;
    sm += __expf(e0[0]-mx) + __expf(e0[1]-mx) + __expf(e0[2]-mx) + __expf(e0[3]-mx)
        + __expf(e1[0]-mx) + __expf(e1[1]-mx) + __expf(e1[2]-mx) + __expf(e1[3]-mx);
  }
  #pragma unroll
  for (int d=16; d<64; d<<=1){
    float omx = __shfl_xor(mx, d, 64);
    float osm = __shfl_xor(sm, d, 64);
    float nm = fmaxf(mx, omx);
    sm = sm*__expf(mx-nm) + osm*__expf(omx-nm);
    mx = nm;
  }
  if (lane < 16){
    rmax[(long)b*NPT + n0 + w*16 + lr] = mx;
    rsum[(long)b*NPT + n0 + w*16 + lr] = sm;
  }
}

// ---------------------------------------------------------------------------
// pass2 PARTIAL, 32 m-rows per wave (2 strips), 2-deep pipelined V staging.
// grid (NPT/128=16, NSEG, B) = 1024 blocks = exactly 4 blocks/CU: no tail.
// per segment seg, n in [seg*512, seg*512+512):
//   xrpart[(b*NSEG+seg)][m][c] = sum_n p[n,m] v[c,n]   (f16 raw)
//   cspart[(b*NSEG+seg)*NPT + m] = sum_n p[n,m]        (fp32, ones-MFMA)
// ---------------------------------------------------------------------------
__global__ __launch_bounds__(256, 4) void k_pass2p(const f16* __restrict__ qT,
                                                   const f16* __restrict__ v16,
                                                   const float* __restrict__ rmax,
                                                   const float* __restrict__ rsum,
                                                   f16* __restrict__ xrpart,
                                                   float* __restrict__ cspart)
{
  __shared__ __align__(16) f16 ps[128][40];     // pT[m][n-tile]; rows wave-private
  __shared__ __align__(16) f16 vs[2][128][40];  // double-buffered v-tile [c][n-tile]
  const int b = blockIdx.z, seg = blockIdx.y, m0 = blockIdx.x*128;
  const int tid = threadIdx.x, lane = tid & 63, w = tid >> 6;
  const int lr = lane & 15, lg = lane >> 4;
  const f16* qb = qT + (long)b*NPT*32;
  const f16* vb = v16 + (long)b*128*NPT;
  const float* rmx = rmax + (long)b*NPT;
  const float* rsm = rsum + (long)b*NPT;
  // two 16-m strips per wave: mbase(mi) = m0 + w*32 + mi*16
  f16x8 afe[2];
  #pragma unroll
  for (int mi=0;mi<2;++mi)
    afe[mi] = *(const f16x8*)(qb + (long)(m0 + w*32 + mi*16 + lr)*32 + lg*8);
  f16x8 ones;
  #pragma unroll
  for (int j=0;j<8;++j) ones[j] = (f16)1.0f;
  f32x4 acc[2][8];
  #pragma unroll
  for (int mi=0;mi<2;++mi)
    #pragma unroll
    for (int cg=0; cg<8; ++cg) acc[mi][cg] = (f32x4){0,0,0,0};
  f32x4 acc_cs[2];
  acc_cs[0] = (f32x4){0,0,0,0}; acc_cs[1] = (f32x4){0,0,0,0};

  const int ntBeg = seg*(NPT/NSEG), ntEnd = ntBeg + NPT/NSEG;
  // prologue: stage first tile into vs[0]
  #pragma unroll
  for (int g = tid; g < 512; g += 256){
    int c = g>>2, s = g&3;
    *(float4*)&vs[0][c][s*8] = *(const float4*)(vb + (long)c*NPT + ntBeg + s*8);
  }
  __syncthreads();
  int cur = 0;

  for (int nt=ntBeg; nt<ntEnd; nt+=32){
    // issue next tile's staging into vs[cur^1] (flies under E+PV compute)
    if (nt + 32 < ntEnd){
      #pragma unroll
      for (int g = tid; g < 512; g += 256){
        int c = g>>2, s = g&3;
        *(float4*)&vs[cur^1][c][s*8] = *(const float4*)(vb + (long)c*NPT + nt + 32 + s*8);
      }
    }
    // E phase: 2 n col-groups x 2 m strips; ps rows wave-private
    #pragma unroll
    for (int ng=0; ng<2; ++ng){
      f16x8 bfe = *(const f16x8*)(qb + (long)(nt + ng*16 + lr)*32 + lg*8);
      const int n = nt + ng*16 + lr;
      const float rm = rmx[n];
      const float irs = 1.f / rsm[n];
      #pragma unroll
      for (int mi=0; mi<2; ++mi){
        f32x4 e = mfma16(afe[mi], bfe, (f32x4){0,0,0,0});
        #pragma unroll
        for (int i=0;i<4;++i){
          float p = __expf(e[i] - rm) * irs;
          ps[w*32 + mi*16 + lg*4 + i][ng*16 + lr] = (f16)p;
        }
      }
    }
    // PV phase: per strip, A = pT rows m (wave-private), B = current v-tile
    #pragma unroll
    for (int mi=0; mi<2; ++mi){
      f16x8 ap = *(const f16x8*)&ps[w*32 + mi*16 + lr][lg*8];
      #pragma unroll
      for (int cg=0; cg<8; ++cg){
        f16x8 bp = *(const f16x8*)&vs[cur][cg*16 + lr][lg*8];
        acc[mi][cg] = mfma16(ap, bp, acc[mi][cg]);
      }
      acc_cs[mi] = mfma16(ap, ones, acc_cs[mi]);
    }
    __syncthreads();                      // drains staging; protects vs[cur] reuse
    cur ^= 1;
  }
  const long row = (long)(b*NSEG + seg);
  f16* xb = xrpart + row*NPT*128;
  #pragma unroll
  for (int mi=0; mi<2; ++mi){
    const int mbase = m0 + w*32 + mi*16;
    if (lr == 0){
      #pragma unroll
      for (int i=0;i<4;++i)
        cspart[row*NPT + mbase + lg*4 + i] = acc_cs[mi][i];
    }
    #pragma unroll
    for (int cg=0; cg<8; ++cg)
      #pragma unroll
      for (int i=0;i<4;++i)
        xb[(long)(mbase + lg*4 + i)*128 + cg*16 + lr] = (f16)acc[mi][cg][i];
  }
}

// ---------------------------------------------------------------------------
// merge NSEG partials: xrT[b][m][c] = (sum_s xrpart)/(1e-9 + sum_s cspart)
// ---------------------------------------------------------------------------
__global__ __launch_bounds__(256) void k_pmerge(const f16* __restrict__ xrpart,
                                                const float* __restrict__ cspart,
                                                f16* __restrict__ xrT)
{
  const long idx = (long)blockIdx.x*256 + threadIdx.x;   // 0..524287
  const long gm = idx >> 4;          // b*2048 + m
  const int  c0 = (int)(idx & 15) * 8;
  const long b = gm >> 11, m = gm & 2047;
  const long r0 = (b*NSEG) * (long)NPT + m;              // row base in [B*NSEG][NPT]
  float cs = 0.f;
  #pragma unroll
  for (int s=0;s<NSEG;++s) cs += cspart[r0 + (long)s*NPT];
  const float inv = 1.f/(1e-9f + cs);
  float a8[8];
  #pragma unroll
  for (int j=0;j<8;++j) a8[j] = 0.f;
  #pragma unroll
  for (int s=0;s<NSEG;++s){
    f16x8 v = *(const f16x8*)(xrpart + (r0 + (long)s*NPT)*128 + c0);
    #pragma unroll
    for (int j=0;j<8;++j) a8[j] += (float)v[j];
  }
  f16x8 ov;
  #pragma unroll
  for (int j=0;j<8;++j) ov[j] = (f16)(a8[j]*inv);
  *(f16x8*)(xrT + gm*128 + c0) = ov;
}

// ---------------------------------------------------------------------------
// xT = prev + lfT (fp16 vector add)
// ---------------------------------------------------------------------------
__global__ __launch_bounds__(256) void k_addT(const f16* __restrict__ prev, int prs, int pcol,
                                              const f16* __restrict__ lfT,
                                              f16* __restrict__ xT)
{
  long idx = (long)blockIdx.x*256 + threadIdx.x;
  long bn = idx >> 4; int c8 = (int)(idx & 15);
  f16x8 a = *(const f16x8*)(prev + bn*prs + pcol + c8*8);
  f16x8 l = *(const f16x8*)(lfT + bn*128 + c8*8);
  *(f16x8*)(xT + bn*128 + c8*8) = a + l;
}

// ---------------------------------------------------------------------------
// gmax over n per (b,c)
// ---------------------------------------------------------------------------
__global__ __launch_bounds__(1024) void k_gmaxT(const f16* __restrict__ lfT,
                                                float* __restrict__ gmaxv)
{
  __shared__ float red[8][128];
  const int b = blockIdx.x;
  const int c = threadIdx.x & 127, h = threadIdx.x >> 7;
  const f16* p = lfT + (long)b*NPT*128;
  float m = -1e30f;
  for (int n = h*256; n < (h+1)*256; ++n) m = fmaxf(m, (float)p[(long)n*128 + c]);
  red[h][c] = m; __syncthreads();
  if (threadIdx.x < 128){
    float mm = red[0][c];
    #pragma unroll
    for (int j=1;j<8;++j) mm = fmaxf(mm, red[j][c]);
    gmaxv[b*128 + c] = mm;
  }
}

__global__ __launch_bounds__(128) void k_gvec(const float* __restrict__ w0,
                                              const float* __restrict__ b0,
                                              const float* __restrict__ gmaxv,
                                              float* __restrict__ gc)
{
  const int b = blockIdx.x, o = threadIdx.x;
  __shared__ float g[128];
  g[o] = gmaxv[b*128+o]; __syncthreads();
  float acc = b0[o];
  for (int c = 0; c < 128; ++c) acc = fmaf(w0[o*256 + 128 + c], g[c], acc);
  gc[b*128+o] = acc;
}

// ---------------------------------------------------------------------------
// SA epilogue GEMM
// ---------------------------------------------------------------------------
__global__ __launch_bounds__(256) void k_safin(
    const f16* __restrict__ Wt, const float* __restrict__ bt,
    const float* __restrict__ g, const float* __restrict__ be,
    const f16* __restrict__ xT, const f16* __restrict__ xrT,
    f16* __restrict__ cat, int Lcol)
{
  __shared__ __align__(16) f16 Xs[64][72];
  __shared__ __align__(16) f16 Wsh[64][72];
  const int b  = blockIdx.z;
  const int n0 = blockIdx.x * 64;
  const int o0 = blockIdx.y * 64;
  const int tid = threadIdx.x, lane = tid & 63, w = tid >> 6;
  const int lr = lane & 15, lg = lane >> 4;
  const int wn = w>>1, wo = w&1;
  const f16* xb  = xT  + (long)b*NPT*128;
  const f16* xrb = xrT + (long)b*NPT*128;
  f32x4 acc[2][2];
  #pragma unroll
  for (int ni=0;ni<2;++ni){ acc[ni][0]=(f32x4){0,0,0,0}; acc[ni][1]=(f32x4){0,0,0,0}; }

  for (int k0=0; k0<128; k0+=64){
    #pragma unroll
    for (int gidx = tid; gidx < 512; gidx += 256){
      int r = gidx>>3, s = gidx&7;
      f16x8 xa = *(const f16x8*)(xb  + (long)(n0+r)*128 + k0 + s*8);
      f16x8 xr = *(const f16x8*)(xrb + (long)(n0+r)*128 + k0 + s*8);
      *(f16x8*)&Xs[r][s*8] = xa - xr;
      *(float4*)&Wsh[r][s*8] = *(const float4*)(Wt + (long)(o0+r)*128 + k0 + s*8);
    }
    __syncthreads();
    #pragma unroll
    for (int ks=0; ks<2; ++ks){
      f16x8 a[2], bf[2];
      #pragma unroll
      for (int ni=0;ni<2;++ni) a[ni] = *(const f16x8*)&Xs[wn*32 + ni*16 + lr][ks*32 + lg*8];
      #pragma unroll
      for (int oi=0;oi<2;++oi) bf[oi] = *(const f16x8*)&Wsh[wo*32 + oi*16 + lr][ks*32 + lg*8];
      #pragma unroll
      for (int ni=0;ni<2;++ni)
        #pragma unroll
        for (int oi=0;oi<2;++oi) acc[ni][oi] = mfma16(a[ni], bf[oi], acc[ni][oi]);
    }
    __syncthreads();
  }
  const float bnsc = rsqrtf(1.f + 1e-5f);
  #pragma unroll
  for (int ni=0;ni<2;++ni)
    #pragma unroll
    for (int oi=0;oi<2;++oi){
      const int oc = o0 + wo*32 + oi*16 + lr;
      const float bti = bt[oc], gi = g[oc]*bnsc, bei = be[oc];
      #pragma unroll
      for (int i=0;i<4;++i){
        const int nn = n0 + wn*32 + ni*16 + lg*4 + i;
        float t = acc[ni][oi][i] + bti;
        float val = fmaxf(fmaf(gi, t, bei), 0.f);
        float res = (float)xb[(long)nn*128 + oc];
        cat[(long)b*NPT*384 + (long)nn*384 + Lcol + oc] = (f16)(res + val);
      }
    }
}

__global__ __launch_bounds__(256) void k_maxfinal(const float* __restrict__ part,
                                                  float* __restrict__ out)
{
  const int t = blockIdx.x*256 + threadIdx.x;   // 0..16383
  float m = -1e30f;
  #pragma unroll
  for (int j=0;j<16;++j) m = fmaxf(m, part[(long)t*16 + j]);
  out[t] = m;
}

// ---------------------------------------------------------------------------
extern "C" void kernel_launch(void* const* d_in, const int* in_sizes, int n_in,
                              void* d_out, int out_size, void* d_ws, size_t ws_size,
                              hipStream_t stream)
{
  const float* in   = (const float*)d_in[0];
  const float* m1w0 = (const float*)d_in[1];
  const float* m1b0 = (const float*)d_in[2];
  const float* m1w1 = (const float*)d_in[3];
  const float* m1b1 = (const float*)d_in[4];
  const float* m2w0 = (const float*)d_in[5];
  const float* m2b0 = (const float*)d_in[6];
  const float* m2w1 = (const float*)d_in[7];
  const float* m2b1 = (const float*)d_in[8];
  const float* m3w0 = (const float*)d_in[9];
  const float* m3b0 = (const float*)d_in[10];
  const float* m3w1 = (const float*)d_in[11];
  const float* m3b1 = (const float*)d_in[12];

  // ws layout (halfs)
  f16* ws16 = (f16*)d_ws;
  f16* W16  = ws16;                       // 880,640
  f16* lfT  = ws16 + 880640;              // [B][N][128]
  f16* xT   = ws16 + 5074944;             // [B][N][128]
  f16* qT   = ws16 + 9269248;             // [B][N][32]
  f16* vbuf = ws16 + 10317824;            // [B][128][N]
  f16* xrT  = ws16 + 14512128;            // [B][N][128] (also mlp2 features)
  f16* hT   = ws16 + 18706432;            // [B][N][512] (mlp hidden)
  f16* xrpart = hT;                       // [B*NSEG][N][128] — aliases hT (dead during SA)
  f16* catT = ws16 + 35483648;            // [B][N][384]
  float* fb = (float*)(ws16 + 48066560);
  float* rmaxp  = fb;                     // [B,N]
  float* rsump  = fb + 32768;             // [B,N]
  float* gmaxv  = fb + 65536;             // [B,128]
  float* gc     = fb + 67584;             // [B,128]
  float* part   = fb + 69632;             // [B,1024,16]
  float* cspart = fb + 593920;            // [B*NSEG][N]

  const dim3 blk(256);

  k_wconv<<<dim3((WTOT+255)/256), blk, 0, stream>>>(
      m1w1, m2w0, m2w1, m3w0, m3w1,
      (const float*)d_in[13], (const float*)d_in[14], (const float*)d_in[16],
      (const float*)d_in[20], (const float*)d_in[21], (const float*)d_in[23],
      (const float*)d_in[27], (const float*)d_in[28], (const float*)d_in[30],
      W16);

  // mlp1
  k_mlp1aT<<<dim3(NBAT*NPT*32/256), blk, 0, stream>>>(in, m1w0, m1b0, hT);
  gemmT<64,false,false><<<dim3(32,2,NBAT), blk, 0, stream>>>(
      W16+OFF_M1W1, m1b1, nullptr, hT, 128, lfT, 128, 0, 128);
  // global max + mlp2
  k_gmaxT<<<dim3(NBAT), dim3(1024), 0, stream>>>(lfT, gmaxv);
  k_gvec<<<dim3(NBAT), dim3(128), 0, stream>>>(m2w0, m2b0, gmaxv, gc);
  gemmT<64,true,true><<<dim3(32,2,NBAT), blk, 0, stream>>>(
      W16+OFF_M2W0A, nullptr, gc, lfT, 128, hT, 128, 0, 128);
  gemmT<64,false,false><<<dim3(32,2,NBAT), blk, 0, stream>>>(
      W16+OFF_M2W1, m2b1, nullptr, hT, 128, xrT, 128, 0, 128);   // features -> xrT

  // 3 SA layers
  for (int L = 0; L < 3; ++L){
    const float* bv = (const float*)d_in[13 + L*7 + 2];
    const float* bt = (const float*)d_in[13 + L*7 + 4];
    const float* gg = (const float*)d_in[13 + L*7 + 5];
    const float* be = (const float*)d_in[13 + L*7 + 6];
    const f16* wq16 = W16 + OFF_SA + L*SA_STRIDE;
    const f16* wv16 = wq16 + 4096;
    const f16* wt16 = wq16 + 20480;

    const f16* prev = (L==0) ? xrT : (catT + (long)(L-1)*128);
    const int  prs  = (L==0) ? 128 : 384;
    k_addT<<<dim3(NBAT*NPT*16/256), blk, 0, stream>>>(prev, prs, 0, lfT, xT);

    gemmT<32,false,false><<<dim3(32,1,NBAT), blk, 0, stream>>>(
        wq16, nullptr, nullptr, xT, 128, qT, 32, 0, 128);
    vgemm<<<dim3(32,2,NBAT), blk, 0, stream>>>(wv16, bv, xT, vbuf);
    k_rowstats2<<<dim3(32,NBAT), blk, 0, stream>>>(qT, rmaxp, rsump);
    k_pass2p<<<dim3(NPT/128,NSEG,NBAT), blk, 0, stream>>>(qT, vbuf, rmaxp, rsump, xrpart, cspart);
    k_pmerge<<<dim3(2048), blk, 0, stream>>>(xrpart, cspart, xrT);
    k_safin<<<dim3(32,2,NBAT), blk, 0, stream>>>(wt16, bt, gg, be, xT, xrT, catT, L*128);
  }

  // mlp3: layer0 (384->512 relu) 128x128 tile, layer1 fused-max 128x128
  gemm128<true><<<dim3(16,4,NBAT), blk, 0, stream>>>(
      W16+OFF_M3W0, m3b0, catT, 384, hT, 512, 384);
  k_gemmax128<<<dim3(16,8,NBAT), blk, 0, stream>>>(W16+OFF_M3W1, m3b1, hT, part);
  k_maxfinal<<<dim3(64), blk, 0, stream>>>(part, (float*)d_out);
}

// Round 16
// 493.709 us; speedup vs baseline: 1.0203x; 1.0203x over previous
//
#include <hip/hip_runtime.h>
#include <hip/hip_bf16.h>
#include <cfloat>

static constexpr int NBAT = 16;
static constexpr int NPT  = 2048;
static constexpr int NSEG = 2;     // pass2 n-split segments (r16: 4->2, halves partial traffic)

typedef _Float16 f16;
typedef _Float16 f16x8 __attribute__((ext_vector_type(8)));
typedef float    f32x4 __attribute__((ext_vector_type(4)));

static __device__ __forceinline__ f32x4 mfma16(f16x8 a, f16x8 b, f32x4 c){
  return __builtin_amdgcn_mfma_f32_16x16x32_f16(a, b, c, 0, 0, 0);
}
// MFMA 16x16x32 f16 layouts (gfx950, e2e-verified by round-4 pass):
//  A[16r x 32k]: lane l -> row l&15, k = (l>>4)*8 + j (16B contiguous)
//  B[32k x 16c]: lane l -> col l&15, k = (l>>4)*8 + j (16B contiguous)
//  D[16r x 16c]: lane l -> col l&15, rows (l>>4)*4 + i

// ---- weight arena offsets (halfs) ----
static constexpr long OFF_M1W1 = 0;              // [128][128]
static constexpr long OFF_M2W0A= 16384;          // [128][128] (cols 0..127 of [128][256])
static constexpr long OFF_M2W1 = 32768;          // [128][128]
static constexpr long OFF_M3W0 = 49152;          // [512][384]
static constexpr long OFF_M3W1 = 245760;         // [1024][512]
static constexpr long OFF_SA   = 770048;         // per-L: wq[32][128], wv[128][128], wt[128][128]
static constexpr long SA_STRIDE= 36864;
static constexpr long WTOT     = OFF_SA + 3*SA_STRIDE;   // 880,640 halfs

// ---------------------------------------------------------------------------
// weight fp32 -> fp16 conversion into arena (one launch)
// ---------------------------------------------------------------------------
__global__ __launch_bounds__(256) void k_wconv(
    const float* m1w1, const float* m2w0, const float* m2w1,
    const float* m3w0, const float* m3w1,
    const float* wq0, const float* wv0, const float* wt0,
    const float* wq1, const float* wv1, const float* wt1,
    const float* wq2, const float* wv2, const float* wt2,
    f16* W)
{
  long t = (long)blockIdx.x*256 + threadIdx.x;
  if (t >= WTOT) return;
  float v;
  if      (t < OFF_M2W0A) v = m1w1[t];
  else if (t < OFF_M2W1) { long u = t-OFF_M2W0A; v = m2w0[(u>>7)*256 + (u&127)]; }
  else if (t < OFF_M3W0)  v = m2w1[t-OFF_M2W1];
  else if (t < OFF_M3W1)  v = m3w0[t-OFF_M3W0];
  else if (t < OFF_SA)    v = m3w1[t-OFF_M3W1];
  else {
    long u = t - OFF_SA; int L = (int)(u / SA_STRIDE); long r = u % SA_STRIDE;
    const float* wq = (L==0)?wq0:(L==1)?wq1:wq2;
    const float* wv = (L==0)?wv0:(L==1)?wv1:wv2;
    const float* wt = (L==0)?wt0:(L==1)?wt1:wt2;
    if (r < 4096) v = wq[r]; else if (r < 20480) v = wv[r-4096]; else v = wt[r-20480];
  }
  W[t] = (f16)v;
}

// ---------------------------------------------------------------------------
// mlp1 layer0 (K=3): h1T[b][n][o] = relu(b0[o] + sum_c w0[o][c]*in[b][n][c])
// ---------------------------------------------------------------------------
__global__ __launch_bounds__(256) void k_mlp1aT(const float* __restrict__ in,
                                                const float* __restrict__ w0,
                                                const float* __restrict__ b0,
                                                f16* __restrict__ h1T)
{
  long idx = (long)blockIdx.x*256 + threadIdx.x;
  int og = idx & 31; long bn = idx >> 5;
  const float* ip = in + bn*3;
  float x0=ip[0], x1=ip[1], x2=ip[2];
  f16* op = h1T + bn*128 + og*4;
  #pragma unroll
  for (int i=0;i<4;++i){
    int o = og*4+i;
    float v = b0[o] + w0[o*3]*x0 + w0[o*3+1]*x1 + w0[o*3+2]*x2;
    op[i] = (f16)fmaxf(v, 0.f);
  }
}

// ---------------------------------------------------------------------------
// generic transposed conv GEMM: OUTT[b][n][ocol+o] = act(bias + sum_k XT[b][n][k]*W[o][k])
// ---------------------------------------------------------------------------
template<int OT, bool RELU, bool B2D>
__global__ __launch_bounds__(256) void gemmT(
    const f16* __restrict__ W, const float* __restrict__ bias,
    const float* __restrict__ bias2d,
    const f16* __restrict__ XT, int xrs,
    f16* __restrict__ OUT, int ors, int ocol, int K)
{
  __shared__ __align__(16) f16 Xs[64][72];
  __shared__ __align__(16) f16 Wsh[OT][72];
  const int b  = blockIdx.z;
  const int n0 = blockIdx.x * 64;
  const int o0 = blockIdx.y * OT;
  const int tid = threadIdx.x, lane = tid & 63, w = tid >> 6;
  const int lr = lane & 15, lg = lane >> 4;
  constexpr int NSUB = (OT==64)?2:1;
  const int wn = (OT==64)? (w>>1) : w;
  const int wo = (OT==64)? (w&1) : 0;
  const int nbase = wn*(16*NSUB);
  const f16* Xb = XT + (long)b*NPT*xrs;
  f32x4 acc[NSUB][2];
  #pragma unroll
  for (int ni=0;ni<NSUB;++ni){ acc[ni][0]=(f32x4){0,0,0,0}; acc[ni][1]=(f32x4){0,0,0,0}; }

  for (int k0=0; k0<K; k0+=64){
    #pragma unroll
    for (int g = tid; g < 512; g += 256){
      int r = g>>3, s = g&7;
      *(float4*)&Xs[r][s*8] = *(const float4*)(Xb + (long)(n0+r)*xrs + k0 + s*8);
    }
    for (int g = tid; g < OT*8; g += 256){
      int r = g>>3, s = g&7;
      *(float4*)&Wsh[r][s*8] = *(const float4*)(W + (long)(o0+r)*K + k0 + s*8);
    }
    __syncthreads();
    #pragma unroll
    for (int ks=0; ks<2; ++ks){
      f16x8 a[NSUB], bf[2];
      #pragma unroll
      for (int ni=0;ni<NSUB;++ni) a[ni] = *(const f16x8*)&Xs[nbase + ni*16 + lr][ks*32 + lg*8];
      #pragma unroll
      for (int oi=0;oi<2;++oi)   bf[oi] = *(const f16x8*)&Wsh[wo*32 + oi*16 + lr][ks*32 + lg*8];
      #pragma unroll
      for (int ni=0;ni<NSUB;++ni)
        #pragma unroll
        for (int oi=0;oi<2;++oi) acc[ni][oi] = mfma16(a[ni], bf[oi], acc[ni][oi]);
    }
    __syncthreads();
  }
  #pragma unroll
  for (int ni=0;ni<NSUB;++ni)
    #pragma unroll
    for (int oi=0;oi<2;++oi){
      const int oc = o0 + wo*32 + oi*16 + lr;
      float bi = bias ? bias[oc] : 0.f;
      if constexpr (B2D) bi += bias2d[b*128 + oc];
      #pragma unroll
      for (int i=0;i<4;++i){
        const int nn = n0 + nbase + ni*16 + lg*4 + i;
        float v = acc[ni][oi][i] + bi;
        if constexpr (RELU) v = fmaxf(v, 0.f);
        OUT[(long)b*NPT*ors + (long)nn*ors + ocol + oc] = (f16)v;
      }
    }
}

// ---------------------------------------------------------------------------
// 128x128-tile GEMM (4 waves as 2x2, each wave 64x64, acc[4][4]):
// __launch_bounds__(256,4): cap regs at 128/thread -> 4 blocks/CU.
// ---------------------------------------------------------------------------
template<bool RELU>
__global__ __launch_bounds__(256, 4) void gemm128(
    const f16* __restrict__ W, const float* __restrict__ bias,
    const f16* __restrict__ XT, int xrs,
    f16* __restrict__ OUT, int ors, int K)
{
  __shared__ __align__(16) f16 Xs[128][72];
  __shared__ __align__(16) f16 Wsh[128][72];
  const int b  = blockIdx.z;
  const int n0 = blockIdx.x * 128;
  const int o0 = blockIdx.y * 128;
  const int tid = threadIdx.x, lane = tid & 63, w = tid >> 6;
  const int lr = lane & 15, lg = lane >> 4;
  const int wn = w >> 1, wo = w & 1;
  const f16* Xb = XT + (long)b*NPT*xrs;
  f32x4 acc[4][4];
  #pragma unroll
  for (int ni=0;ni<4;++ni)
    #pragma unroll
    for (int oi=0;oi<4;++oi) acc[ni][oi] = (f32x4){0,0,0,0};

  for (int k0=0; k0<K; k0+=64){
    #pragma unroll
    for (int g = tid; g < 1024; g += 256){
      int r = g>>3, s = g&7;
      *(float4*)&Xs[r][s*8]  = *(const float4*)(Xb + (long)(n0+r)*xrs + k0 + s*8);
      *(float4*)&Wsh[r][s*8] = *(const float4*)(W + (long)(o0+r)*K + k0 + s*8);
    }
    __syncthreads();
    #pragma unroll
    for (int ks=0; ks<2; ++ks){
      f16x8 a[4], bf[4];
      #pragma unroll
      for (int ni=0;ni<4;++ni) a[ni]  = *(const f16x8*)&Xs[wn*64 + ni*16 + lr][ks*32 + lg*8];
      #pragma unroll
      for (int oi=0;oi<4;++oi) bf[oi] = *(const f16x8*)&Wsh[wo*64 + oi*16 + lr][ks*32 + lg*8];
      #pragma unroll
      for (int ni=0;ni<4;++ni)
        #pragma unroll
        for (int oi=0;oi<4;++oi) acc[ni][oi] = mfma16(a[ni], bf[oi], acc[ni][oi]);
    }
    __syncthreads();
  }
  #pragma unroll
  for (int ni=0;ni<4;++ni)
    #pragma unroll
    for (int oi=0;oi<4;++oi){
      const int oc = o0 + wo*64 + oi*16 + lr;
      const float bi = bias[oc];
      #pragma unroll
      for (int i=0;i<4;++i){
        const int nn = n0 + wn*64 + ni*16 + lg*4 + i;
        float v = acc[ni][oi][i] + bi;
        if constexpr (RELU) v = fmaxf(v, 0.f);
        OUT[(long)b*NPT*ors + (long)nn*ors + oc] = (f16)v;
      }
    }
}

// ---------------------------------------------------------------------------
// mlp3 layer1 with fused max, 128x128 tile. grid (16, 8, B). K=512.
// ---------------------------------------------------------------------------
__global__ __launch_bounds__(256, 4) void k_gemmax128(
    const f16* __restrict__ W, const float* __restrict__ bias,
    const f16* __restrict__ XT, float* __restrict__ part)
{
  __shared__ __align__(16) f16 Xs[128][72];
  __shared__ __align__(16) f16 Wsh[128][72];
  __shared__ float red[2][128];
  const int b  = blockIdx.z;
  const int n0 = blockIdx.x * 128;
  const int o0 = blockIdx.y * 128;
  const int tid = threadIdx.x, lane = tid & 63, w = tid >> 6;
  const int lr = lane & 15, lg = lane >> 4;
  const int wn = w >> 1, wo = w & 1;
  const f16* Xb = XT + (long)b*NPT*512;
  f32x4 acc[4][4];
  #pragma unroll
  for (int ni=0;ni<4;++ni)
    #pragma unroll
    for (int oi=0;oi<4;++oi) acc[ni][oi] = (f32x4){0,0,0,0};

  for (int k0=0; k0<512; k0+=64){
    #pragma unroll
    for (int g = tid; g < 1024; g += 256){
      int r = g>>3, s = g&7;
      *(float4*)&Xs[r][s*8]  = *(const float4*)(Xb + (long)(n0+r)*512 + k0 + s*8);
      *(float4*)&Wsh[r][s*8] = *(const float4*)(W + (long)(o0+r)*512 + k0 + s*8);
    }
    __syncthreads();
    #pragma unroll
    for (int ks=0; ks<2; ++ks){
      f16x8 a[4], bf[4];
      #pragma unroll
      for (int ni=0;ni<4;++ni) a[ni]  = *(const f16x8*)&Xs[wn*64 + ni*16 + lr][ks*32 + lg*8];
      #pragma unroll
      for (int oi=0;oi<4;++oi) bf[oi] = *(const f16x8*)&Wsh[wo*64 + oi*16 + lr][ks*32 + lg*8];
      #pragma unroll
      for (int ni=0;ni<4;++ni)
        #pragma unroll
        for (int oi=0;oi<4;++oi) acc[ni][oi] = mfma16(a[ni], bf[oi], acc[ni][oi]);
    }
    __syncthreads();
  }
  #pragma unroll
  for (int oi=0;oi<4;++oi){
    const int oc128 = wo*64 + oi*16 + lr;
    const float bi = bias[o0 + oc128];
    float mv = -1e30f;
    #pragma unroll
    for (int ni=0;ni<4;++ni)
      #pragma unroll
      for (int i=0;i<4;++i) mv = fmaxf(mv, acc[ni][oi][i] + bi);
    mv = fmaxf(mv, __shfl_xor(mv, 16, 64));
    mv = fmaxf(mv, __shfl_xor(mv, 32, 64));
    if (lg == 0) red[wn][oc128] = mv;
  }
  __syncthreads();
  if (tid < 128)
    part[((long)b*1024 + o0 + tid)*16 + blockIdx.x] = fmaxf(red[0][tid], red[1][tid]);
}

// ---------------------------------------------------------------------------
// v GEMM: v16[b][c][n] = bv[c] + sum_k Wv[c][k]*XT[b][n][k]  (c rows, n cols)
// ---------------------------------------------------------------------------
__global__ __launch_bounds__(256) void vgemm(
    const f16* __restrict__ Wv, const float* __restrict__ bv,
    const f16* __restrict__ XT, f16* __restrict__ v16)
{
  __shared__ __align__(16) f16 Xs[64][72];
  __shared__ __align__(16) f16 Wsh[64][72];
  const int b  = blockIdx.z;
  const int n0 = blockIdx.x * 64;
  const int c0 = blockIdx.y * 64;
  const int tid = threadIdx.x, lane = tid & 63, w = tid >> 6;
  const int lr = lane & 15, lg = lane >> 4;
  const int wc = w>>1, wn = w&1;
  const f16* Xb = XT + (long)b*NPT*128;
  f32x4 acc[2][2];
  #pragma unroll
  for (int ci=0;ci<2;++ci){ acc[ci][0]=(f32x4){0,0,0,0}; acc[ci][1]=(f32x4){0,0,0,0}; }

  for (int k0=0; k0<128; k0+=64){
    #pragma unroll
    for (int g = tid; g < 512; g += 256){
      int r = g>>3, s = g&7;
      *(float4*)&Xs[r][s*8]  = *(const float4*)(Xb + (long)(n0+r)*128 + k0 + s*8);
      *(float4*)&Wsh[r][s*8] = *(const float4*)(Wv + (long)(c0+r)*128 + k0 + s*8);
    }
    __syncthreads();
    #pragma unroll
    for (int ks=0; ks<2; ++ks){
      f16x8 a[2], bf[2];
      #pragma unroll
      for (int ci=0;ci<2;++ci) a[ci] = *(const f16x8*)&Wsh[wc*32 + ci*16 + lr][ks*32 + lg*8];
      #pragma unroll
      for (int ni=0;ni<2;++ni) bf[ni] = *(const f16x8*)&Xs[wn*32 + ni*16 + lr][ks*32 + lg*8];
      #pragma unroll
      for (int ci=0;ci<2;++ci)
        #pragma unroll
        for (int ni=0;ni<2;++ni) acc[ci][ni] = mfma16(a[ci], bf[ni], acc[ci][ni]);
    }
    __syncthreads();
  }
  #pragma unroll
  for (int ci=0;ci<2;++ci)
    #pragma unroll
    for (int i=0;i<4;++i){
      const int c = c0 + wc*32 + ci*16 + lg*4 + i;
      const float bi = bv[c];
      #pragma unroll
      for (int ni=0;ni<2;++ni){
        const int n = n0 + wn*32 + ni*16 + lr;
        v16[(long)b*128*NPT + (long)c*NPT + n] = (f16)(acc[ci][ni][i] + bi);
      }
    }
}

// ---------------------------------------------------------------------------
// rowstats via MFMA: rmax/rsum over m of e[m,n] (symmetric e) per col n.
// ---------------------------------------------------------------------------
__global__ __launch_bounds__(256) void k_rowstats2(const f16* __restrict__ qT,
                                                   float* __restrict__ rmax,
                                                   float* __restrict__ rsum)
{
  const int b = blockIdx.y, n0 = blockIdx.x*64;
  const int tid = threadIdx.x, lane = tid & 63, w = tid >> 6;
  const int lr = lane & 15, lg = lane >> 4;
  const f16* qb = qT + (long)b*NPT*32;
  const f16x8 bfr = *(const f16x8*)(qb + (long)(n0 + w*16 + lr)*32 + lg*8);
  float mx = -1e30f, sm = 0.f;
  for (int m0=0; m0<NPT; m0+=32){
    f16x8 af0 = *(const f16x8*)(qb + (long)(m0+lr)*32 + lg*8);
    f16x8 af1 = *(const f16x8*)(qb + (long)(m0+16+lr)*32 + lg*8);
    f32x4 e0 = mfma16(af0, bfr, (f32x4){0,0,0,0});
    f32x4 e1 = mfma16(af1, bfr, (f32x4){0,0,0,0});
    float t0 = fmaxf(fmaxf(e0[0],e0[1]), fmaxf(e0[2],e0[3]));
    float t1 = fmaxf(fmaxf(e1[0],e1[1]), fmaxf(e1[2],e1[3]));
    float nm = fmaxf(mx, fmaxf(t0, t1));
    sm *= __expf(mx - nm);
    mx = nm;
    sm += __expf(e0[0]-mx) + __expf(e0[1]-mx) + __expf(e0[2]-mx) + __expf(e0[3]-mx)
        + __expf(e1[0]-mx) + __expf(e1[1]-mx) + __expf(e1[2]-mx) + __expf(e1[3]-mx);
  }
  #pragma unroll
  for (int d=16; d<64; d<<=1){
    float omx = __shfl_xor(mx, d, 64);
    float osm = __shfl_xor(sm, d, 64);
    float nm = fmaxf(mx, omx);
    sm = sm*__expf(mx-nm) + osm*__expf(omx-nm);
    mx = nm;
  }
  if (lane < 16){
    rmax[(long)b*NPT + n0 + w*16 + lr] = mx;
    rsum[(long)b*NPT + n0 + w*16 + lr] = sm;
  }
}

// ---------------------------------------------------------------------------
// pass2 PARTIAL [round-14 proven kernel, 64-m blocks, 2-deep pipelined V
// staging, one barrier/tile, ones-MFMA colsum]. NSEG=2: segment = 1024 n.
// grid (32, NSEG, B) = 1024 blocks = exactly 4 blocks/CU.
//   xrpart[(b*NSEG+seg)][m][c] = sum_n p[n,m] v[c,n]   (f16 raw)
//   cspart[(b*NSEG+seg)*NPT + m] = sum_n p[n,m]        (fp32)
// ---------------------------------------------------------------------------
__global__ __launch_bounds__(256) void k_pass2p(const f16* __restrict__ qT,
                                                const f16* __restrict__ v16,
                                                const float* __restrict__ rmax,
                                                const float* __restrict__ rsum,
                                                f16* __restrict__ xrpart,
                                                float* __restrict__ cspart)
{
  __shared__ __align__(16) f16 ps[64][40];      // pT[m][n-tile]; rows wave-private
  __shared__ __align__(16) f16 vs[2][128][40];  // double-buffered v-tile [c][n-tile]
  const int b = blockIdx.z, seg = blockIdx.y, m0 = blockIdx.x*64;
  const int tid = threadIdx.x, lane = tid & 63, w = tid >> 6;
  const int lr = lane & 15, lg = lane >> 4;
  const f16* qb = qT + (long)b*NPT*32;
  const f16* vb = v16 + (long)b*128*NPT;
  const float* rmx = rmax + (long)b*NPT;
  const float* rsm = rsum + (long)b*NPT;
  const f16x8 afe = *(const f16x8*)(qb + (long)(m0 + w*16 + lr)*32 + lg*8);  // E A-frag (rows m)
  f16x8 ones;
  #pragma unroll
  for (int j=0;j<8;++j) ones[j] = (f16)1.0f;
  f32x4 acc[8];
  #pragma unroll
  for (int cg=0; cg<8; ++cg) acc[cg] = (f32x4){0,0,0,0};
  f32x4 acc_cs = (f32x4){0,0,0,0};

  const int ntBeg = seg*(NPT/NSEG), ntEnd = ntBeg + NPT/NSEG;
  // prologue: stage first tile into vs[0]
  #pragma unroll
  for (int g = tid; g < 512; g += 256){
    int c = g>>2, s = g&3;
    *(float4*)&vs[0][c][s*8] = *(const float4*)(vb + (long)c*NPT + ntBeg + s*8);
  }
  __syncthreads();
  int cur = 0;

  for (int nt=ntBeg; nt<ntEnd; nt+=32){
    // issue next tile's staging into vs[cur^1] (loads fly under E+PV compute)
    if (nt + 32 < ntEnd){
      #pragma unroll
      for (int g = tid; g < 512; g += 256){
        int c = g>>2, s = g&3;
        *(float4*)&vs[cur^1][c][s*8] = *(const float4*)(vb + (long)c*NPT + nt + 32 + s*8);
      }
    }
    // E phase: 2 col-groups; lane col n fixed, 4 m-rows (ps wave-private)
    #pragma unroll
    for (int ng=0; ng<2; ++ng){
      f16x8 bfe = *(const f16x8*)(qb + (long)(nt + ng*16 + lr)*32 + lg*8);
      f32x4 e = mfma16(afe, bfe, (f32x4){0,0,0,0});
      const int n = nt + ng*16 + lr;
      const float rm = rmx[n];
      const float irs = 1.f / rsm[n];
      #pragma unroll
      for (int i=0;i<4;++i){
        float p = __expf(e[i] - rm) * irs;
        ps[w*16 + lg*4 + i][ng*16 + lr] = (f16)p;
      }
    }
    // PV phase: A = pT rows m (wave-private), B = current v-tile
    f16x8 ap = *(const f16x8*)&ps[w*16 + lr][lg*8];
    #pragma unroll
    for (int cg=0; cg<8; ++cg){
      f16x8 bp = *(const f16x8*)&vs[cur][cg*16 + lr][lg*8];
      acc[cg] = mfma16(ap, bp, acc[cg]);
    }
    acc_cs = mfma16(ap, ones, acc_cs);   // colsum on matrix pipe
    __syncthreads();                      // drains staging; protects vs[cur] reuse
    cur ^= 1;
  }
  const long row = (long)(b*NSEG + seg);
  // acc_cs[i] = cs[m0 + w*16 + lg*4 + i], duplicated across lr
  if (lr == 0){
    #pragma unroll
    for (int i=0;i<4;++i)
      cspart[row*NPT + m0 + w*16 + lg*4 + i] = acc_cs[i];
  }
  // raw partial store (no renorm)
  f16* xb = xrpart + row*NPT*128;
  #pragma unroll
  for (int cg=0; cg<8; ++cg)
    #pragma unroll
    for (int i=0;i<4;++i)
      xb[(long)(m0 + w*16 + lg*4 + i)*128 + cg*16 + lr] = (f16)acc[cg][i];
}

// ---------------------------------------------------------------------------
// merge NSEG partials: xrT[b][m][c] = (sum_s xrpart)/(1e-9 + sum_s cspart)
// ---------------------------------------------------------------------------
__global__ __launch_bounds__(256) void k_pmerge(const f16* __restrict__ xrpart,
                                                const float* __restrict__ cspart,
                                                f16* __restrict__ xrT)
{
  const long idx = (long)blockIdx.x*256 + threadIdx.x;   // 0..524287
  const long gm = idx >> 4;          // b*2048 + m
  const int  c0 = (int)(idx & 15) * 8;
  const long b = gm >> 11, m = gm & 2047;
  const long r0 = (b*NSEG) * (long)NPT + m;              // row base in [B*NSEG][NPT]
  float cs = 0.f;
  #pragma unroll
  for (int s=0;s<NSEG;++s) cs += cspart[r0 + (long)s*NPT];
  const float inv = 1.f/(1e-9f + cs);
  float a8[8];
  #pragma unroll
  for (int j=0;j<8;++j) a8[j] = 0.f;
  #pragma unroll
  for (int s=0;s<NSEG;++s){
    f16x8 v = *(const f16x8*)(xrpart + (r0 + (long)s*NPT)*128 + c0);
    #pragma unroll
    for (int j=0;j<8;++j) a8[j] += (float)v[j];
  }
  f16x8 ov;
  #pragma unroll
  for (int j=0;j<8;++j) ov[j] = (f16)(a8[j]*inv);
  *(f16x8*)(xrT + gm*128 + c0) = ov;
}

// ---------------------------------------------------------------------------
// xT = prev + lfT (fp16 vector add)
// ---------------------------------------------------------------------------
__global__ __launch_bounds__(256) void k_addT(const f16* __restrict__ prev, int prs, int pcol,
                                              const f16* __restrict__ lfT,
                                              f16* __restrict__ xT)
{
  long idx = (long)blockIdx.x*256 + threadIdx.x;
  long bn = idx >> 4; int c8 = (int)(idx & 15);
  f16x8 a = *(const f16x8*)(prev + bn*prs + pcol + c8*8);
  f16x8 l = *(const f16x8*)(lfT + bn*128 + c8*8);
  *(f16x8*)(xT + bn*128 + c8*8) = a + l;
}

// ---------------------------------------------------------------------------
// gmax over n per (b,c)
// ---------------------------------------------------------------------------
__global__ __launch_bounds__(1024) void k_gmaxT(const f16* __restrict__ lfT,
                                                float* __restrict__ gmaxv)
{
  __shared__ float red[8][128];
  const int b = blockIdx.x;
  const int c = threadIdx.x & 127, h = threadIdx.x >> 7;
  const f16* p = lfT + (long)b*NPT*128;
  float m = -1e30f;
  for (int n = h*256; n < (h+1)*256; ++n) m = fmaxf(m, (float)p[(long)n*128 + c]);
  red[h][c] = m; __syncthreads();
  if (threadIdx.x < 128){
    float mm = red[0][c];
    #pragma unroll
    for (int j=1;j<8;++j) mm = fmaxf(mm, red[j][c]);
    gmaxv[b*128 + c] = mm;
  }
}

__global__ __launch_bounds__(128) void k_gvec(const float* __restrict__ w0,
                                              const float* __restrict__ b0,
                                              const float* __restrict__ gmaxv,
                                              float* __restrict__ gc)
{
  const int b = blockIdx.x, o = threadIdx.x;
  __shared__ float g[128];
  g[o] = gmaxv[b*128+o]; __syncthreads();
  float acc = b0[o];
  for (int c = 0; c < 128; ++c) acc = fmaf(w0[o*256 + 128 + c], g[c], acc);
  gc[b*128+o] = acc;
}

// ---------------------------------------------------------------------------
// SA epilogue GEMM
// ---------------------------------------------------------------------------
__global__ __launch_bounds__(256) void k_safin(
    const f16* __restrict__ Wt, const float* __restrict__ bt,
    const float* __restrict__ g, const float* __restrict__ be,
    const f16* __restrict__ xT, const f16* __restrict__ xrT,
    f16* __restrict__ cat, int Lcol)
{
  __shared__ __align__(16) f16 Xs[64][72];
  __shared__ __align__(16) f16 Wsh[64][72];
  const int b  = blockIdx.z;
  const int n0 = blockIdx.x * 64;
  const int o0 = blockIdx.y * 64;
  const int tid = threadIdx.x, lane = tid & 63, w = tid >> 6;
  const int lr = lane & 15, lg = lane >> 4;
  const int wn = w>>1, wo = w&1;
  const f16* xb  = xT  + (long)b*NPT*128;
  const f16* xrb = xrT + (long)b*NPT*128;
  f32x4 acc[2][2];
  #pragma unroll
  for (int ni=0;ni<2;++ni){ acc[ni][0]=(f32x4){0,0,0,0}; acc[ni][1]=(f32x4){0,0,0,0}; }

  for (int k0=0; k0<128; k0+=64){
    #pragma unroll
    for (int gidx = tid; gidx < 512; gidx += 256){
      int r = gidx>>3, s = gidx&7;
      f16x8 xa = *(const f16x8*)(xb  + (long)(n0+r)*128 + k0 + s*8);
      f16x8 xr = *(const f16x8*)(xrb + (long)(n0+r)*128 + k0 + s*8);
      *(f16x8*)&Xs[r][s*8] = xa - xr;
      *(float4*)&Wsh[r][s*8] = *(const float4*)(Wt + (long)(o0+r)*128 + k0 + s*8);
    }
    __syncthreads();
    #pragma unroll
    for (int ks=0; ks<2; ++ks){
      f16x8 a[2], bf[2];
      #pragma unroll
      for (int ni=0;ni<2;++ni) a[ni] = *(const f16x8*)&Xs[wn*32 + ni*16 + lr][ks*32 + lg*8];
      #pragma unroll
      for (int oi=0;oi<2;++oi) bf[oi] = *(const f16x8*)&Wsh[wo*32 + oi*16 + lr][ks*32 + lg*8];
      #pragma unroll
      for (int ni=0;ni<2;++ni)
        #pragma unroll
        for (int oi=0;oi<2;++oi) acc[ni][oi] = mfma16(a[ni], bf[oi], acc[ni][oi]);
    }
    __syncthreads();
  }
  const float bnsc = rsqrtf(1.f + 1e-5f);
  #pragma unroll
  for (int ni=0;ni<2;++ni)
    #pragma unroll
    for (int oi=0;oi<2;++oi){
      const int oc = o0 + wo*32 + oi*16 + lr;
      const float bti = bt[oc], gi = g[oc]*bnsc, bei = be[oc];
      #pragma unroll
      for (int i=0;i<4;++i){
        const int nn = n0 + wn*32 + ni*16 + lg*4 + i;
        float t = acc[ni][oi][i] + bti;
        float val = fmaxf(fmaf(gi, t, bei), 0.f);
        float res = (float)xb[(long)nn*128 + oc];
        cat[(long)b*NPT*384 + (long)nn*384 + Lcol + oc] = (f16)(res + val);
      }
    }
}

__global__ __launch_bounds__(256) void k_maxfinal(const float* __restrict__ part,
                                                  float* __restrict__ out)
{
  const int t = blockIdx.x*256 + threadIdx.x;   // 0..16383
  float m = -1e30f;
  #pragma unroll
  for (int j=0;j<16;++j) m = fmaxf(m, part[(long)t*16 + j]);
  out[t] = m;
}

// ---------------------------------------------------------------------------
extern "C" void kernel_launch(void* const* d_in, const int* in_sizes, int n_in,
                              void* d_out, int out_size, void* d_ws, size_t ws_size,
                              hipStream_t stream)
{
  const float* in   = (const float*)d_in[0];
  const float* m1w0 = (const float*)d_in[1];
  const float* m1b0 = (const float*)d_in[2];
  const float* m1w1 = (const float*)d_in[3];
  const float* m1b1 = (const float*)d_in[4];
  const float* m2w0 = (const float*)d_in[5];
  const float* m2b0 = (const float*)d_in[6];
  const float* m2w1 = (const float*)d_in[7];
  const float* m2b1 = (const float*)d_in[8];
  const float* m3w0 = (const float*)d_in[9];
  const float* m3b0 = (const float*)d_in[10];
  const float* m3w1 = (const float*)d_in[11];
  const float* m3b1 = (const float*)d_in[12];

  // ws layout (halfs)
  f16* ws16 = (f16*)d_ws;
  f16* W16  = ws16;                       // 880,640
  f16* lfT  = ws16 + 880640;              // [B][N][128]
  f16* xT   = ws16 + 5074944;             // [B][N][128]
  f16* qT   = ws16 + 9269248;             // [B][N][32]
  f16* vbuf = ws16 + 10317824;            // [B][128][N]
  f16* xrT  = ws16 + 14512128;            // [B][N][128] (also mlp2 features)
  f16* hT   = ws16 + 18706432;            // [B][N][512] (mlp hidden)
  f16* xrpart = hT;                       // [B*NSEG][N][128] — aliases hT (dead during SA)
  f16* catT = ws16 + 35483648;            // [B][N][384]
  float* fb = (float*)(ws16 + 48066560);
  float* rmaxp  = fb;                     // [B,N]
  float* rsump  = fb + 32768;             // [B,N]
  float* gmaxv  = fb + 65536;             // [B,128]
  float* gc     = fb + 67584;             // [B,128]
  float* part   = fb + 69632;             // [B,1024,16]
  float* cspart = fb + 593920;            // [B*NSEG][N]

  const dim3 blk(256);

  k_wconv<<<dim3((WTOT+255)/256), blk, 0, stream>>>(
      m1w1, m2w0, m2w1, m3w0, m3w1,
      (const float*)d_in[13], (const float*)d_in[14], (const float*)d_in[16],
      (const float*)d_in[20], (const float*)d_in[21], (const float*)d_in[23],
      (const float*)d_in[27], (const float*)d_in[28], (const float*)d_in[30],
      W16);

  // mlp1
  k_mlp1aT<<<dim3(NBAT*NPT*32/256), blk, 0, stream>>>(in, m1w0, m1b0, hT);
  gemmT<64,false,false><<<dim3(32,2,NBAT), blk, 0, stream>>>(
      W16+OFF_M1W1, m1b1, nullptr, hT, 128, lfT, 128, 0, 128);
  // global max + mlp2
  k_gmaxT<<<dim3(NBAT), dim3(1024), 0, stream>>>(lfT, gmaxv);
  k_gvec<<<dim3(NBAT), dim3(128), 0, stream>>>(m2w0, m2b0, gmaxv, gc);
  gemmT<64,true,true><<<dim3(32,2,NBAT), blk, 0, stream>>>(
      W16+OFF_M2W0A, nullptr, gc, lfT, 128, hT, 128, 0, 128);
  gemmT<64,false,false><<<dim3(32,2,NBAT), blk, 0, stream>>>(
      W16+OFF_M2W1, m2b1, nullptr, hT, 128, xrT, 128, 0, 128);   // features -> xrT

  // 3 SA layers
  for (int L = 0; L < 3; ++L){
    const float* bv = (const float*)d_in[13 + L*7 + 2];
    const float* bt = (const float*)d_in[13 + L*7 + 4];
    const float* gg = (const float*)d_in[13 + L*7 + 5];
    const float* be = (const float*)d_in[13 + L*7 + 6];
    const f16* wq16 = W16 + OFF_SA + L*SA_STRIDE;
    const f16* wv16 = wq16 + 4096;
    const f16* wt16 = wq16 + 20480;

    const f16* prev = (L==0) ? xrT : (catT + (long)(L-1)*128);
    const int  prs  = (L==0) ? 128 : 384;
    k_addT<<<dim3(NBAT*NPT*16/256), blk, 0, stream>>>(prev, prs, 0, lfT, xT);

    gemmT<32,false,false><<<dim3(32,1,NBAT), blk, 0, stream>>>(
        wq16, nullptr, nullptr, xT, 128, qT, 32, 0, 128);
    vgemm<<<dim3(32,2,NBAT), blk, 0, stream>>>(wv16, bv, xT, vbuf);
    k_rowstats2<<<dim3(32,NBAT), blk, 0, stream>>>(qT, rmaxp, rsump);
    k_pass2p<<<dim3(32,NSEG,NBAT), blk, 0, stream>>>(qT, vbuf, rmaxp, rsump, xrpart, cspart);
    k_pmerge<<<dim3(2048), blk, 0, stream>>>(xrpart, cspart, xrT);
    k_safin<<<dim3(32,2,NBAT), blk, 0, stream>>>(wt16, bt, gg, be, xT, xrT, catT, L*128);
  }

  // mlp3: layer0 (384->512 relu) 128x128 tile, layer1 fused-max 128x128
  gemm128<true><<<dim3(16,4,NBAT), blk, 0, stream>>>(
      W16+OFF_M3W0, m3b0, catT, 384, hT, 512, 384);
  k_gemmax128<<<dim3(16,8,NBAT), blk, 0, stream>>>(W16+OFF_M3W1, m3b1, hT, part);
  k_maxfinal<<<dim3(64), blk, 0, stream>>>(part, (float*)d_out);
}

// Round 17
// 463.555 us; speedup vs baseline: 1.0867x; 1.0650x over previous
//
#include <hip/hip_runtime.h>
#include <hip/hip_bf16.h>
#include <cfloat>

static constexpr int NBAT = 16;
static constexpr int NPT  = 2048;
static constexpr int NSEG = 2;     // pass2 n-split segments

typedef _Float16 f16;
typedef _Float16 f16x8 __attribute__((ext_vector_type(8)));
typedef float    f32x4 __attribute__((ext_vector_type(4)));

static __device__ __forceinline__ f32x4 mfma16(f16x8 a, f16x8 b, f32x4 c){
  return __builtin_amdgcn_mfma_f32_16x16x32_f16(a, b, c, 0, 0, 0);
}
// MFMA 16x16x32 f16 layouts (gfx950, e2e-verified by round-4 pass):
//  A[16r x 32k]: lane l -> row l&15, k = (l>>4)*8 + j (16B contiguous)
//  B[32k x 16c]: lane l -> col l&15, k = (l>>4)*8 + j (16B contiguous)
//  D[16r x 16c]: lane l -> col l&15, rows (l>>4)*4 + i

// ---- weight arena offsets (halfs) ----
static constexpr long OFF_M1W1 = 0;              // [128][128]
static constexpr long OFF_M2W0A= 16384;          // [128][128] (cols 0..127 of [128][256])
static constexpr long OFF_M2W1 = 32768;          // [128][128]
static constexpr long OFF_M3W0 = 49152;          // [512][384]
static constexpr long OFF_M3W1 = 245760;         // [1024][512]
static constexpr long OFF_SA   = 770048;         // per-L: wq[32][128], wv[128][128], wt[128][128]
static constexpr long SA_STRIDE= 36864;
static constexpr long WTOT     = OFF_SA + 3*SA_STRIDE;   // 880,640 halfs

// ---------------------------------------------------------------------------
// weight fp32 -> fp16 conversion into arena (one launch)
// ---------------------------------------------------------------------------
__global__ __launch_bounds__(256) void k_wconv(
    const float* m1w1, const float* m2w0, const float* m2w1,
    const float* m3w0, const float* m3w1,
    const float* wq0, const float* wv0, const float* wt0,
    const float* wq1, const float* wv1, const float* wt1,
    const float* wq2, const float* wv2, const float* wt2,
    f16* W)
{
  long t = (long)blockIdx.x*256 + threadIdx.x;
  if (t >= WTOT) return;
  float v;
  if      (t < OFF_M2W0A) v = m1w1[t];
  else if (t < OFF_M2W1) { long u = t-OFF_M2W0A; v = m2w0[(u>>7)*256 + (u&127)]; }
  else if (t < OFF_M3W0)  v = m2w1[t-OFF_M2W1];
  else if (t < OFF_M3W1)  v = m3w0[t-OFF_M3W0];
  else if (t < OFF_SA)    v = m3w1[t-OFF_M3W1];
  else {
    long u = t - OFF_SA; int L = (int)(u / SA_STRIDE); long r = u % SA_STRIDE;
    const float* wq = (L==0)?wq0:(L==1)?wq1:wq2;
    const float* wv = (L==0)?wv0:(L==1)?wv1:wv2;
    const float* wt = (L==0)?wt0:(L==1)?wt1:wt2;
    if (r < 4096) v = wq[r]; else if (r < 20480) v = wv[r-4096]; else v = wt[r-20480];
  }
  W[t] = (f16)v;
}

// ---------------------------------------------------------------------------
// mlp1 layer0 (K=3): h1T[b][n][o] = relu(b0[o] + sum_c w0[o][c]*in[b][n][c])
// ---------------------------------------------------------------------------
__global__ __launch_bounds__(256) void k_mlp1aT(const float* __restrict__ in,
                                                const float* __restrict__ w0,
                                                const float* __restrict__ b0,
                                                f16* __restrict__ h1T)
{
  long idx = (long)blockIdx.x*256 + threadIdx.x;
  int og = idx & 31; long bn = idx >> 5;
  const float* ip = in + bn*3;
  float x0=ip[0], x1=ip[1], x2=ip[2];
  f16* op = h1T + bn*128 + og*4;
  #pragma unroll
  for (int i=0;i<4;++i){
    int o = og*4+i;
    float v = b0[o] + w0[o*3]*x0 + w0[o*3+1]*x1 + w0[o*3+2]*x2;
    op[i] = (f16)fmaxf(v, 0.f);
  }
}

// ---------------------------------------------------------------------------
// generic transposed conv GEMM: OUTT[b][n][ocol+o] = act(bias + sum_k XT[b][n][k]*W[o][k])
// ---------------------------------------------------------------------------
template<int OT, bool RELU, bool B2D>
__global__ __launch_bounds__(256) void gemmT(
    const f16* __restrict__ W, const float* __restrict__ bias,
    const float* __restrict__ bias2d,
    const f16* __restrict__ XT, int xrs,
    f16* __restrict__ OUT, int ors, int ocol, int K)
{
  __shared__ __align__(16) f16 Xs[64][72];
  __shared__ __align__(16) f16 Wsh[OT][72];
  const int b  = blockIdx.z;
  const int n0 = blockIdx.x * 64;
  const int o0 = blockIdx.y * OT;
  const int tid = threadIdx.x, lane = tid & 63, w = tid >> 6;
  const int lr = lane & 15, lg = lane >> 4;
  constexpr int NSUB = (OT==64)?2:1;
  const int wn = (OT==64)? (w>>1) : w;
  const int wo = (OT==64)? (w&1) : 0;
  const int nbase = wn*(16*NSUB);
  const f16* Xb = XT + (long)b*NPT*xrs;
  f32x4 acc[NSUB][2];
  #pragma unroll
  for (int ni=0;ni<NSUB;++ni){ acc[ni][0]=(f32x4){0,0,0,0}; acc[ni][1]=(f32x4){0,0,0,0}; }

  for (int k0=0; k0<K; k0+=64){
    #pragma unroll
    for (int g = tid; g < 512; g += 256){
      int r = g>>3, s = g&7;
      *(float4*)&Xs[r][s*8] = *(const float4*)(Xb + (long)(n0+r)*xrs + k0 + s*8);
    }
    for (int g = tid; g < OT*8; g += 256){
      int r = g>>3, s = g&7;
      *(float4*)&Wsh[r][s*8] = *(const float4*)(W + (long)(o0+r)*K + k0 + s*8);
    }
    __syncthreads();
    #pragma unroll
    for (int ks=0; ks<2; ++ks){
      f16x8 a[NSUB], bf[2];
      #pragma unroll
      for (int ni=0;ni<NSUB;++ni) a[ni] = *(const f16x8*)&Xs[nbase + ni*16 + lr][ks*32 + lg*8];
      #pragma unroll
      for (int oi=0;oi<2;++oi)   bf[oi] = *(const f16x8*)&Wsh[wo*32 + oi*16 + lr][ks*32 + lg*8];
      #pragma unroll
      for (int ni=0;ni<NSUB;++ni)
        #pragma unroll
        for (int oi=0;oi<2;++oi) acc[ni][oi] = mfma16(a[ni], bf[oi], acc[ni][oi]);
    }
    __syncthreads();
  }
  #pragma unroll
  for (int ni=0;ni<NSUB;++ni)
    #pragma unroll
    for (int oi=0;oi<2;++oi){
      const int oc = o0 + wo*32 + oi*16 + lr;
      float bi = bias ? bias[oc] : 0.f;
      if constexpr (B2D) bi += bias2d[b*128 + oc];
      #pragma unroll
      for (int i=0;i<4;++i){
        const int nn = n0 + nbase + ni*16 + lg*4 + i;
        float v = acc[ni][oi][i] + bi;
        if constexpr (RELU) v = fmaxf(v, 0.f);
        OUT[(long)b*NPT*ors + (long)nn*ors + ocol + oc] = (f16)v;
      }
    }
}

// ---------------------------------------------------------------------------
// 128x128-tile GEMM (4 waves as 2x2, each wave 64x64, acc[4][4]):
// __launch_bounds__(256,4): cap regs at 128/thread -> 4 blocks/CU.
// ---------------------------------------------------------------------------
template<bool RELU>
__global__ __launch_bounds__(256, 4) void gemm128(
    const f16* __restrict__ W, const float* __restrict__ bias,
    const f16* __restrict__ XT, int xrs,
    f16* __restrict__ OUT, int ors, int K)
{
  __shared__ __align__(16) f16 Xs[128][72];
  __shared__ __align__(16) f16 Wsh[128][72];
  const int b  = blockIdx.z;
  const int n0 = blockIdx.x * 128;
  const int o0 = blockIdx.y * 128;
  const int tid = threadIdx.x, lane = tid & 63, w = tid >> 6;
  const int lr = lane & 15, lg = lane >> 4;
  const int wn = w >> 1, wo = w & 1;
  const f16* Xb = XT + (long)b*NPT*xrs;
  f32x4 acc[4][4];
  #pragma unroll
  for (int ni=0;ni<4;++ni)
    #pragma unroll
    for (int oi=0;oi<4;++oi) acc[ni][oi] = (f32x4){0,0,0,0};

  for (int k0=0; k0<K; k0+=64){
    #pragma unroll
    for (int g = tid; g < 1024; g += 256){
      int r = g>>3, s = g&7;
      *(float4*)&Xs[r][s*8]  = *(const float4*)(Xb + (long)(n0+r)*xrs + k0 + s*8);
      *(float4*)&Wsh[r][s*8] = *(const float4*)(W + (long)(o0+r)*K + k0 + s*8);
    }
    __syncthreads();
    #pragma unroll
    for (int ks=0; ks<2; ++ks){
      f16x8 a[4], bf[4];
      #pragma unroll
      for (int ni=0;ni<4;++ni) a[ni]  = *(const f16x8*)&Xs[wn*64 + ni*16 + lr][ks*32 + lg*8];
      #pragma unroll
      for (int oi=0;oi<4;++oi) bf[oi] = *(const f16x8*)&Wsh[wo*64 + oi*16 + lr][ks*32 + lg*8];
      #pragma unroll
      for (int ni=0;ni<4;++ni)
        #pragma unroll
        for (int oi=0;oi<4;++oi) acc[ni][oi] = mfma16(a[ni], bf[oi], acc[ni][oi]);
    }
    __syncthreads();
  }
  #pragma unroll
  for (int ni=0;ni<4;++ni)
    #pragma unroll
    for (int oi=0;oi<4;++oi){
      const int oc = o0 + wo*64 + oi*16 + lr;
      const float bi = bias[oc];
      #pragma unroll
      for (int i=0;i<4;++i){
        const int nn = n0 + wn*64 + ni*16 + lg*4 + i;
        float v = acc[ni][oi][i] + bi;
        if constexpr (RELU) v = fmaxf(v, 0.f);
        OUT[(long)b*NPT*ors + (long)nn*ors + oc] = (f16)v;
      }
    }
}

// ---------------------------------------------------------------------------
// mlp3 layer1 with fused max, 128x128 tile. grid (16, 8, B). K=512.
// ---------------------------------------------------------------------------
__global__ __launch_bounds__(256, 4) void k_gemmax128(
    const f16* __restrict__ W, const float* __restrict__ bias,
    const f16* __restrict__ XT, float* __restrict__ part)
{
  __shared__ __align__(16) f16 Xs[128][72];
  __shared__ __align__(16) f16 Wsh[128][72];
  __shared__ float red[2][128];
  const int b  = blockIdx.z;
  const int n0 = blockIdx.x * 128;
  const int o0 = blockIdx.y * 128;
  const int tid = threadIdx.x, lane = tid & 63, w = tid >> 6;
  const int lr = lane & 15, lg = lane >> 4;
  const int wn = w >> 1, wo = w & 1;
  const f16* Xb = XT + (long)b*NPT*512;
  f32x4 acc[4][4];
  #pragma unroll
  for (int ni=0;ni<4;++ni)
    #pragma unroll
    for (int oi=0;oi<4;++oi) acc[ni][oi] = (f32x4){0,0,0,0};

  for (int k0=0; k0<512; k0+=64){
    #pragma unroll
    for (int g = tid; g < 1024; g += 256){
      int r = g>>3, s = g&7;
      *(float4*)&Xs[r][s*8]  = *(const float4*)(Xb + (long)(n0+r)*512 + k0 + s*8);
      *(float4*)&Wsh[r][s*8] = *(const float4*)(W + (long)(o0+r)*512 + k0 + s*8);
    }
    __syncthreads();
    #pragma unroll
    for (int ks=0; ks<2; ++ks){
      f16x8 a[4], bf[4];
      #pragma unroll
      for (int ni=0;ni<4;++ni) a[ni]  = *(const f16x8*)&Xs[wn*64 + ni*16 + lr][ks*32 + lg*8];
      #pragma unroll
      for (int oi=0;oi<4;++oi) bf[oi] = *(const f16x8*)&Wsh[wo*64 + oi*16 + lr][ks*32 + lg*8];
      #pragma unroll
      for (int ni=0;ni<4;++ni)
        #pragma unroll
        for (int oi=0;oi<4;++oi) acc[ni][oi] = mfma16(a[ni], bf[oi], acc[ni][oi]);
    }
    __syncthreads();
  }
  #pragma unroll
  for (int oi=0;oi<4;++oi){
    const int oc128 = wo*64 + oi*16 + lr;
    const float bi = bias[o0 + oc128];
    float mv = -1e30f;
    #pragma unroll
    for (int ni=0;ni<4;++ni)
      #pragma unroll
      for (int i=0;i<4;++i) mv = fmaxf(mv, acc[ni][oi][i] + bi);
    mv = fmaxf(mv, __shfl_xor(mv, 16, 64));
    mv = fmaxf(mv, __shfl_xor(mv, 32, 64));
    if (lg == 0) red[wn][oc128] = mv;
  }
  __syncthreads();
  if (tid < 128)
    part[((long)b*1024 + o0 + tid)*16 + blockIdx.x] = fmaxf(red[0][tid], red[1][tid]);
}

// ---------------------------------------------------------------------------
// FUSED q GEMM: x = prev + lfT computed in staging (k_addT folded in).
// qT[b][n][o] = sum_k x[n][k]*Wq[o][k].  grid (32, 1, B). K=128, OT=32.
// ---------------------------------------------------------------------------
__global__ __launch_bounds__(256) void k_qgemmF(
    const f16* __restrict__ W,
    const f16* __restrict__ prev, int prs,
    const f16* __restrict__ lfT,
    f16* __restrict__ qT)
{
  __shared__ __align__(16) f16 Xs[64][72];
  __shared__ __align__(16) f16 Wsh[32][72];
  const int b  = blockIdx.z;
  const int n0 = blockIdx.x * 64;
  const int tid = threadIdx.x, lane = tid & 63, w = tid >> 6;
  const int lr = lane & 15, lg = lane >> 4;
  f32x4 acc[2];
  acc[0] = (f32x4){0,0,0,0}; acc[1] = (f32x4){0,0,0,0};

  for (int k0=0; k0<128; k0+=64){
    #pragma unroll
    for (int g = tid; g < 512; g += 256){
      int r = g>>3, s = g&7;
      const long bn = (long)b*NPT + n0 + r;
      f16x8 xa = *(const f16x8*)(prev + bn*prs + k0 + s*8);
      f16x8 l  = *(const f16x8*)(lfT + bn*128 + k0 + s*8);
      *(f16x8*)&Xs[r][s*8] = xa + l;
    }
    for (int g = tid; g < 256; g += 256){
      int r = g>>3, s = g&7;
      *(float4*)&Wsh[r][s*8] = *(const float4*)(W + (long)r*128 + k0 + s*8);
    }
    __syncthreads();
    #pragma unroll
    for (int ks=0; ks<2; ++ks){
      f16x8 a = *(const f16x8*)&Xs[w*16 + lr][ks*32 + lg*8];
      #pragma unroll
      for (int oi=0;oi<2;++oi){
        f16x8 bf = *(const f16x8*)&Wsh[oi*16 + lr][ks*32 + lg*8];
        acc[oi] = mfma16(a, bf, acc[oi]);
      }
    }
    __syncthreads();
  }
  #pragma unroll
  for (int oi=0;oi<2;++oi){
    const int oc = oi*16 + lr;
    #pragma unroll
    for (int i=0;i<4;++i){
      const int nn = n0 + w*16 + lg*4 + i;
      qT[((long)b*NPT + nn)*32 + oc] = (f16)acc[oi][i];
    }
  }
}

// ---------------------------------------------------------------------------
// FUSED v GEMM: x = prev + lfT computed in staging; c0==0 blocks also
// write staged x back to xT (for safin). v16[b][c][n]. grid (32, 2, B).
// ---------------------------------------------------------------------------
__global__ __launch_bounds__(256) void k_vgemmF(
    const f16* __restrict__ Wv, const float* __restrict__ bv,
    const f16* __restrict__ prev, int prs,
    const f16* __restrict__ lfT,
    f16* __restrict__ v16, f16* __restrict__ xT)
{
  __shared__ __align__(16) f16 Xs[64][72];
  __shared__ __align__(16) f16 Wsh[64][72];
  const int b  = blockIdx.z;
  const int n0 = blockIdx.x * 64;
  const int c0 = blockIdx.y * 64;
  const int tid = threadIdx.x, lane = tid & 63, w = tid >> 6;
  const int lr = lane & 15, lg = lane >> 4;
  const int wc = w>>1, wn = w&1;
  f32x4 acc[2][2];
  #pragma unroll
  for (int ci=0;ci<2;++ci){ acc[ci][0]=(f32x4){0,0,0,0}; acc[ci][1]=(f32x4){0,0,0,0}; }

  for (int k0=0; k0<128; k0+=64){
    #pragma unroll
    for (int g = tid; g < 512; g += 256){
      int r = g>>3, s = g&7;
      const long bn = (long)b*NPT + n0 + r;
      f16x8 xa = *(const f16x8*)(prev + bn*prs + k0 + s*8);
      f16x8 l  = *(const f16x8*)(lfT + bn*128 + k0 + s*8);
      f16x8 xv = xa + l;
      *(f16x8*)&Xs[r][s*8] = xv;
      if (c0 == 0) *(f16x8*)(xT + bn*128 + k0 + s*8) = xv;   // materialize x for safin
      *(float4*)&Wsh[r][s*8] = *(const float4*)(Wv + (long)(c0+r)*128 + k0 + s*8);
    }
    __syncthreads();
    #pragma unroll
    for (int ks=0; ks<2; ++ks){
      f16x8 a[2], bf[2];
      #pragma unroll
      for (int ci=0;ci<2;++ci) a[ci] = *(const f16x8*)&Wsh[wc*32 + ci*16 + lr][ks*32 + lg*8];
      #pragma unroll
      for (int ni=0;ni<2;++ni) bf[ni] = *(const f16x8*)&Xs[wn*32 + ni*16 + lr][ks*32 + lg*8];
      #pragma unroll
      for (int ci=0;ci<2;++ci)
        #pragma unroll
        for (int ni=0;ni<2;++ni) acc[ci][ni] = mfma16(a[ci], bf[ni], acc[ci][ni]);
    }
    __syncthreads();
  }
  #pragma unroll
  for (int ci=0;ci<2;++ci)
    #pragma unroll
    for (int i=0;i<4;++i){
      const int c = c0 + wc*32 + ci*16 + lg*4 + i;
      const float bi = bv[c];
      #pragma unroll
      for (int ni=0;ni<2;++ni){
        const int n = n0 + wn*32 + ni*16 + lr;
        v16[(long)b*128*NPT + (long)c*NPT + n] = (f16)(acc[ci][ni][i] + bi);
      }
    }
}

// ---------------------------------------------------------------------------
// rowstats via MFMA: rmax/rsum over m of e[m,n] (symmetric e) per col n.
// ---------------------------------------------------------------------------
__global__ __launch_bounds__(256) void k_rowstats2(const f16* __restrict__ qT,
                                                   float* __restrict__ rmax,
                                                   float* __restrict__ rsum)
{
  const int b = blockIdx.y, n0 = blockIdx.x*64;
  const int tid = threadIdx.x, lane = tid & 63, w = tid >> 6;
  const int lr = lane & 15, lg = lane >> 4;
  const f16* qb = qT + (long)b*NPT*32;
  const f16x8 bfr = *(const f16x8*)(qb + (long)(n0 + w*16 + lr)*32 + lg*8);
  float mx = -1e30f, sm = 0.f;
  for (int m0=0; m0<NPT; m0+=32){
    f16x8 af0 = *(const f16x8*)(qb + (long)(m0+lr)*32 + lg*8);
    f16x8 af1 = *(const f16x8*)(qb + (long)(m0+16+lr)*32 + lg*8);
    f32x4 e0 = mfma16(af0, bfr, (f32x4){0,0,0,0});
    f32x4 e1 = mfma16(af1, bfr, (f32x4){0,0,0,0});
    float t0 = fmaxf(fmaxf(e0[0],e0[1]), fmaxf(e0[2],e0[3]));
    float t1 = fmaxf(fmaxf(e1[0],e1[1]), fmaxf(e1[2],e1[3]));
    float nm = fmaxf(mx, fmaxf(t0, t1));
    sm *= __expf(mx - nm);
    mx = nm;
    sm += __expf(e0[0]-mx) + __expf(e0[1]-mx) + __expf(e0[2]-mx) + __expf(e0[3]-mx)
        + __expf(e1[0]-mx) + __expf(e1[1]-mx) + __expf(e1[2]-mx) + __expf(e1[3]-mx);
  }
  #pragma unroll
  for (int d=16; d<64; d<<=1){
    float omx = __shfl_xor(mx, d, 64);
    float osm = __shfl_xor(sm, d, 64);
    float nm = fmaxf(mx, omx);
    sm = sm*__expf(mx-nm) + osm*__expf(omx-nm);
    mx = nm;
  }
  if (lane < 16){
    rmax[(long)b*NPT + n0 + w*16 + lr] = mx;
    rsum[(long)b*NPT + n0 + w*16 + lr] = sm;
  }
}

// ---------------------------------------------------------------------------
// pass2 PARTIAL [proven kernel: 64-m blocks, 2-deep pipelined V staging,
// one barrier/tile, ones-MFMA colsum]. NSEG=2. grid (32, NSEG, B).
//   xrpart[(b*NSEG+seg)][m][c] = sum_n p[n,m] v[c,n]   (f16 raw)
//   cspart[(b*NSEG+seg)*NPT + m] = sum_n p[n,m]        (fp32)
// ---------------------------------------------------------------------------
__global__ __launch_bounds__(256) void k_pass2p(const f16* __restrict__ qT,
                                                const f16* __restrict__ v16,
                                                const float* __restrict__ rmax,
                                                const float* __restrict__ rsum,
                                                f16* __restrict__ xrpart,
                                                float* __restrict__ cspart)
{
  __shared__ __align__(16) f16 ps[64][40];      // pT[m][n-tile]; rows wave-private
  __shared__ __align__(16) f16 vs[2][128][40];  // double-buffered v-tile [c][n-tile]
  const int b = blockIdx.z, seg = blockIdx.y, m0 = blockIdx.x*64;
  const int tid = threadIdx.x, lane = tid & 63, w = tid >> 6;
  const int lr = lane & 15, lg = lane >> 4;
  const f16* qb = qT + (long)b*NPT*32;
  const f16* vb = v16 + (long)b*128*NPT;
  const float* rmx = rmax + (long)b*NPT;
  const float* rsm = rsum + (long)b*NPT;
  const f16x8 afe = *(const f16x8*)(qb + (long)(m0 + w*16 + lr)*32 + lg*8);  // E A-frag (rows m)
  f16x8 ones;
  #pragma unroll
  for (int j=0;j<8;++j) ones[j] = (f16)1.0f;
  f32x4 acc[8];
  #pragma unroll
  for (int cg=0; cg<8; ++cg) acc[cg] = (f32x4){0,0,0,0};
  f32x4 acc_cs = (f32x4){0,0,0,0};

  const int ntBeg = seg*(NPT/NSEG), ntEnd = ntBeg + NPT/NSEG;
  // prologue: stage first tile into vs[0]
  #pragma unroll
  for (int g = tid; g < 512; g += 256){
    int c = g>>2, s = g&3;
    *(float4*)&vs[0][c][s*8] = *(const float4*)(vb + (long)c*NPT + ntBeg + s*8);
  }
  __syncthreads();
  int cur = 0;

  for (int nt=ntBeg; nt<ntEnd; nt+=32){
    // issue next tile's staging into vs[cur^1] (loads fly under E+PV compute)
    if (nt + 32 < ntEnd){
      #pragma unroll
      for (int g = tid; g < 512; g += 256){
        int c = g>>2, s = g&3;
        *(float4*)&vs[cur^1][c][s*8] = *(const float4*)(vb + (long)c*NPT + nt + 32 + s*8);
      }
    }
    // E phase: 2 col-groups; lane col n fixed, 4 m-rows (ps wave-private)
    #pragma unroll
    for (int ng=0; ng<2; ++ng){
      f16x8 bfe = *(const f16x8*)(qb + (long)(nt + ng*16 + lr)*32 + lg*8);
      f32x4 e = mfma16(afe, bfe, (f32x4){0,0,0,0});
      const int n = nt + ng*16 + lr;
      const float rm = rmx[n];
      const float irs = 1.f / rsm[n];
      #pragma unroll
      for (int i=0;i<4;++i){
        float p = __expf(e[i] - rm) * irs;
        ps[w*16 + lg*4 + i][ng*16 + lr] = (f16)p;
      }
    }
    // PV phase: A = pT rows m (wave-private), B = current v-tile
    f16x8 ap = *(const f16x8*)&ps[w*16 + lr][lg*8];
    #pragma unroll
    for (int cg=0; cg<8; ++cg){
      f16x8 bp = *(const f16x8*)&vs[cur][cg*16 + lr][lg*8];
      acc[cg] = mfma16(ap, bp, acc[cg]);
    }
    acc_cs = mfma16(ap, ones, acc_cs);   // colsum on matrix pipe
    __syncthreads();                      // drains staging; protects vs[cur] reuse
    cur ^= 1;
  }
  const long row = (long)(b*NSEG + seg);
  // acc_cs[i] = cs[m0 + w*16 + lg*4 + i], duplicated across lr
  if (lr == 0){
    #pragma unroll
    for (int i=0;i<4;++i)
      cspart[row*NPT + m0 + w*16 + lg*4 + i] = acc_cs[i];
  }
  // raw partial store (no renorm)
  f16* xb = xrpart + row*NPT*128;
  #pragma unroll
  for (int cg=0; cg<8; ++cg)
    #pragma unroll
    for (int i=0;i<4;++i)
      xb[(long)(m0 + w*16 + lg*4 + i)*128 + cg*16 + lr] = (f16)acc[cg][i];
}

// ---------------------------------------------------------------------------
// gmax over n per (b,c)
// ---------------------------------------------------------------------------
__global__ __launch_bounds__(1024) void k_gmaxT(const f16* __restrict__ lfT,
                                                float* __restrict__ gmaxv)
{
  __shared__ float red[8][128];
  const int b = blockIdx.x;
  const int c = threadIdx.x & 127, h = threadIdx.x >> 7;
  const f16* p = lfT + (long)b*NPT*128;
  float m = -1e30f;
  for (int n = h*256; n < (h+1)*256; ++n) m = fmaxf(m, (float)p[(long)n*128 + c]);
  red[h][c] = m; __syncthreads();
  if (threadIdx.x < 128){
    float mm = red[0][c];
    #pragma unroll
    for (int j=1;j<8;++j) mm = fmaxf(mm, red[j][c]);
    gmaxv[b*128 + c] = mm;
  }
}

__global__ __launch_bounds__(128) void k_gvec(const float* __restrict__ w0,
                                              const float* __restrict__ b0,
                                              const float* __restrict__ gmaxv,
                                              float* __restrict__ gc)
{
  const int b = blockIdx.x, o = threadIdx.x;
  __shared__ float g[128];
  g[o] = gmaxv[b*128+o]; __syncthreads();
  float acc = b0[o];
  for (int c = 0; c < 128; ++c) acc = fmaf(w0[o*256 + 128 + c], g[c], acc);
  gc[b*128+o] = acc;
}

// ---------------------------------------------------------------------------
// SA epilogue GEMM with FUSED partial merge (k_pmerge folded into staging):
// xr[n][c] = (p0+p1)*inv computed inline from xrpart/cspart (NSEG=2).
// cat[b][n][Lcol+o] = x[n][o] + relu(g'*(wt@(x-xr))+..). grid (32,2,B).
// ---------------------------------------------------------------------------
__global__ __launch_bounds__(256) void k_safin2(
    const f16* __restrict__ Wt, const float* __restrict__ bt,
    const float* __restrict__ g, const float* __restrict__ be,
    const f16* __restrict__ xT,
    const f16* __restrict__ xrpart, const float* __restrict__ cspart,
    f16* __restrict__ cat, int Lcol)
{
  __shared__ __align__(16) f16 Xs[64][72];
  __shared__ __align__(16) f16 Wsh[64][72];
  const int b  = blockIdx.z;
  const int n0 = blockIdx.x * 64;
  const int o0 = blockIdx.y * 64;
  const int tid = threadIdx.x, lane = tid & 63, w = tid >> 6;
  const int lr = lane & 15, lg = lane >> 4;
  const int wn = w>>1, wo = w&1;
  const f16* xb = xT + (long)b*NPT*128;
  f32x4 acc[2][2];
  #pragma unroll
  for (int ni=0;ni<2;++ni){ acc[ni][0]=(f32x4){0,0,0,0}; acc[ni][1]=(f32x4){0,0,0,0}; }

  for (int k0=0; k0<128; k0+=64){
    #pragma unroll
    for (int gidx = tid; gidx < 512; gidx += 256){
      int r = gidx>>3, s = gidx&7;
      const long nn = n0 + r;
      const long r0 = ((long)b*NSEG + 0)*NPT + nn;
      const long r1 = r0 + NPT;
      const float inv = 1.f/(1e-9f + cspart[r0] + cspart[r1]);
      f16x8 xa = *(const f16x8*)(xb + nn*128 + k0 + s*8);
      f16x8 p0 = *(const f16x8*)(xrpart + r0*128 + k0 + s*8);
      f16x8 p1 = *(const f16x8*)(xrpart + r1*128 + k0 + s*8);
      f16x8 xs;
      #pragma unroll
      for (int j=0;j<8;++j)
        xs[j] = (f16)((float)xa[j] - ((float)p0[j] + (float)p1[j]) * inv);
      *(f16x8*)&Xs[r][s*8] = xs;
      *(float4*)&Wsh[r][s*8] = *(const float4*)(Wt + (long)(o0+r)*128 + k0 + s*8);
    }
    __syncthreads();
    #pragma unroll
    for (int ks=0; ks<2; ++ks){
      f16x8 a[2], bf[2];
      #pragma unroll
      for (int ni=0;ni<2;++ni) a[ni] = *(const f16x8*)&Xs[wn*32 + ni*16 + lr][ks*32 + lg*8];
      #pragma unroll
      for (int oi=0;oi<2;++oi) bf[oi] = *(const f16x8*)&Wsh[wo*32 + oi*16 + lr][ks*32 + lg*8];
      #pragma unroll
      for (int ni=0;ni<2;++ni)
        #pragma unroll
        for (int oi=0;oi<2;++oi) acc[ni][oi] = mfma16(a[ni], bf[oi], acc[ni][oi]);
    }
    __syncthreads();
  }
  const float bnsc = rsqrtf(1.f + 1e-5f);
  #pragma unroll
  for (int ni=0;ni<2;++ni)
    #pragma unroll
    for (int oi=0;oi<2;++oi){
      const int oc = o0 + wo*32 + oi*16 + lr;
      const float bti = bt[oc], gi = g[oc]*bnsc, bei = be[oc];
      #pragma unroll
      for (int i=0;i<4;++i){
        const int nn = n0 + wn*32 + ni*16 + lg*4 + i;
        float t = acc[ni][oi][i] + bti;
        float val = fmaxf(fmaf(gi, t, bei), 0.f);
        float res = (float)xb[(long)nn*128 + oc];
        cat[(long)b*NPT*384 + (long)nn*384 + Lcol + oc] = (f16)(res + val);
      }
    }
}

__global__ __launch_bounds__(256) void k_maxfinal(const float* __restrict__ part,
                                                  float* __restrict__ out)
{
  const int t = blockIdx.x*256 + threadIdx.x;   // 0..16383
  float m = -1e30f;
  #pragma unroll
  for (int j=0;j<16;++j) m = fmaxf(m, part[(long)t*16 + j]);
  out[t] = m;
}

// ---------------------------------------------------------------------------
extern "C" void kernel_launch(void* const* d_in, const int* in_sizes, int n_in,
                              void* d_out, int out_size, void* d_ws, size_t ws_size,
                              hipStream_t stream)
{
  const float* in   = (const float*)d_in[0];
  const float* m1w0 = (const float*)d_in[1];
  const float* m1b0 = (const float*)d_in[2];
  const float* m1w1 = (const float*)d_in[3];
  const float* m1b1 = (const float*)d_in[4];
  const float* m2w0 = (const float*)d_in[5];
  const float* m2b0 = (const float*)d_in[6];
  const float* m2w1 = (const float*)d_in[7];
  const float* m2b1 = (const float*)d_in[8];
  const float* m3w0 = (const float*)d_in[9];
  const float* m3b0 = (const float*)d_in[10];
  const float* m3w1 = (const float*)d_in[11];
  const float* m3b1 = (const float*)d_in[12];

  // ws layout (halfs)
  f16* ws16 = (f16*)d_ws;
  f16* W16  = ws16;                       // 880,640
  f16* lfT  = ws16 + 880640;              // [B][N][128]
  f16* xT   = ws16 + 5074944;             // [B][N][128]
  f16* qT   = ws16 + 9269248;             // [B][N][32]
  f16* vbuf = ws16 + 10317824;            // [B][128][N]
  f16* xrT  = ws16 + 14512128;            // [B][N][128] (mlp2 features; never clobbered now)
  f16* hT   = ws16 + 18706432;            // [B][N][512] (mlp hidden)
  f16* xrpart = hT;                       // [B*NSEG][N][128] — aliases hT (dead during SA)
  f16* catT = ws16 + 35483648;            // [B][N][384]
  float* fb = (float*)(ws16 + 48066560);
  float* rmaxp  = fb;                     // [B,N]
  float* rsump  = fb + 32768;             // [B,N]
  float* gmaxv  = fb + 65536;             // [B,128]
  float* gc     = fb + 67584;             // [B,128]
  float* part   = fb + 69632;             // [B,1024,16]
  float* cspart = fb + 593920;            // [B*NSEG][N]

  const dim3 blk(256);

  k_wconv<<<dim3((WTOT+255)/256), blk, 0, stream>>>(
      m1w1, m2w0, m2w1, m3w0, m3w1,
      (const float*)d_in[13], (const float*)d_in[14], (const float*)d_in[16],
      (const float*)d_in[20], (const float*)d_in[21], (const float*)d_in[23],
      (const float*)d_in[27], (const float*)d_in[28], (const float*)d_in[30],
      W16);

  // mlp1
  k_mlp1aT<<<dim3(NBAT*NPT*32/256), blk, 0, stream>>>(in, m1w0, m1b0, hT);
  gemmT<64,false,false><<<dim3(32,2,NBAT), blk, 0, stream>>>(
      W16+OFF_M1W1, m1b1, nullptr, hT, 128, lfT, 128, 0, 128);
  // global max + mlp2
  k_gmaxT<<<dim3(NBAT), dim3(1024), 0, stream>>>(lfT, gmaxv);
  k_gvec<<<dim3(NBAT), dim3(128), 0, stream>>>(m2w0, m2b0, gmaxv, gc);
  gemmT<64,true,true><<<dim3(32,2,NBAT), blk, 0, stream>>>(
      W16+OFF_M2W0A, nullptr, gc, lfT, 128, hT, 128, 0, 128);
  gemmT<64,false,false><<<dim3(32,2,NBAT), blk, 0, stream>>>(
      W16+OFF_M2W1, m2b1, nullptr, hT, 128, xrT, 128, 0, 128);   // features -> xrT

  // 3 SA layers (addT and pmerge fused away)
  for (int L = 0; L < 3; ++L){
    const float* bv = (const float*)d_in[13 + L*7 + 2];
    const float* bt = (const float*)d_in[13 + L*7 + 4];
    const float* gg = (const float*)d_in[13 + L*7 + 5];
    const float* be = (const float*)d_in[13 + L*7 + 6];
    const f16* wq16 = W16 + OFF_SA + L*SA_STRIDE;
    const f16* wv16 = wq16 + 4096;
    const f16* wt16 = wq16 + 20480;

    const f16* prev = (L==0) ? xrT : (catT + (long)(L-1)*128);
    const int  prs  = (L==0) ? 128 : 384;

    k_qgemmF<<<dim3(32,1,NBAT), blk, 0, stream>>>(wq16, prev, prs, lfT, qT);
    k_vgemmF<<<dim3(32,2,NBAT), blk, 0, stream>>>(wv16, bv, prev, prs, lfT, vbuf, xT);
    k_rowstats2<<<dim3(32,NBAT), blk, 0, stream>>>(qT, rmaxp, rsump);
    k_pass2p<<<dim3(32,NSEG,NBAT), blk, 0, stream>>>(qT, vbuf, rmaxp, rsump, xrpart, cspart);
    k_safin2<<<dim3(32,2,NBAT), blk, 0, stream>>>(
        wt16, bt, gg, be, xT, xrpart, cspart, catT, L*128);
  }

  // mlp3: layer0 (384->512 relu) 128x128 tile, layer1 fused-max 128x128
  gemm128<true><<<dim3(16,4,NBAT), blk, 0, stream>>>(
      W16+OFF_M3W0, m3b0, catT, 384, hT, 512, 384);
  k_gemmax128<<<dim3(16,8,NBAT), blk, 0, stream>>>(W16+OFF_M3W1, m3b1, hT, part);
  k_maxfinal<<<dim3(64), blk, 0, stream>>>(part, (float*)d_out);
}

// Round 18
// 461.479 us; speedup vs baseline: 1.0916x; 1.0045x over previous
//
#include <hip/hip_runtime.h>
#include <hip/hip_bf16.h>
#include <cfloat>

static constexpr int NBAT = 16;
static constexpr int NPT  = 2048;
static constexpr int NSEG = 2;     // pass2 n-split segments

typedef _Float16 f16;
typedef _Float16 f16x8 __attribute__((ext_vector_type(8)));
typedef float    f32x4 __attribute__((ext_vector_type(4)));

static __device__ __forceinline__ f32x4 mfma16(f16x8 a, f16x8 b, f32x4 c){
  return __builtin_amdgcn_mfma_f32_16x16x32_f16(a, b, c, 0, 0, 0);
}
// MFMA 16x16x32 f16 layouts (gfx950, e2e-verified by round-4 pass):
//  A[16r x 32k]: lane l -> row l&15, k = (l>>4)*8 + j (16B contiguous)
//  B[32k x 16c]: lane l -> col l&15, k = (l>>4)*8 + j (16B contiguous)
//  D[16r x 16c]: lane l -> col l&15, rows (l>>4)*4 + i

// ---- weight arena offsets (halfs) ----
static constexpr long OFF_M1W1 = 0;              // [128][128]
static constexpr long OFF_M2W0A= 16384;          // [128][128] (cols 0..127 of [128][256])
static constexpr long OFF_M2W1 = 32768;          // [128][128]
static constexpr long OFF_M3W0 = 49152;          // [512][384]
static constexpr long OFF_M3W1 = 245760;         // [1024][512]
static constexpr long OFF_SA   = 770048;         // per-L: wq[32][128], wv[128][128], wt[128][128]
static constexpr long SA_STRIDE= 36864;
static constexpr long WTOT     = OFF_SA + 3*SA_STRIDE;   // 880,640 halfs

// ---------------------------------------------------------------------------
// weight fp32 -> fp16 conversion into arena (one launch)
// ---------------------------------------------------------------------------
__global__ __launch_bounds__(256) void k_wconv(
    const float* m1w1, const float* m2w0, const float* m2w1,
    const float* m3w0, const float* m3w1,
    const float* wq0, const float* wv0, const float* wt0,
    const float* wq1, const float* wv1, const float* wt1,
    const float* wq2, const float* wv2, const float* wt2,
    f16* W)
{
  long t = (long)blockIdx.x*256 + threadIdx.x;
  if (t >= WTOT) return;
  float v;
  if      (t < OFF_M2W0A) v = m1w1[t];
  else if (t < OFF_M2W1) { long u = t-OFF_M2W0A; v = m2w0[(u>>7)*256 + (u&127)]; }
  else if (t < OFF_M3W0)  v = m2w1[t-OFF_M2W1];
  else if (t < OFF_M3W1)  v = m3w0[t-OFF_M3W0];
  else if (t < OFF_SA)    v = m3w1[t-OFF_M3W1];
  else {
    long u = t - OFF_SA; int L = (int)(u / SA_STRIDE); long r = u % SA_STRIDE;
    const float* wq = (L==0)?wq0:(L==1)?wq1:wq2;
    const float* wv = (L==0)?wv0:(L==1)?wv1:wv2;
    const float* wt = (L==0)?wt0:(L==1)?wt1:wt2;
    if (r < 4096) v = wq[r]; else if (r < 20480) v = wv[r-4096]; else v = wt[r-20480];
  }
  W[t] = (f16)v;
}

// ---------------------------------------------------------------------------
// mlp1 layer0 (K=3): h1T[b][n][o] = relu(b0[o] + sum_c w0[o][c]*in[b][n][c])
// ---------------------------------------------------------------------------
__global__ __launch_bounds__(256) void k_mlp1aT(const float* __restrict__ in,
                                                const float* __restrict__ w0,
                                                const float* __restrict__ b0,
                                                f16* __restrict__ h1T)
{
  long idx = (long)blockIdx.x*256 + threadIdx.x;
  int og = idx & 31; long bn = idx >> 5;
  const float* ip = in + bn*3;
  float x0=ip[0], x1=ip[1], x2=ip[2];
  f16* op = h1T + bn*128 + og*4;
  #pragma unroll
  for (int i=0;i<4;++i){
    int o = og*4+i;
    float v = b0[o] + w0[o*3]*x0 + w0[o*3+1]*x1 + w0[o*3+2]*x2;
    op[i] = (f16)fmaxf(v, 0.f);
  }
}

// ---------------------------------------------------------------------------
// generic transposed conv GEMM: OUTT[b][n][ocol+o] = act(bias + sum_k XT[b][n][k]*W[o][k])
// ---------------------------------------------------------------------------
template<int OT, bool RELU, bool B2D>
__global__ __launch_bounds__(256) void gemmT(
    const f16* __restrict__ W, const float* __restrict__ bias,
    const float* __restrict__ bias2d,
    const f16* __restrict__ XT, int xrs,
    f16* __restrict__ OUT, int ors, int ocol, int K)
{
  __shared__ __align__(16) f16 Xs[64][72];
  __shared__ __align__(16) f16 Wsh[OT][72];
  const int b  = blockIdx.z;
  const int n0 = blockIdx.x * 64;
  const int o0 = blockIdx.y * OT;
  const int tid = threadIdx.x, lane = tid & 63, w = tid >> 6;
  const int lr = lane & 15, lg = lane >> 4;
  constexpr int NSUB = (OT==64)?2:1;
  const int wn = (OT==64)? (w>>1) : w;
  const int wo = (OT==64)? (w&1) : 0;
  const int nbase = wn*(16*NSUB);
  const f16* Xb = XT + (long)b*NPT*xrs;
  f32x4 acc[NSUB][2];
  #pragma unroll
  for (int ni=0;ni<NSUB;++ni){ acc[ni][0]=(f32x4){0,0,0,0}; acc[ni][1]=(f32x4){0,0,0,0}; }

  for (int k0=0; k0<K; k0+=64){
    #pragma unroll
    for (int g = tid; g < 512; g += 256){
      int r = g>>3, s = g&7;
      *(float4*)&Xs[r][s*8] = *(const float4*)(Xb + (long)(n0+r)*xrs + k0 + s*8);
    }
    for (int g = tid; g < OT*8; g += 256){
      int r = g>>3, s = g&7;
      *(float4*)&Wsh[r][s*8] = *(const float4*)(W + (long)(o0+r)*K + k0 + s*8);
    }
    __syncthreads();
    #pragma unroll
    for (int ks=0; ks<2; ++ks){
      f16x8 a[NSUB], bf[2];
      #pragma unroll
      for (int ni=0;ni<NSUB;++ni) a[ni] = *(const f16x8*)&Xs[nbase + ni*16 + lr][ks*32 + lg*8];
      #pragma unroll
      for (int oi=0;oi<2;++oi)   bf[oi] = *(const f16x8*)&Wsh[wo*32 + oi*16 + lr][ks*32 + lg*8];
      #pragma unroll
      for (int ni=0;ni<NSUB;++ni)
        #pragma unroll
        for (int oi=0;oi<2;++oi) acc[ni][oi] = mfma16(a[ni], bf[oi], acc[ni][oi]);
    }
    __syncthreads();
  }
  #pragma unroll
  for (int ni=0;ni<NSUB;++ni)
    #pragma unroll
    for (int oi=0;oi<2;++oi){
      const int oc = o0 + wo*32 + oi*16 + lr;
      float bi = bias ? bias[oc] : 0.f;
      if constexpr (B2D) bi += bias2d[b*128 + oc];
      #pragma unroll
      for (int i=0;i<4;++i){
        const int nn = n0 + nbase + ni*16 + lg*4 + i;
        float v = acc[ni][oi][i] + bi;
        if constexpr (RELU) v = fmaxf(v, 0.f);
        OUT[(long)b*NPT*ors + (long)nn*ors + ocol + oc] = (f16)v;
      }
    }
}

// ---------------------------------------------------------------------------
// 128x128-tile GEMM (4 waves as 2x2, each wave 64x64, acc[4][4]):
// __launch_bounds__(256,4): cap regs at 128/thread -> 4 blocks/CU.
// ---------------------------------------------------------------------------
template<bool RELU>
__global__ __launch_bounds__(256, 4) void gemm128(
    const f16* __restrict__ W, const float* __restrict__ bias,
    const f16* __restrict__ XT, int xrs,
    f16* __restrict__ OUT, int ors, int K)
{
  __shared__ __align__(16) f16 Xs[128][72];
  __shared__ __align__(16) f16 Wsh[128][72];
  const int b  = blockIdx.z;
  const int n0 = blockIdx.x * 128;
  const int o0 = blockIdx.y * 128;
  const int tid = threadIdx.x, lane = tid & 63, w = tid >> 6;
  const int lr = lane & 15, lg = lane >> 4;
  const int wn = w >> 1, wo = w & 1;
  const f16* Xb = XT + (long)b*NPT*xrs;
  f32x4 acc[4][4];
  #pragma unroll
  for (int ni=0;ni<4;++ni)
    #pragma unroll
    for (int oi=0;oi<4;++oi) acc[ni][oi] = (f32x4){0,0,0,0};

  for (int k0=0; k0<K; k0+=64){
    #pragma unroll
    for (int g = tid; g < 1024; g += 256){
      int r = g>>3, s = g&7;
      *(float4*)&Xs[r][s*8]  = *(const float4*)(Xb + (long)(n0+r)*xrs + k0 + s*8);
      *(float4*)&Wsh[r][s*8] = *(const float4*)(W + (long)(o0+r)*K + k0 + s*8);
    }
    __syncthreads();
    #pragma unroll
    for (int ks=0; ks<2; ++ks){
      f16x8 a[4], bf[4];
      #pragma unroll
      for (int ni=0;ni<4;++ni) a[ni]  = *(const f16x8*)&Xs[wn*64 + ni*16 + lr][ks*32 + lg*8];
      #pragma unroll
      for (int oi=0;oi<4;++oi) bf[oi] = *(const f16x8*)&Wsh[wo*64 + oi*16 + lr][ks*32 + lg*8];
      #pragma unroll
      for (int ni=0;ni<4;++ni)
        #pragma unroll
        for (int oi=0;oi<4;++oi) acc[ni][oi] = mfma16(a[ni], bf[oi], acc[ni][oi]);
    }
    __syncthreads();
  }
  #pragma unroll
  for (int ni=0;ni<4;++ni)
    #pragma unroll
    for (int oi=0;oi<4;++oi){
      const int oc = o0 + wo*64 + oi*16 + lr;
      const float bi = bias[oc];
      #pragma unroll
      for (int i=0;i<4;++i){
        const int nn = n0 + wn*64 + ni*16 + lg*4 + i;
        float v = acc[ni][oi][i] + bi;
        if constexpr (RELU) v = fmaxf(v, 0.f);
        OUT[(long)b*NPT*ors + (long)nn*ors + oc] = (f16)v;
      }
    }
}

// ---------------------------------------------------------------------------
// mlp3 layer1 with fused max, 128x128 tile. grid (16, 8, B). K=512.
// ---------------------------------------------------------------------------
__global__ __launch_bounds__(256, 4) void k_gemmax128(
    const f16* __restrict__ W, const float* __restrict__ bias,
    const f16* __restrict__ XT, float* __restrict__ part)
{
  __shared__ __align__(16) f16 Xs[128][72];
  __shared__ __align__(16) f16 Wsh[128][72];
  __shared__ float red[2][128];
  const int b  = blockIdx.z;
  const int n0 = blockIdx.x * 128;
  const int o0 = blockIdx.y * 128;
  const int tid = threadIdx.x, lane = tid & 63, w = tid >> 6;
  const int lr = lane & 15, lg = lane >> 4;
  const int wn = w >> 1, wo = w & 1;
  const f16* Xb = XT + (long)b*NPT*512;
  f32x4 acc[4][4];
  #pragma unroll
  for (int ni=0;ni<4;++ni)
    #pragma unroll
    for (int oi=0;oi<4;++oi) acc[ni][oi] = (f32x4){0,0,0,0};

  for (int k0=0; k0<512; k0+=64){
    #pragma unroll
    for (int g = tid; g < 1024; g += 256){
      int r = g>>3, s = g&7;
      *(float4*)&Xs[r][s*8]  = *(const float4*)(Xb + (long)(n0+r)*512 + k0 + s*8);
      *(float4*)&Wsh[r][s*8] = *(const float4*)(W + (long)(o0+r)*512 + k0 + s*8);
    }
    __syncthreads();
    #pragma unroll
    for (int ks=0; ks<2; ++ks){
      f16x8 a[4], bf[4];
      #pragma unroll
      for (int ni=0;ni<4;++ni) a[ni]  = *(const f16x8*)&Xs[wn*64 + ni*16 + lr][ks*32 + lg*8];
      #pragma unroll
      for (int oi=0;oi<4;++oi) bf[oi] = *(const f16x8*)&Wsh[wo*64 + oi*16 + lr][ks*32 + lg*8];
      #pragma unroll
      for (int ni=0;ni<4;++ni)
        #pragma unroll
        for (int oi=0;oi<4;++oi) acc[ni][oi] = mfma16(a[ni], bf[oi], acc[ni][oi]);
    }
    __syncthreads();
  }
  #pragma unroll
  for (int oi=0;oi<4;++oi){
    const int oc128 = wo*64 + oi*16 + lr;
    const float bi = bias[o0 + oc128];
    float mv = -1e30f;
    #pragma unroll
    for (int ni=0;ni<4;++ni)
      #pragma unroll
      for (int i=0;i<4;++i) mv = fmaxf(mv, acc[ni][oi][i] + bi);
    mv = fmaxf(mv, __shfl_xor(mv, 16, 64));
    mv = fmaxf(mv, __shfl_xor(mv, 32, 64));
    if (lg == 0) red[wn][oc128] = mv;
  }
  __syncthreads();
  if (tid < 128)
    part[((long)b*1024 + o0 + tid)*16 + blockIdx.x] = fmaxf(red[0][tid], red[1][tid]);
}

// ---------------------------------------------------------------------------
// FUSED v+q GEMM: x = prev + lfT computed in staging.
// v16[b][c][n] for all blocks; c0==0 blocks ALSO: write staged x to xT and
// compute qT[b][n][o] (o<32) with Wq B-frags loaded direct from global
// (same fragment recipe as the green qgemmF/gemmT<32>). grid (32, 2, B).
// ---------------------------------------------------------------------------
__global__ __launch_bounds__(256) void k_vqgemmF(
    const f16* __restrict__ Wv, const float* __restrict__ bv,
    const f16* __restrict__ Wq,
    const f16* __restrict__ prev, int prs,
    const f16* __restrict__ lfT,
    f16* __restrict__ v16, f16* __restrict__ xT, f16* __restrict__ qT)
{
  __shared__ __align__(16) f16 Xs[64][72];
  __shared__ __align__(16) f16 Wsh[64][72];
  const int b  = blockIdx.z;
  const int n0 = blockIdx.x * 64;
  const int c0 = blockIdx.y * 64;
  const int tid = threadIdx.x, lane = tid & 63, w = tid >> 6;
  const int lr = lane & 15, lg = lane >> 4;
  const int wc = w>>1, wn = w&1;
  f32x4 acc[2][2];
  #pragma unroll
  for (int ci=0;ci<2;++ci){ acc[ci][0]=(f32x4){0,0,0,0}; acc[ci][1]=(f32x4){0,0,0,0}; }
  f32x4 accq[2];
  accq[0] = (f32x4){0,0,0,0}; accq[1] = (f32x4){0,0,0,0};

  for (int k0=0; k0<128; k0+=64){
    #pragma unroll
    for (int g = tid; g < 512; g += 256){
      int r = g>>3, s = g&7;
      const long bn = (long)b*NPT + n0 + r;
      f16x8 xa = *(const f16x8*)(prev + bn*prs + k0 + s*8);
      f16x8 l  = *(const f16x8*)(lfT + bn*128 + k0 + s*8);
      f16x8 xv = xa + l;
      *(f16x8*)&Xs[r][s*8] = xv;
      if (c0 == 0) *(f16x8*)(xT + bn*128 + k0 + s*8) = xv;   // materialize x for safin
      *(float4*)&Wsh[r][s*8] = *(const float4*)(Wv + (long)(c0+r)*128 + k0 + s*8);
    }
    __syncthreads();
    #pragma unroll
    for (int ks=0; ks<2; ++ks){
      f16x8 a[2], bf[2];
      #pragma unroll
      for (int ci=0;ci<2;++ci) a[ci] = *(const f16x8*)&Wsh[wc*32 + ci*16 + lr][ks*32 + lg*8];
      #pragma unroll
      for (int ni=0;ni<2;++ni) bf[ni] = *(const f16x8*)&Xs[wn*32 + ni*16 + lr][ks*32 + lg*8];
      #pragma unroll
      for (int ci=0;ci<2;++ci)
        #pragma unroll
        for (int ni=0;ni<2;++ni) acc[ci][ni] = mfma16(a[ci], bf[ni], acc[ci][ni]);
    }
    if (c0 == 0){
      // q: A = Xs rows n (wave w owns n0+w*16..+15), B = Wq direct from global
      #pragma unroll
      for (int ks=0; ks<2; ++ks){
        f16x8 aq = *(const f16x8*)&Xs[w*16 + lr][ks*32 + lg*8];
        #pragma unroll
        for (int oi=0;oi<2;++oi){
          f16x8 bq = *(const f16x8*)(Wq + (long)(oi*16 + lr)*128 + k0 + ks*32 + lg*8);
          accq[oi] = mfma16(aq, bq, accq[oi]);
        }
      }
    }
    __syncthreads();
  }
  #pragma unroll
  for (int ci=0;ci<2;++ci)
    #pragma unroll
    for (int i=0;i<4;++i){
      const int c = c0 + wc*32 + ci*16 + lg*4 + i;
      const float bi = bv[c];
      #pragma unroll
      for (int ni=0;ni<2;++ni){
        const int n = n0 + wn*32 + ni*16 + lr;
        v16[(long)b*128*NPT + (long)c*NPT + n] = (f16)(acc[ci][ni][i] + bi);
      }
    }
  if (c0 == 0){
    #pragma unroll
    for (int oi=0;oi<2;++oi){
      const int oc = oi*16 + lr;
      #pragma unroll
      for (int i=0;i<4;++i){
        const int nn = n0 + w*16 + lg*4 + i;
        qT[((long)b*NPT + nn)*32 + oc] = (f16)accq[oi][i];
      }
    }
  }
}

// ---------------------------------------------------------------------------
// rowstats via MFMA: rmax/rsum over m of e[m,n] (symmetric e) per col n.
// ---------------------------------------------------------------------------
__global__ __launch_bounds__(256) void k_rowstats2(const f16* __restrict__ qT,
                                                   float* __restrict__ rmax,
                                                   float* __restrict__ rsum)
{
  const int b = blockIdx.y, n0 = blockIdx.x*64;
  const int tid = threadIdx.x, lane = tid & 63, w = tid >> 6;
  const int lr = lane & 15, lg = lane >> 4;
  const f16* qb = qT + (long)b*NPT*32;
  const f16x8 bfr = *(const f16x8*)(qb + (long)(n0 + w*16 + lr)*32 + lg*8);
  float mx = -1e30f, sm = 0.f;
  for (int m0=0; m0<NPT; m0+=32){
    f16x8 af0 = *(const f16x8*)(qb + (long)(m0+lr)*32 + lg*8);
    f16x8 af1 = *(const f16x8*)(qb + (long)(m0+16+lr)*32 + lg*8);
    f32x4 e0 = mfma16(af0, bfr, (f32x4){0,0,0,0});
    f32x4 e1 = mfma16(af1, bfr, (f32x4){0,0,0,0});
    float t0 = fmaxf(fmaxf(e0[0],e0[1]), fmaxf(e0[2],e0[3]));
    float t1 = fmaxf(fmaxf(e1[0],e1[1]), fmaxf(e1[2],e1[3]));
    float nm = fmaxf(mx, fmaxf(t0, t1));
    sm *= __expf(mx - nm);
    mx = nm;
    sm += __expf(e0[0]-mx) + __expf(e0[1]-mx) + __expf(e0[2]-mx) + __expf(e0[3]-mx)
        + __expf(e1[0]-mx) + __expf(e1[1]-mx) + __expf(e1[2]-mx) + __expf(e1[3]-mx);
  }
  #pragma unroll
  for (int d=16; d<64; d<<=1){
    float omx = __shfl_xor(mx, d, 64);
    float osm = __shfl_xor(sm, d, 64);
    float nm = fmaxf(mx, omx);
    sm = sm*__expf(mx-nm) + osm*__expf(omx-nm);
    mx = nm;
  }
  if (lane < 16){
    rmax[(long)b*NPT + n0 + w*16 + lr] = mx;
    rsum[(long)b*NPT + n0 + w*16 + lr] = sm;
  }
}

// ---------------------------------------------------------------------------
// pass2 PARTIAL [proven kernel: 64-m blocks, 2-deep pipelined V staging,
// one barrier/tile, ones-MFMA colsum]. NSEG=2. grid (32, NSEG, B).
//   xrpart[(b*NSEG+seg)][m][c] = sum_n p[n,m] v[c,n]   (f16 raw)
//   cspart[(b*NSEG+seg)*NPT + m] = sum_n p[n,m]        (fp32)
// ---------------------------------------------------------------------------
__global__ __launch_bounds__(256) void k_pass2p(const f16* __restrict__ qT,
                                                const f16* __restrict__ v16,
                                                const float* __restrict__ rmax,
                                                const float* __restrict__ rsum,
                                                f16* __restrict__ xrpart,
                                                float* __restrict__ cspart)
{
  __shared__ __align__(16) f16 ps[64][40];      // pT[m][n-tile]; rows wave-private
  __shared__ __align__(16) f16 vs[2][128][40];  // double-buffered v-tile [c][n-tile]
  const int b = blockIdx.z, seg = blockIdx.y, m0 = blockIdx.x*64;
  const int tid = threadIdx.x, lane = tid & 63, w = tid >> 6;
  const int lr = lane & 15, lg = lane >> 4;
  const f16* qb = qT + (long)b*NPT*32;
  const f16* vb = v16 + (long)b*128*NPT;
  const float* rmx = rmax + (long)b*NPT;
  const float* rsm = rsum + (long)b*NPT;
  const f16x8 afe = *(const f16x8*)(qb + (long)(m0 + w*16 + lr)*32 + lg*8);  // E A-frag (rows m)
  f16x8 ones;
  #pragma unroll
  for (int j=0;j<8;++j) ones[j] = (f16)1.0f;
  f32x4 acc[8];
  #pragma unroll
  for (int cg=0; cg<8; ++cg) acc[cg] = (f32x4){0,0,0,0};
  f32x4 acc_cs = (f32x4){0,0,0,0};

  const int ntBeg = seg*(NPT/NSEG), ntEnd = ntBeg + NPT/NSEG;
  // prologue: stage first tile into vs[0]
  #pragma unroll
  for (int g = tid; g < 512; g += 256){
    int c = g>>2, s = g&3;
    *(float4*)&vs[0][c][s*8] = *(const float4*)(vb + (long)c*NPT + ntBeg + s*8);
  }
  __syncthreads();
  int cur = 0;

  for (int nt=ntBeg; nt<ntEnd; nt+=32){
    // issue next tile's staging into vs[cur^1] (loads fly under E+PV compute)
    if (nt + 32 < ntEnd){
      #pragma unroll
      for (int g = tid; g < 512; g += 256){
        int c = g>>2, s = g&3;
        *(float4*)&vs[cur^1][c][s*8] = *(const float4*)(vb + (long)c*NPT + nt + 32 + s*8);
      }
    }
    // E phase: 2 col-groups; lane col n fixed, 4 m-rows (ps wave-private)
    #pragma unroll
    for (int ng=0; ng<2; ++ng){
      f16x8 bfe = *(const f16x8*)(qb + (long)(nt + ng*16 + lr)*32 + lg*8);
      f32x4 e = mfma16(afe, bfe, (f32x4){0,0,0,0});
      const int n = nt + ng*16 + lr;
      const float rm = rmx[n];
      const float irs = 1.f / rsm[n];
      #pragma unroll
      for (int i=0;i<4;++i){
        float p = __expf(e[i] - rm) * irs;
        ps[w*16 + lg*4 + i][ng*16 + lr] = (f16)p;
      }
    }
    // PV phase: A = pT rows m (wave-private), B = current v-tile
    f16x8 ap = *(const f16x8*)&ps[w*16 + lr][lg*8];
    #pragma unroll
    for (int cg=0; cg<8; ++cg){
      f16x8 bp = *(const f16x8*)&vs[cur][cg*16 + lr][lg*8];
      acc[cg] = mfma16(ap, bp, acc[cg]);
    }
    acc_cs = mfma16(ap, ones, acc_cs);   // colsum on matrix pipe
    __syncthreads();                      // drains staging; protects vs[cur] reuse
    cur ^= 1;
  }
  const long row = (long)(b*NSEG + seg);
  // acc_cs[i] = cs[m0 + w*16 + lg*4 + i], duplicated across lr
  if (lr == 0){
    #pragma unroll
    for (int i=0;i<4;++i)
      cspart[row*NPT + m0 + w*16 + lg*4 + i] = acc_cs[i];
  }
  // raw partial store (no renorm)
  f16* xb = xrpart + row*NPT*128;
  #pragma unroll
  for (int cg=0; cg<8; ++cg)
    #pragma unroll
    for (int i=0;i<4;++i)
      xb[(long)(m0 + w*16 + lg*4 + i)*128 + cg*16 + lr] = (f16)acc[cg][i];
}

// ---------------------------------------------------------------------------
// gmax over n per (b,c)
// ---------------------------------------------------------------------------
__global__ __launch_bounds__(1024) void k_gmaxT(const f16* __restrict__ lfT,
                                                float* __restrict__ gmaxv)
{
  __shared__ float red[8][128];
  const int b = blockIdx.x;
  const int c = threadIdx.x & 127, h = threadIdx.x >> 7;
  const f16* p = lfT + (long)b*NPT*128;
  float m = -1e30f;
  for (int n = h*256; n < (h+1)*256; ++n) m = fmaxf(m, (float)p[(long)n*128 + c]);
  red[h][c] = m; __syncthreads();
  if (threadIdx.x < 128){
    float mm = red[0][c];
    #pragma unroll
    for (int j=1;j<8;++j) mm = fmaxf(mm, red[j][c]);
    gmaxv[b*128 + c] = mm;
  }
}

__global__ __launch_bounds__(128) void k_gvec(const float* __restrict__ w0,
                                              const float* __restrict__ b0,
                                              const float* __restrict__ gmaxv,
                                              float* __restrict__ gc)
{
  const int b = blockIdx.x, o = threadIdx.x;
  __shared__ float g[128];
  g[o] = gmaxv[b*128+o]; __syncthreads();
  float acc = b0[o];
  for (int c = 0; c < 128; ++c) acc = fmaf(w0[o*256 + 128 + c], g[c], acc);
  gc[b*128+o] = acc;
}

// ---------------------------------------------------------------------------
// SA epilogue GEMM with FUSED partial merge (NSEG=2):
// xr[n][c] = (p0+p1)*inv computed inline from xrpart/cspart.
// cat[b][n][Lcol+o] = x[n][o] + relu(g'*(wt@(x-xr))+..). grid (32,2,B).
// ---------------------------------------------------------------------------
__global__ __launch_bounds__(256) void k_safin2(
    const f16* __restrict__ Wt, const float* __restrict__ bt,
    const float* __restrict__ g, const float* __restrict__ be,
    const f16* __restrict__ xT,
    const f16* __restrict__ xrpart, const float* __restrict__ cspart,
    f16* __restrict__ cat, int Lcol)
{
  __shared__ __align__(16) f16 Xs[64][72];
  __shared__ __align__(16) f16 Wsh[64][72];
  const int b  = blockIdx.z;
  const int n0 = blockIdx.x * 64;
  const int o0 = blockIdx.y * 64;
  const int tid = threadIdx.x, lane = tid & 63, w = tid >> 6;
  const int lr = lane & 15, lg = lane >> 4;
  const int wn = w>>1, wo = w&1;
  const f16* xb = xT + (long)b*NPT*128;
  f32x4 acc[2][2];
  #pragma unroll
  for (int ni=0;ni<2;++ni){ acc[ni][0]=(f32x4){0,0,0,0}; acc[ni][1]=(f32x4){0,0,0,0}; }

  for (int k0=0; k0<128; k0+=64){
    #pragma unroll
    for (int gidx = tid; gidx < 512; gidx += 256){
      int r = gidx>>3, s = gidx&7;
      const long nn = n0 + r;
      const long r0 = ((long)b*NSEG + 0)*NPT + nn;
      const long r1 = r0 + NPT;
      const float inv = 1.f/(1e-9f + cspart[r0] + cspart[r1]);
      f16x8 xa = *(const f16x8*)(xb + nn*128 + k0 + s*8);
      f16x8 p0 = *(const f16x8*)(xrpart + r0*128 + k0 + s*8);
      f16x8 p1 = *(const f16x8*)(xrpart + r1*128 + k0 + s*8);
      f16x8 xs;
      #pragma unroll
      for (int j=0;j<8;++j)
        xs[j] = (f16)((float)xa[j] - ((float)p0[j] + (float)p1[j]) * inv);
      *(f16x8*)&Xs[r][s*8] = xs;
      *(float4*)&Wsh[r][s*8] = *(const float4*)(Wt + (long)(o0+r)*128 + k0 + s*8);
    }
    __syncthreads();
    #pragma unroll
    for (int ks=0; ks<2; ++ks){
      f16x8 a[2], bf[2];
      #pragma unroll
      for (int ni=0;ni<2;++ni) a[ni] = *(const f16x8*)&Xs[wn*32 + ni*16 + lr][ks*32 + lg*8];
      #pragma unroll
      for (int oi=0;oi<2;++oi) bf[oi] = *(const f16x8*)&Wsh[wo*32 + oi*16 + lr][ks*32 + lg*8];
      #pragma unroll
      for (int ni=0;ni<2;++ni)
        #pragma unroll
        for (int oi=0;oi<2;++oi) acc[ni][oi] = mfma16(a[ni], bf[oi], acc[ni][oi]);
    }
    __syncthreads();
  }
  const float bnsc = rsqrtf(1.f + 1e-5f);
  #pragma unroll
  for (int ni=0;ni<2;++ni)
    #pragma unroll
    for (int oi=0;oi<2;++oi){
      const int oc = o0 + wo*32 + oi*16 + lr;
      const float bti = bt[oc], gi = g[oc]*bnsc, bei = be[oc];
      #pragma unroll
      for (int i=0;i<4;++i){
        const int nn = n0 + wn*32 + ni*16 + lg*4 + i;
        float t = acc[ni][oi][i] + bti;
        float val = fmaxf(fmaf(gi, t, bei), 0.f);
        float res = (float)xb[(long)nn*128 + oc];
        cat[(long)b*NPT*384 + (long)nn*384 + Lcol + oc] = (f16)(res + val);
      }
    }
}

__global__ __launch_bounds__(256) void k_maxfinal(const float* __restrict__ part,
                                                  float* __restrict__ out)
{
  const int t = blockIdx.x*256 + threadIdx.x;   // 0..16383
  float m = -1e30f;
  #pragma unroll
  for (int j=0;j<16;++j) m = fmaxf(m, part[(long)t*16 + j]);
  out[t] = m;
}

// ---------------------------------------------------------------------------
extern "C" void kernel_launch(void* const* d_in, const int* in_sizes, int n_in,
                              void* d_out, int out_size, void* d_ws, size_t ws_size,
                              hipStream_t stream)
{
  const float* in   = (const float*)d_in[0];
  const float* m1w0 = (const float*)d_in[1];
  const float* m1b0 = (const float*)d_in[2];
  const float* m1w1 = (const float*)d_in[3];
  const float* m1b1 = (const float*)d_in[4];
  const float* m2w0 = (const float*)d_in[5];
  const float* m2b0 = (const float*)d_in[6];
  const float* m2w1 = (const float*)d_in[7];
  const float* m2b1 = (const float*)d_in[8];
  const float* m3w0 = (const float*)d_in[9];
  const float* m3b0 = (const float*)d_in[10];
  const float* m3w1 = (const float*)d_in[11];
  const float* m3b1 = (const float*)d_in[12];

  // ws layout (halfs)
  f16* ws16 = (f16*)d_ws;
  f16* W16  = ws16;                       // 880,640
  f16* lfT  = ws16 + 880640;              // [B][N][128]
  f16* xT   = ws16 + 5074944;             // [B][N][128]
  f16* qT   = ws16 + 9269248;             // [B][N][32]
  f16* vbuf = ws16 + 10317824;            // [B][128][N]
  f16* xrT  = ws16 + 14512128;            // [B][N][128] (mlp2 features; never clobbered)
  f16* hT   = ws16 + 18706432;            // [B][N][512] (mlp hidden)
  f16* xrpart = hT;                       // [B*NSEG][N][128] — aliases hT (dead during SA)
  f16* catT = ws16 + 35483648;            // [B][N][384]
  float* fb = (float*)(ws16 + 48066560);
  float* rmaxp  = fb;                     // [B,N]
  float* rsump  = fb + 32768;             // [B,N]
  float* gmaxv  = fb + 65536;             // [B,128]
  float* gc     = fb + 67584;             // [B,128]
  float* part   = fb + 69632;             // [B,1024,16]
  float* cspart = fb + 593920;            // [B*NSEG][N]

  const dim3 blk(256);

  k_wconv<<<dim3((WTOT+255)/256), blk, 0, stream>>>(
      m1w1, m2w0, m2w1, m3w0, m3w1,
      (const float*)d_in[13], (const float*)d_in[14], (const float*)d_in[16],
      (const float*)d_in[20], (const float*)d_in[21], (const float*)d_in[23],
      (const float*)d_in[27], (const float*)d_in[28], (const float*)d_in[30],
      W16);

  // mlp1
  k_mlp1aT<<<dim3(NBAT*NPT*32/256), blk, 0, stream>>>(in, m1w0, m1b0, hT);
  gemmT<64,false,false><<<dim3(32,2,NBAT), blk, 0, stream>>>(
      W16+OFF_M1W1, m1b1, nullptr, hT, 128, lfT, 128, 0, 128);
  // global max + mlp2
  k_gmaxT<<<dim3(NBAT), dim3(1024), 0, stream>>>(lfT, gmaxv);
  k_gvec<<<dim3(NBAT), dim3(128), 0, stream>>>(m2w0, m2b0, gmaxv, gc);
  gemmT<64,true,true><<<dim3(32,2,NBAT), blk, 0, stream>>>(
      W16+OFF_M2W0A, nullptr, gc, lfT, 128, hT, 128, 0, 128);
  gemmT<64,false,false><<<dim3(32,2,NBAT), blk, 0, stream>>>(
      W16+OFF_M2W1, m2b1, nullptr, hT, 128, xrT, 128, 0, 128);   // features -> xrT

  // 3 SA layers (addT, qgemm, pmerge all fused away)
  for (int L = 0; L < 3; ++L){
    const float* bv = (const float*)d_in[13 + L*7 + 2];
    const float* bt = (const float*)d_in[13 + L*7 + 4];
    const float* gg = (const float*)d_in[13 + L*7 + 5];
    const float* be = (const float*)d_in[13 + L*7 + 6];
    const f16* wq16 = W16 + OFF_SA + L*SA_STRIDE;
    const f16* wv16 = wq16 + 4096;
    const f16* wt16 = wq16 + 20480;

    const f16* prev = (L==0) ? xrT : (catT + (long)(L-1)*128);
    const int  prs  = (L==0) ? 128 : 384;

    k_vqgemmF<<<dim3(32,2,NBAT), blk, 0, stream>>>(
        wv16, bv, wq16, prev, prs, lfT, vbuf, xT, qT);
    k_rowstats2<<<dim3(32,NBAT), blk, 0, stream>>>(qT, rmaxp, rsump);
    k_pass2p<<<dim3(32,NSEG,NBAT), blk, 0, stream>>>(qT, vbuf, rmaxp, rsump, xrpart, cspart);
    k_safin2<<<dim3(32,2,NBAT), blk, 0, stream>>>(
        wt16, bt, gg, be, xT, xrpart, cspart, catT, L*128);
  }

  // mlp3: layer0 (384->512 relu) 128x128 tile, layer1 fused-max 128x128
  gemm128<true><<<dim3(16,4,NBAT), blk, 0, stream>>>(
      W16+OFF_M3W0, m3b0, catT, 384, hT, 512, 384);
  k_gemmax128<<<dim3(16,8,NBAT), blk, 0, stream>>>(W16+OFF_M3W1, m3b1, hT, part);
  k_maxfinal<<<dim3(64), blk, 0, stream>>>(part, (float*)d_out);
}

// Round 19
// 449.072 us; speedup vs baseline: 1.1218x; 1.0276x over previous
//
#include <hip/hip_runtime.h>
#include <hip/hip_bf16.h>
#include <cfloat>

static constexpr int NBAT = 16;
static constexpr int NPT  = 2048;
static constexpr int NSEG = 2;     // pass2 n-split segments

typedef _Float16 f16;
typedef _Float16 f16x8 __attribute__((ext_vector_type(8)));
typedef float    f32x4 __attribute__((ext_vector_type(4)));

static __device__ __forceinline__ f32x4 mfma16(f16x8 a, f16x8 b, f32x4 c){
  return __builtin_amdgcn_mfma_f32_16x16x32_f16(a, b, c, 0, 0, 0);
}
// MFMA 16x16x32 f16 layouts (gfx950, e2e-verified by round-4 pass):
//  A[16r x 32k]: lane l -> row l&15, k = (l>>4)*8 + j (16B contiguous)
//  B[32k x 16c]: lane l -> col l&15, k = (l>>4)*8 + j (16B contiguous)
//  D[16r x 16c]: lane l -> col l&15, rows (l>>4)*4 + i

// ---- weight arena offsets (halfs) ----
static constexpr long OFF_M1W1 = 0;              // [128][128]
static constexpr long OFF_M2W0A= 16384;          // [128][128] (cols 0..127 of [128][256])
static constexpr long OFF_M2W1 = 32768;          // [128][128]
static constexpr long OFF_M3W0 = 49152;          // [512][384]
static constexpr long OFF_M3W1 = 245760;         // [1024][512]
static constexpr long OFF_SA   = 770048;         // per-L: wq[32][128], wv[128][128], wt[128][128]
static constexpr long SA_STRIDE= 36864;
static constexpr long WTOT     = OFF_SA + 3*SA_STRIDE;   // 880,640 halfs

// ---------------------------------------------------------------------------
// weight fp32 -> fp16 conversion into arena (one launch)
// ---------------------------------------------------------------------------
__global__ __launch_bounds__(256) void k_wconv(
    const float* m1w1, const float* m2w0, const float* m2w1,
    const float* m3w0, const float* m3w1,
    const float* wq0, const float* wv0, const float* wt0,
    const float* wq1, const float* wv1, const float* wt1,
    const float* wq2, const float* wv2, const float* wt2,
    f16* W)
{
  long t = (long)blockIdx.x*256 + threadIdx.x;
  if (t >= WTOT) return;
  float v;
  if      (t < OFF_M2W0A) v = m1w1[t];
  else if (t < OFF_M2W1) { long u = t-OFF_M2W0A; v = m2w0[(u>>7)*256 + (u&127)]; }
  else if (t < OFF_M3W0)  v = m2w1[t-OFF_M2W1];
  else if (t < OFF_M3W1)  v = m3w0[t-OFF_M3W0];
  else if (t < OFF_SA)    v = m3w1[t-OFF_M3W1];
  else {
    long u = t - OFF_SA; int L = (int)(u / SA_STRIDE); long r = u % SA_STRIDE;
    const float* wq = (L==0)?wq0:(L==1)?wq1:wq2;
    const float* wv = (L==0)?wv0:(L==1)?wv1:wv2;
    const float* wt = (L==0)?wt0:(L==1)?wt1:wt2;
    if (r < 4096) v = wq[r]; else if (r < 20480) v = wv[r-4096]; else v = wt[r-20480];
  }
  W[t] = (f16)v;
}

// ---------------------------------------------------------------------------
// mlp1 layer0 (K=3): h1T[b][n][o] = relu(b0[o] + sum_c w0[o][c]*in[b][n][c])
// ---------------------------------------------------------------------------
__global__ __launch_bounds__(256) void k_mlp1aT(const float* __restrict__ in,
                                                const float* __restrict__ w0,
                                                const float* __restrict__ b0,
                                                f16* __restrict__ h1T)
{
  long idx = (long)blockIdx.x*256 + threadIdx.x;
  int og = idx & 31; long bn = idx >> 5;
  const float* ip = in + bn*3;
  float x0=ip[0], x1=ip[1], x2=ip[2];
  f16* op = h1T + bn*128 + og*4;
  #pragma unroll
  for (int i=0;i<4;++i){
    int o = og*4+i;
    float v = b0[o] + w0[o*3]*x0 + w0[o*3+1]*x1 + w0[o*3+2]*x2;
    op[i] = (f16)fmaxf(v, 0.f);
  }
}

// ---------------------------------------------------------------------------
// generic transposed conv GEMM: OUTT[b][n][ocol+o] = act(bias + sum_k XT[b][n][k]*W[o][k])
// ---------------------------------------------------------------------------
template<int OT, bool RELU, bool B2D>
__global__ __launch_bounds__(256) void gemmT(
    const f16* __restrict__ W, const float* __restrict__ bias,
    const float* __restrict__ bias2d,
    const f16* __restrict__ XT, int xrs,
    f16* __restrict__ OUT, int ors, int ocol, int K)
{
  __shared__ __align__(16) f16 Xs[64][72];
  __shared__ __align__(16) f16 Wsh[OT][72];
  const int b  = blockIdx.z;
  const int n0 = blockIdx.x * 64;
  const int o0 = blockIdx.y * OT;
  const int tid = threadIdx.x, lane = tid & 63, w = tid >> 6;
  const int lr = lane & 15, lg = lane >> 4;
  constexpr int NSUB = (OT==64)?2:1;
  const int wn = (OT==64)? (w>>1) : w;
  const int wo = (OT==64)? (w&1) : 0;
  const int nbase = wn*(16*NSUB);
  const f16* Xb = XT + (long)b*NPT*xrs;
  f32x4 acc[NSUB][2];
  #pragma unroll
  for (int ni=0;ni<NSUB;++ni){ acc[ni][0]=(f32x4){0,0,0,0}; acc[ni][1]=(f32x4){0,0,0,0}; }

  for (int k0=0; k0<K; k0+=64){
    #pragma unroll
    for (int g = tid; g < 512; g += 256){
      int r = g>>3, s = g&7;
      *(float4*)&Xs[r][s*8] = *(const float4*)(Xb + (long)(n0+r)*xrs + k0 + s*8);
    }
    for (int g = tid; g < OT*8; g += 256){
      int r = g>>3, s = g&7;
      *(float4*)&Wsh[r][s*8] = *(const float4*)(W + (long)(o0+r)*K + k0 + s*8);
    }
    __syncthreads();
    #pragma unroll
    for (int ks=0; ks<2; ++ks){
      f16x8 a[NSUB], bf[2];
      #pragma unroll
      for (int ni=0;ni<NSUB;++ni) a[ni] = *(const f16x8*)&Xs[nbase + ni*16 + lr][ks*32 + lg*8];
      #pragma unroll
      for (int oi=0;oi<2;++oi)   bf[oi] = *(const f16x8*)&Wsh[wo*32 + oi*16 + lr][ks*32 + lg*8];
      #pragma unroll
      for (int ni=0;ni<NSUB;++ni)
        #pragma unroll
        for (int oi=0;oi<2;++oi) acc[ni][oi] = mfma16(a[ni], bf[oi], acc[ni][oi]);
    }
    __syncthreads();
  }
  #pragma unroll
  for (int ni=0;ni<NSUB;++ni)
    #pragma unroll
    for (int oi=0;oi<2;++oi){
      const int oc = o0 + wo*32 + oi*16 + lr;
      float bi = bias ? bias[oc] : 0.f;
      if constexpr (B2D) bi += bias2d[b*128 + oc];
      #pragma unroll
      for (int i=0;i<4;++i){
        const int nn = n0 + nbase + ni*16 + lg*4 + i;
        float v = acc[ni][oi][i] + bi;
        if constexpr (RELU) v = fmaxf(v, 0.f);
        OUT[(long)b*NPT*ors + (long)nn*ors + ocol + oc] = (f16)v;
      }
    }
}

// ---------------------------------------------------------------------------
// 128x128-tile GEMM (4 waves as 2x2, each wave 64x64, acc[4][4]):
// __launch_bounds__(256,4): cap regs at 128/thread -> 4 blocks/CU.
// ---------------------------------------------------------------------------
template<bool RELU>
__global__ __launch_bounds__(256, 4) void gemm128(
    const f16* __restrict__ W, const float* __restrict__ bias,
    const f16* __restrict__ XT, int xrs,
    f16* __restrict__ OUT, int ors, int K)
{
  __shared__ __align__(16) f16 Xs[128][72];
  __shared__ __align__(16) f16 Wsh[128][72];
  const int b  = blockIdx.z;
  const int n0 = blockIdx.x * 128;
  const int o0 = blockIdx.y * 128;
  const int tid = threadIdx.x, lane = tid & 63, w = tid >> 6;
  const int lr = lane & 15, lg = lane >> 4;
  const int wn = w >> 1, wo = w & 1;
  const f16* Xb = XT + (long)b*NPT*xrs;
  f32x4 acc[4][4];
  #pragma unroll
  for (int ni=0;ni<4;++ni)
    #pragma unroll
    for (int oi=0;oi<4;++oi) acc[ni][oi] = (f32x4){0,0,0,0};

  for (int k0=0; k0<K; k0+=64){
    #pragma unroll
    for (int g = tid; g < 1024; g += 256){
      int r = g>>3, s = g&7;
      *(float4*)&Xs[r][s*8]  = *(const float4*)(Xb + (long)(n0+r)*xrs + k0 + s*8);
      *(float4*)&Wsh[r][s*8] = *(const float4*)(W + (long)(o0+r)*K + k0 + s*8);
    }
    __syncthreads();
    #pragma unroll
    for (int ks=0; ks<2; ++ks){
      f16x8 a[4], bf[4];
      #pragma unroll
      for (int ni=0;ni<4;++ni) a[ni]  = *(const f16x8*)&Xs[wn*64 + ni*16 + lr][ks*32 + lg*8];
      #pragma unroll
      for (int oi=0;oi<4;++oi) bf[oi] = *(const f16x8*)&Wsh[wo*64 + oi*16 + lr][ks*32 + lg*8];
      #pragma unroll
      for (int ni=0;ni<4;++ni)
        #pragma unroll
        for (int oi=0;oi<4;++oi) acc[ni][oi] = mfma16(a[ni], bf[oi], acc[ni][oi]);
    }
    __syncthreads();
  }
  #pragma unroll
  for (int ni=0;ni<4;++ni)
    #pragma unroll
    for (int oi=0;oi<4;++oi){
      const int oc = o0 + wo*64 + oi*16 + lr;
      const float bi = bias[oc];
      #pragma unroll
      for (int i=0;i<4;++i){
        const int nn = n0 + wn*64 + ni*16 + lg*4 + i;
        float v = acc[ni][oi][i] + bi;
        if constexpr (RELU) v = fmaxf(v, 0.f);
        OUT[(long)b*NPT*ors + (long)nn*ors + oc] = (f16)v;
      }
    }
}

// ---------------------------------------------------------------------------
// mlp3 layer1 with fused max, 128x128 tile. grid (16, 8, B). K=512.
// ---------------------------------------------------------------------------
__global__ __launch_bounds__(256, 4) void k_gemmax128(
    const f16* __restrict__ W, const float* __restrict__ bias,
    const f16* __restrict__ XT, float* __restrict__ part)
{
  __shared__ __align__(16) f16 Xs[128][72];
  __shared__ __align__(16) f16 Wsh[128][72];
  __shared__ float red[2][128];
  const int b  = blockIdx.z;
  const int n0 = blockIdx.x * 128;
  const int o0 = blockIdx.y * 128;
  const int tid = threadIdx.x, lane = tid & 63, w = tid >> 6;
  const int lr = lane & 15, lg = lane >> 4;
  const int wn = w >> 1, wo = w & 1;
  const f16* Xb = XT + (long)b*NPT*512;
  f32x4 acc[4][4];
  #pragma unroll
  for (int ni=0;ni<4;++ni)
    #pragma unroll
    for (int oi=0;oi<4;++oi) acc[ni][oi] = (f32x4){0,0,0,0};

  for (int k0=0; k0<512; k0+=64){
    #pragma unroll
    for (int g = tid; g < 1024; g += 256){
      int r = g>>3, s = g&7;
      *(float4*)&Xs[r][s*8]  = *(const float4*)(Xb + (long)(n0+r)*512 + k0 + s*8);
      *(float4*)&Wsh[r][s*8] = *(const float4*)(W + (long)(o0+r)*512 + k0 + s*8);
    }
    __syncthreads();
    #pragma unroll
    for (int ks=0; ks<2; ++ks){
      f16x8 a[4], bf[4];
      #pragma unroll
      for (int ni=0;ni<4;++ni) a[ni]  = *(const f16x8*)&Xs[wn*64 + ni*16 + lr][ks*32 + lg*8];
      #pragma unroll
      for (int oi=0;oi<4;++oi) bf[oi] = *(const f16x8*)&Wsh[wo*64 + oi*16 + lr][ks*32 + lg*8];
      #pragma unroll
      for (int ni=0;ni<4;++ni)
        #pragma unroll
        for (int oi=0;oi<4;++oi) acc[ni][oi] = mfma16(a[ni], bf[oi], acc[ni][oi]);
    }
    __syncthreads();
  }
  #pragma unroll
  for (int oi=0;oi<4;++oi){
    const int oc128 = wo*64 + oi*16 + lr;
    const float bi = bias[o0 + oc128];
    float mv = -1e30f;
    #pragma unroll
    for (int ni=0;ni<4;++ni)
      #pragma unroll
      for (int i=0;i<4;++i) mv = fmaxf(mv, acc[ni][oi][i] + bi);
    mv = fmaxf(mv, __shfl_xor(mv, 16, 64));
    mv = fmaxf(mv, __shfl_xor(mv, 32, 64));
    if (lg == 0) red[wn][oc128] = mv;
  }
  __syncthreads();
  if (tid < 128)
    part[((long)b*1024 + o0 + tid)*16 + blockIdx.x] = fmaxf(red[0][tid], red[1][tid]);
}

// ---------------------------------------------------------------------------
// FUSED v+q GEMM: x = prev + lfT computed in staging.
// v16[b][c][n] for all blocks; c0==0 blocks ALSO: write staged x to xT and
// compute qT[b][n][o] (o<32) with Wq B-frags loaded direct from global.
// grid (32, 2, B).
// ---------------------------------------------------------------------------
__global__ __launch_bounds__(256) void k_vqgemmF(
    const f16* __restrict__ Wv, const float* __restrict__ bv,
    const f16* __restrict__ Wq,
    const f16* __restrict__ prev, int prs,
    const f16* __restrict__ lfT,
    f16* __restrict__ v16, f16* __restrict__ xT, f16* __restrict__ qT)
{
  __shared__ __align__(16) f16 Xs[64][72];
  __shared__ __align__(16) f16 Wsh[64][72];
  const int b  = blockIdx.z;
  const int n0 = blockIdx.x * 64;
  const int c0 = blockIdx.y * 64;
  const int tid = threadIdx.x, lane = tid & 63, w = tid >> 6;
  const int lr = lane & 15, lg = lane >> 4;
  const int wc = w>>1, wn = w&1;
  f32x4 acc[2][2];
  #pragma unroll
  for (int ci=0;ci<2;++ci){ acc[ci][0]=(f32x4){0,0,0,0}; acc[ci][1]=(f32x4){0,0,0,0}; }
  f32x4 accq[2];
  accq[0] = (f32x4){0,0,0,0}; accq[1] = (f32x4){0,0,0,0};

  for (int k0=0; k0<128; k0+=64){
    #pragma unroll
    for (int g = tid; g < 512; g += 256){
      int r = g>>3, s = g&7;
      const long bn = (long)b*NPT + n0 + r;
      f16x8 xa = *(const f16x8*)(prev + bn*prs + k0 + s*8);
      f16x8 l  = *(const f16x8*)(lfT + bn*128 + k0 + s*8);
      f16x8 xv = xa + l;
      *(f16x8*)&Xs[r][s*8] = xv;
      if (c0 == 0) *(f16x8*)(xT + bn*128 + k0 + s*8) = xv;   // materialize x for safin
      *(float4*)&Wsh[r][s*8] = *(const float4*)(Wv + (long)(c0+r)*128 + k0 + s*8);
    }
    __syncthreads();
    #pragma unroll
    for (int ks=0; ks<2; ++ks){
      f16x8 a[2], bf[2];
      #pragma unroll
      for (int ci=0;ci<2;++ci) a[ci] = *(const f16x8*)&Wsh[wc*32 + ci*16 + lr][ks*32 + lg*8];
      #pragma unroll
      for (int ni=0;ni<2;++ni) bf[ni] = *(const f16x8*)&Xs[wn*32 + ni*16 + lr][ks*32 + lg*8];
      #pragma unroll
      for (int ci=0;ci<2;++ci)
        #pragma unroll
        for (int ni=0;ni<2;++ni) acc[ci][ni] = mfma16(a[ci], bf[ni], acc[ci][ni]);
    }
    if (c0 == 0){
      // q: A = Xs rows n (wave w owns n0+w*16..+15), B = Wq direct from global
      #pragma unroll
      for (int ks=0; ks<2; ++ks){
        f16x8 aq = *(const f16x8*)&Xs[w*16 + lr][ks*32 + lg*8];
        #pragma unroll
        for (int oi=0;oi<2;++oi){
          f16x8 bq = *(const f16x8*)(Wq + (long)(oi*16 + lr)*128 + k0 + ks*32 + lg*8);
          accq[oi] = mfma16(aq, bq, accq[oi]);
        }
      }
    }
    __syncthreads();
  }
  #pragma unroll
  for (int ci=0;ci<2;++ci)
    #pragma unroll
    for (int i=0;i<4;++i){
      const int c = c0 + wc*32 + ci*16 + lg*4 + i;
      const float bi = bv[c];
      #pragma unroll
      for (int ni=0;ni<2;++ni){
        const int n = n0 + wn*32 + ni*16 + lr;
        v16[(long)b*128*NPT + (long)c*NPT + n] = (f16)(acc[ci][ni][i] + bi);
      }
    }
  if (c0 == 0){
    #pragma unroll
    for (int oi=0;oi<2;++oi){
      const int oc = oi*16 + lr;
      #pragma unroll
      for (int i=0;i<4;++i){
        const int nn = n0 + w*16 + lg*4 + i;
        qT[((long)b*NPT + nn)*32 + oc] = (f16)accq[oi][i];
      }
    }
  }
}

// ---------------------------------------------------------------------------
// rowstats via MFMA: ralpha[n] = rmax + log(rsum) over m of e[m,n]
// (folded stats: p = exp(e - ralpha); round-5/6-verified form).
// ---------------------------------------------------------------------------
__global__ __launch_bounds__(256) void k_rowstats2(const f16* __restrict__ qT,
                                                   float* __restrict__ ralpha)
{
  const int b = blockIdx.y, n0 = blockIdx.x*64;
  const int tid = threadIdx.x, lane = tid & 63, w = tid >> 6;
  const int lr = lane & 15, lg = lane >> 4;
  const f16* qb = qT + (long)b*NPT*32;
  const f16x8 bfr = *(const f16x8*)(qb + (long)(n0 + w*16 + lr)*32 + lg*8);
  float mx = -1e30f, sm = 0.f;
  for (int m0=0; m0<NPT; m0+=32){
    f16x8 af0 = *(const f16x8*)(qb + (long)(m0+lr)*32 + lg*8);
    f16x8 af1 = *(const f16x8*)(qb + (long)(m0+16+lr)*32 + lg*8);
    f32x4 e0 = mfma16(af0, bfr, (f32x4){0,0,0,0});
    f32x4 e1 = mfma16(af1, bfr, (f32x4){0,0,0,0});
    float t0 = fmaxf(fmaxf(e0[0],e0[1]), fmaxf(e0[2],e0[3]));
    float t1 = fmaxf(fmaxf(e1[0],e1[1]), fmaxf(e1[2],e1[3]));
    float nm = fmaxf(mx, fmaxf(t0, t1));
    sm *= __expf(mx - nm);
    mx = nm;
    sm += __expf(e0[0]-mx) + __expf(e0[1]-mx) + __expf(e0[2]-mx) + __expf(e0[3]-mx)
        + __expf(e1[0]-mx) + __expf(e1[1]-mx) + __expf(e1[2]-mx) + __expf(e1[3]-mx);
  }
  #pragma unroll
  for (int d=16; d<64; d<<=1){
    float omx = __shfl_xor(mx, d, 64);
    float osm = __shfl_xor(sm, d, 64);
    float nm = fmaxf(mx, omx);
    sm = sm*__expf(mx-nm) + osm*__expf(omx-nm);
    mx = nm;
  }
  if (lane < 16)
    ralpha[(long)b*NPT + n0 + w*16 + lr] = mx + __logf(sm);
}

// ---------------------------------------------------------------------------
// pass2 PARTIAL [proven kernel: 64-m blocks, 2-deep pipelined V staging,
// one barrier/tile, ones-MFMA colsum]. Stats folded: p = exp(e - ralpha[n])
// (removes 1/rsum reciprocal + 8 muls/iter from the hot VALU pipe).
// NSEG=2. grid (32, NSEG, B).
// ---------------------------------------------------------------------------
__global__ __launch_bounds__(256) void k_pass2p(const f16* __restrict__ qT,
                                                const f16* __restrict__ v16,
                                                const float* __restrict__ ralpha,
                                                f16* __restrict__ xrpart,
                                                float* __restrict__ cspart)
{
  __shared__ __align__(16) f16 ps[64][40];      // pT[m][n-tile]; rows wave-private
  __shared__ __align__(16) f16 vs[2][128][40];  // double-buffered v-tile [c][n-tile]
  const int b = blockIdx.z, seg = blockIdx.y, m0 = blockIdx.x*64;
  const int tid = threadIdx.x, lane = tid & 63, w = tid >> 6;
  const int lr = lane & 15, lg = lane >> 4;
  const f16* qb = qT + (long)b*NPT*32;
  const f16* vb = v16 + (long)b*128*NPT;
  const float* ral = ralpha + (long)b*NPT;
  const f16x8 afe = *(const f16x8*)(qb + (long)(m0 + w*16 + lr)*32 + lg*8);  // E A-frag (rows m)
  f16x8 ones;
  #pragma unroll
  for (int j=0;j<8;++j) ones[j] = (f16)1.0f;
  f32x4 acc[8];
  #pragma unroll
  for (int cg=0; cg<8; ++cg) acc[cg] = (f32x4){0,0,0,0};
  f32x4 acc_cs = (f32x4){0,0,0,0};

  const int ntBeg = seg*(NPT/NSEG), ntEnd = ntBeg + NPT/NSEG;
  // prologue: stage first tile into vs[0]
  #pragma unroll
  for (int g = tid; g < 512; g += 256){
    int c = g>>2, s = g&3;
    *(float4*)&vs[0][c][s*8] = *(const float4*)(vb + (long)c*NPT + ntBeg + s*8);
  }
  __syncthreads();
  int cur = 0;

  for (int nt=ntBeg; nt<ntEnd; nt+=32){
    // issue next tile's staging into vs[cur^1] (loads fly under E+PV compute)
    if (nt + 32 < ntEnd){
      #pragma unroll
      for (int g = tid; g < 512; g += 256){
        int c = g>>2, s = g&3;
        *(float4*)&vs[cur^1][c][s*8] = *(const float4*)(vb + (long)c*NPT + nt + 32 + s*8);
      }
    }
    // E phase: 2 col-groups; lane col n fixed, 4 m-rows (ps wave-private)
    #pragma unroll
    for (int ng=0; ng<2; ++ng){
      f16x8 bfe = *(const f16x8*)(qb + (long)(nt + ng*16 + lr)*32 + lg*8);
      f32x4 e = mfma16(afe, bfe, (f32x4){0,0,0,0});
      const float ra = ral[nt + ng*16 + lr];
      #pragma unroll
      for (int i=0;i<4;++i){
        float p = __expf(e[i] - ra);
        ps[w*16 + lg*4 + i][ng*16 + lr] = (f16)p;
      }
    }
    // PV phase: A = pT rows m (wave-private), B = current v-tile
    f16x8 ap = *(const f16x8*)&ps[w*16 + lr][lg*8];
    #pragma unroll
    for (int cg=0; cg<8; ++cg){
      f16x8 bp = *(const f16x8*)&vs[cur][cg*16 + lr][lg*8];
      acc[cg] = mfma16(ap, bp, acc[cg]);
    }
    acc_cs = mfma16(ap, ones, acc_cs);   // colsum on matrix pipe
    __syncthreads();                      // drains staging; protects vs[cur] reuse
    cur ^= 1;
  }
  const long row = (long)(b*NSEG + seg);
  // acc_cs[i] = cs[m0 + w*16 + lg*4 + i], duplicated across lr
  if (lr == 0){
    #pragma unroll
    for (int i=0;i<4;++i)
      cspart[row*NPT + m0 + w*16 + lg*4 + i] = acc_cs[i];
  }
  // raw partial store (no renorm)
  f16* xb = xrpart + row*NPT*128;
  #pragma unroll
  for (int cg=0; cg<8; ++cg)
    #pragma unroll
    for (int i=0;i<4;++i)
      xb[(long)(m0 + w*16 + lg*4 + i)*128 + cg*16 + lr] = (f16)acc[cg][i];
}

// ---------------------------------------------------------------------------
// gmax over n per (b,c)
// ---------------------------------------------------------------------------
__global__ __launch_bounds__(1024) void k_gmaxT(const f16* __restrict__ lfT,
                                                float* __restrict__ gmaxv)
{
  __shared__ float red[8][128];
  const int b = blockIdx.x;
  const int c = threadIdx.x & 127, h = threadIdx.x >> 7;
  const f16* p = lfT + (long)b*NPT*128;
  float m = -1e30f;
  for (int n = h*256; n < (h+1)*256; ++n) m = fmaxf(m, (float)p[(long)n*128 + c]);
  red[h][c] = m; __syncthreads();
  if (threadIdx.x < 128){
    float mm = red[0][c];
    #pragma unroll
    for (int j=1;j<8;++j) mm = fmaxf(mm, red[j][c]);
    gmaxv[b*128 + c] = mm;
  }
}

__global__ __launch_bounds__(128) void k_gvec(const float* __restrict__ w0,
                                              const float* __restrict__ b0,
                                              const float* __restrict__ gmaxv,
                                              float* __restrict__ gc)
{
  const int b = blockIdx.x, o = threadIdx.x;
  __shared__ float g[128];
  g[o] = gmaxv[b*128+o]; __syncthreads();
  float acc = b0[o];
  for (int c = 0; c < 128; ++c) acc = fmaf(w0[o*256 + 128 + c], g[c], acc);
  gc[b*128+o] = acc;
}

// ---------------------------------------------------------------------------
// SA epilogue GEMM with FUSED partial merge (NSEG=2):
// xr[n][c] = (p0+p1)*inv computed inline from xrpart/cspart.
// cat[b][n][Lcol+o] = x[n][o] + relu(g'*(wt@(x-xr))+..). grid (32,2,B).
// ---------------------------------------------------------------------------
__global__ __launch_bounds__(256) void k_safin2(
    const f16* __restrict__ Wt, const float* __restrict__ bt,
    const float* __restrict__ g, const float* __restrict__ be,
    const f16* __restrict__ xT,
    const f16* __restrict__ xrpart, const float* __restrict__ cspart,
    f16* __restrict__ cat, int Lcol)
{
  __shared__ __align__(16) f16 Xs[64][72];
  __shared__ __align__(16) f16 Wsh[64][72];
  const int b  = blockIdx.z;
  const int n0 = blockIdx.x * 64;
  const int o0 = blockIdx.y * 64;
  const int tid = threadIdx.x, lane = tid & 63, w = tid >> 6;
  const int lr = lane & 15, lg = lane >> 4;
  const int wn = w>>1, wo = w&1;
  const f16* xb = xT + (long)b*NPT*128;
  f32x4 acc[2][2];
  #pragma unroll
  for (int ni=0;ni<2;++ni){ acc[ni][0]=(f32x4){0,0,0,0}; acc[ni][1]=(f32x4){0,0,0,0}; }

  for (int k0=0; k0<128; k0+=64){
    #pragma unroll
    for (int gidx = tid; gidx < 512; gidx += 256){
      int r = gidx>>3, s = gidx&7;
      const long nn = n0 + r;
      const long r0 = ((long)b*NSEG + 0)*NPT + nn;
      const long r1 = r0 + NPT;
      const float inv = 1.f/(1e-9f + cspart[r0] + cspart[r1]);
      f16x8 xa = *(const f16x8*)(xb + nn*128 + k0 + s*8);
      f16x8 p0 = *(const f16x8*)(xrpart + r0*128 + k0 + s*8);
      f16x8 p1 = *(const f16x8*)(xrpart + r1*128 + k0 + s*8);
      f16x8 xs;
      #pragma unroll
      for (int j=0;j<8;++j)
        xs[j] = (f16)((float)xa[j] - ((float)p0[j] + (float)p1[j]) * inv);
      *(f16x8*)&Xs[r][s*8] = xs;
      *(float4*)&Wsh[r][s*8] = *(const float4*)(Wt + (long)(o0+r)*128 + k0 + s*8);
    }
    __syncthreads();
    #pragma unroll
    for (int ks=0; ks<2; ++ks){
      f16x8 a[2], bf[2];
      #pragma unroll
      for (int ni=0;ni<2;++ni) a[ni] = *(const f16x8*)&Xs[wn*32 + ni*16 + lr][ks*32 + lg*8];
      #pragma unroll
      for (int oi=0;oi<2;++oi) bf[oi] = *(const f16x8*)&Wsh[wo*32 + oi*16 + lr][ks*32 + lg*8];
      #pragma unroll
      for (int ni=0;ni<2;++ni)
        #pragma unroll
        for (int oi=0;oi<2;++oi) acc[ni][oi] = mfma16(a[ni], bf[oi], acc[ni][oi]);
    }
    __syncthreads();
  }
  const float bnsc = rsqrtf(1.f + 1e-5f);
  #pragma unroll
  for (int ni=0;ni<2;++ni)
    #pragma unroll
    for (int oi=0;oi<2;++oi){
      const int oc = o0 + wo*32 + oi*16 + lr;
      const float bti = bt[oc], gi = g[oc]*bnsc, bei = be[oc];
      #pragma unroll
      for (int i=0;i<4;++i){
        const int nn = n0 + wn*32 + ni*16 + lg*4 + i;
        float t = acc[ni][oi][i] + bti;
        float val = fmaxf(fmaf(gi, t, bei), 0.f);
        float res = (float)xb[(long)nn*128 + oc];
        cat[(long)b*NPT*384 + (long)nn*384 + Lcol + oc] = (f16)(res + val);
      }
    }
}

__global__ __launch_bounds__(256) void k_maxfinal(const float* __restrict__ part,
                                                  float* __restrict__ out)
{
  const int t = blockIdx.x*256 + threadIdx.x;   // 0..16383
  float m = -1e30f;
  #pragma unroll
  for (int j=0;j<16;++j) m = fmaxf(m, part[(long)t*16 + j]);
  out[t] = m;
}

// ---------------------------------------------------------------------------
extern "C" void kernel_launch(void* const* d_in, const int* in_sizes, int n_in,
                              void* d_out, int out_size, void* d_ws, size_t ws_size,
                              hipStream_t stream)
{
  const float* in   = (const float*)d_in[0];
  const float* m1w0 = (const float*)d_in[1];
  const float* m1b0 = (const float*)d_in[2];
  const float* m1w1 = (const float*)d_in[3];
  const float* m1b1 = (const float*)d_in[4];
  const float* m2w0 = (const float*)d_in[5];
  const float* m2b0 = (const float*)d_in[6];
  const float* m2w1 = (const float*)d_in[7];
  const float* m2b1 = (const float*)d_in[8];
  const float* m3w0 = (const float*)d_in[9];
  const float* m3b0 = (const float*)d_in[10];
  const float* m3w1 = (const float*)d_in[11];
  const float* m3b1 = (const float*)d_in[12];

  // ws layout (halfs)
  f16* ws16 = (f16*)d_ws;
  f16* W16  = ws16;                       // 880,640
  f16* lfT  = ws16 + 880640;              // [B][N][128]
  f16* xT   = ws16 + 5074944;             // [B][N][128]
  f16* qT   = ws16 + 9269248;             // [B][N][32]
  f16* vbuf = ws16 + 10317824;            // [B][128][N]
  f16* xrT  = ws16 + 14512128;            // [B][N][128] (mlp2 features; never clobbered)
  f16* hT   = ws16 + 18706432;            // [B][N][512] (mlp hidden)
  f16* xrpart = hT;                       // [B*NSEG][N][128] — aliases hT (dead during SA)
  f16* catT = ws16 + 35483648;            // [B][N][384]
  float* fb = (float*)(ws16 + 48066560);
  float* ralpha = fb;                     // [B,N] (folded rmax+log(rsum))
  float* gmaxv  = fb + 65536;             // [B,128]
  float* gc     = fb + 67584;             // [B,128]
  float* part   = fb + 69632;             // [B,1024,16]
  float* cspart = fb + 593920;            // [B*NSEG][N]

  const dim3 blk(256);

  k_wconv<<<dim3((WTOT+255)/256), blk, 0, stream>>>(
      m1w1, m2w0, m2w1, m3w0, m3w1,
      (const float*)d_in[13], (const float*)d_in[14], (const float*)d_in[16],
      (const float*)d_in[20], (const float*)d_in[21], (const float*)d_in[23],
      (const float*)d_in[27], (const float*)d_in[28], (const float*)d_in[30],
      W16);

  // mlp1
  k_mlp1aT<<<dim3(NBAT*NPT*32/256), blk, 0, stream>>>(in, m1w0, m1b0, hT);
  gemmT<64,false,false><<<dim3(32,2,NBAT), blk, 0, stream>>>(
      W16+OFF_M1W1, m1b1, nullptr, hT, 128, lfT, 128, 0, 128);
  // global max + mlp2
  k_gmaxT<<<dim3(NBAT), dim3(1024), 0, stream>>>(lfT, gmaxv);
  k_gvec<<<dim3(NBAT), dim3(128), 0, stream>>>(m2w0, m2b0, gmaxv, gc);
  gemmT<64,true,true><<<dim3(32,2,NBAT), blk, 0, stream>>>(
      W16+OFF_M2W0A, nullptr, gc, lfT, 128, hT, 128, 0, 128);
  gemmT<64,false,false><<<dim3(32,2,NBAT), blk, 0, stream>>>(
      W16+OFF_M2W1, m2b1, nullptr, hT, 128, xrT, 128, 0, 128);   // features -> xrT

  // 3 SA layers (addT, qgemm, pmerge all fused away; folded softmax stats)
  for (int L = 0; L < 3; ++L){
    const float* bv = (const float*)d_in[13 + L*7 + 2];
    const float* bt = (const float*)d_in[13 + L*7 + 4];
    const float* gg = (const float*)d_in[13 + L*7 + 5];
    const float* be = (const float*)d_in[13 + L*7 + 6];
    const f16* wq16 = W16 + OFF_SA + L*SA_STRIDE;
    const f16* wv16 = wq16 + 4096;
    const f16* wt16 = wq16 + 20480;

    const f16* prev = (L==0) ? xrT : (catT + (long)(L-1)*128);
    const int  prs  = (L==0) ? 128 : 384;

    k_vqgemmF<<<dim3(32,2,NBAT), blk, 0, stream>>>(
        wv16, bv, wq16, prev, prs, lfT, vbuf, xT, qT);
    k_rowstats2<<<dim3(32,NBAT), blk, 0, stream>>>(qT, ralpha);
    k_pass2p<<<dim3(32,NSEG,NBAT), blk, 0, stream>>>(qT, vbuf, ralpha, xrpart, cspart);
    k_safin2<<<dim3(32,2,NBAT), blk, 0, stream>>>(
        wt16, bt, gg, be, xT, xrpart, cspart, catT, L*128);
  }

  // mlp3: layer0 (384->512 relu) 128x128 tile, layer1 fused-max 128x128
  gemm128<true><<<dim3(16,4,NBAT), blk, 0, stream>>>(
      W16+OFF_M3W0, m3b0, catT, 384, hT, 512, 384);
  k_gemmax128<<<dim3(16,8,NBAT), blk, 0, stream>>>(W16+OFF_M3W1, m3b1, hT, part);
  k_maxfinal<<<dim3(64), blk, 0, stream>>>(part, (float*)d_out);
}

// Round 20
// 408.071 us; speedup vs baseline: 1.2345x; 1.1005x over previous
//
#include <hip/hip_runtime.h>
#include <hip/hip_bf16.h>
#include <cfloat>

static constexpr int NBAT = 16;
static constexpr int NPT  = 2048;
static constexpr int NSEG = 2;     // pass2 n-split segments

typedef _Float16 f16;
typedef _Float16 f16x8 __attribute__((ext_vector_type(8)));
typedef float    f32x4 __attribute__((ext_vector_type(4)));

static __device__ __forceinline__ f32x4 mfma16(f16x8 a, f16x8 b, f32x4 c){
  return __builtin_amdgcn_mfma_f32_16x16x32_f16(a, b, c, 0, 0, 0);
}
// MFMA 16x16x32 f16 layouts (gfx950, e2e-verified by round-4 pass):
//  A[16r x 32k]: lane l -> row l&15, k = (l>>4)*8 + j (16B contiguous)
//  B[32k x 16c]: lane l -> col l&15, k = (l>>4)*8 + j (16B contiguous)
//  D[16r x 16c]: lane l -> col l&15, rows (l>>4)*4 + i

// ---- weight arena offsets (halfs) ----
static constexpr long OFF_M1W1 = 0;              // [128][128]
static constexpr long OFF_M2W0A= 16384;          // [128][128] (cols 0..127 of [128][256])
static constexpr long OFF_M2W1 = 32768;          // [128][128]
static constexpr long OFF_M3W0 = 49152;          // [512][384]
static constexpr long OFF_M3W1 = 245760;         // [1024][512]
static constexpr long OFF_SA   = 770048;         // per-L: wq[32][128], wv[128][128], wt[128][128]
static constexpr long SA_STRIDE= 36864;
static constexpr long WTOT     = OFF_SA + 3*SA_STRIDE;   // 880,640 halfs

// ---------------------------------------------------------------------------
// weight fp32 -> fp16 conversion into arena (one launch)
// ---------------------------------------------------------------------------
__global__ __launch_bounds__(256) void k_wconv(
    const float* m1w1, const float* m2w0, const float* m2w1,
    const float* m3w0, const float* m3w1,
    const float* wq0, const float* wv0, const float* wt0,
    const float* wq1, const float* wv1, const float* wt1,
    const float* wq2, const float* wv2, const float* wt2,
    f16* W)
{
  long t = (long)blockIdx.x*256 + threadIdx.x;
  if (t >= WTOT) return;
  float v;
  if      (t < OFF_M2W0A) v = m1w1[t];
  else if (t < OFF_M2W1) { long u = t-OFF_M2W0A; v = m2w0[(u>>7)*256 + (u&127)]; }
  else if (t < OFF_M3W0)  v = m2w1[t-OFF_M2W1];
  else if (t < OFF_M3W1)  v = m3w0[t-OFF_M3W0];
  else if (t < OFF_SA)    v = m3w1[t-OFF_M3W1];
  else {
    long u = t - OFF_SA; int L = (int)(u / SA_STRIDE); long r = u % SA_STRIDE;
    const float* wq = (L==0)?wq0:(L==1)?wq1:wq2;
    const float* wv = (L==0)?wv0:(L==1)?wv1:wv2;
    const float* wt = (L==0)?wt0:(L==1)?wt1:wt2;
    if (r < 4096) v = wq[r]; else if (r < 20480) v = wv[r-4096]; else v = wt[r-20480];
  }
  W[t] = (f16)v;
}

// ---------------------------------------------------------------------------
// mlp1 layer0 (K=3): h1T[b][n][o] = relu(b0[o] + sum_c w0[o][c]*in[b][n][c])
// ---------------------------------------------------------------------------
__global__ __launch_bounds__(256) void k_mlp1aT(const float* __restrict__ in,
                                                const float* __restrict__ w0,
                                                const float* __restrict__ b0,
                                                f16* __restrict__ h1T)
{
  long idx = (long)blockIdx.x*256 + threadIdx.x;
  int og = idx & 31; long bn = idx >> 5;
  const float* ip = in + bn*3;
  float x0=ip[0], x1=ip[1], x2=ip[2];
  f16* op = h1T + bn*128 + og*4;
  #pragma unroll
  for (int i=0;i<4;++i){
    int o = og*4+i;
    float v = b0[o] + w0[o*3]*x0 + w0[o*3+1]*x1 + w0[o*3+2]*x2;
    op[i] = (f16)fmaxf(v, 0.f);
  }
}

// ---------------------------------------------------------------------------
// generic transposed conv GEMM: OUTT[b][n][ocol+o] = act(bias + sum_k XT[b][n][k]*W[o][k])
// ---------------------------------------------------------------------------
template<int OT, bool RELU, bool B2D>
__global__ __launch_bounds__(256) void gemmT(
    const f16* __restrict__ W, const float* __restrict__ bias,
    const float* __restrict__ bias2d,
    const f16* __restrict__ XT, int xrs,
    f16* __restrict__ OUT, int ors, int ocol, int K)
{
  __shared__ __align__(16) f16 Xs[64][72];
  __shared__ __align__(16) f16 Wsh[OT][72];
  const int b  = blockIdx.z;
  const int n0 = blockIdx.x * 64;
  const int o0 = blockIdx.y * OT;
  const int tid = threadIdx.x, lane = tid & 63, w = tid >> 6;
  const int lr = lane & 15, lg = lane >> 4;
  constexpr int NSUB = (OT==64)?2:1;
  const int wn = (OT==64)? (w>>1) : w;
  const int wo = (OT==64)? (w&1) : 0;
  const int nbase = wn*(16*NSUB);
  const f16* Xb = XT + (long)b*NPT*xrs;
  f32x4 acc[NSUB][2];
  #pragma unroll
  for (int ni=0;ni<NSUB;++ni){ acc[ni][0]=(f32x4){0,0,0,0}; acc[ni][1]=(f32x4){0,0,0,0}; }

  for (int k0=0; k0<K; k0+=64){
    #pragma unroll
    for (int g = tid; g < 512; g += 256){
      int r = g>>3, s = g&7;
      *(float4*)&Xs[r][s*8] = *(const float4*)(Xb + (long)(n0+r)*xrs + k0 + s*8);
    }
    for (int g = tid; g < OT*8; g += 256){
      int r = g>>3, s = g&7;
      *(float4*)&Wsh[r][s*8] = *(const float4*)(W + (long)(o0+r)*K + k0 + s*8);
    }
    __syncthreads();
    #pragma unroll
    for (int ks=0; ks<2; ++ks){
      f16x8 a[NSUB], bf[2];
      #pragma unroll
      for (int ni=0;ni<NSUB;++ni) a[ni] = *(const f16x8*)&Xs[nbase + ni*16 + lr][ks*32 + lg*8];
      #pragma unroll
      for (int oi=0;oi<2;++oi)   bf[oi] = *(const f16x8*)&Wsh[wo*32 + oi*16 + lr][ks*32 + lg*8];
      #pragma unroll
      for (int ni=0;ni<NSUB;++ni)
        #pragma unroll
        for (int oi=0;oi<2;++oi) acc[ni][oi] = mfma16(a[ni], bf[oi], acc[ni][oi]);
    }
    __syncthreads();
  }
  #pragma unroll
  for (int ni=0;ni<NSUB;++ni)
    #pragma unroll
    for (int oi=0;oi<2;++oi){
      const int oc = o0 + wo*32 + oi*16 + lr;
      float bi = bias ? bias[oc] : 0.f;
      if constexpr (B2D) bi += bias2d[b*128 + oc];
      #pragma unroll
      for (int i=0;i<4;++i){
        const int nn = n0 + nbase + ni*16 + lg*4 + i;
        float v = acc[ni][oi][i] + bi;
        if constexpr (RELU) v = fmaxf(v, 0.f);
        OUT[(long)b*NPT*ors + (long)nn*ors + ocol + oc] = (f16)v;
      }
    }
}

// ---------------------------------------------------------------------------
// 128x128-tile GEMM (4 waves as 2x2, each wave 64x64, acc[4][4]):
// __launch_bounds__(256,4): cap regs at 128/thread -> 4 blocks/CU.
// ---------------------------------------------------------------------------
template<bool RELU>
__global__ __launch_bounds__(256, 4) void gemm128(
    const f16* __restrict__ W, const float* __restrict__ bias,
    const f16* __restrict__ XT, int xrs,
    f16* __restrict__ OUT, int ors, int K)
{
  __shared__ __align__(16) f16 Xs[128][72];
  __shared__ __align__(16) f16 Wsh[128][72];
  const int b  = blockIdx.z;
  const int n0 = blockIdx.x * 128;
  const int o0 = blockIdx.y * 128;
  const int tid = threadIdx.x, lane = tid & 63, w = tid >> 6;
  const int lr = lane & 15, lg = lane >> 4;
  const int wn = w >> 1, wo = w & 1;
  const f16* Xb = XT + (long)b*NPT*xrs;
  f32x4 acc[4][4];
  #pragma unroll
  for (int ni=0;ni<4;++ni)
    #pragma unroll
    for (int oi=0;oi<4;++oi) acc[ni][oi] = (f32x4){0,0,0,0};

  for (int k0=0; k0<K; k0+=64){
    #pragma unroll
    for (int g = tid; g < 1024; g += 256){
      int r = g>>3, s = g&7;
      *(float4*)&Xs[r][s*8]  = *(const float4*)(Xb + (long)(n0+r)*xrs + k0 + s*8);
      *(float4*)&Wsh[r][s*8] = *(const float4*)(W + (long)(o0+r)*K + k0 + s*8);
    }
    __syncthreads();
    #pragma unroll
    for (int ks=0; ks<2; ++ks){
      f16x8 a[4], bf[4];
      #pragma unroll
      for (int ni=0;ni<4;++ni) a[ni]  = *(const f16x8*)&Xs[wn*64 + ni*16 + lr][ks*32 + lg*8];
      #pragma unroll
      for (int oi=0;oi<4;++oi) bf[oi] = *(const f16x8*)&Wsh[wo*64 + oi*16 + lr][ks*32 + lg*8];
      #pragma unroll
      for (int ni=0;ni<4;++ni)
        #pragma unroll
        for (int oi=0;oi<4;++oi) acc[ni][oi] = mfma16(a[ni], bf[oi], acc[ni][oi]);
    }
    __syncthreads();
  }
  #pragma unroll
  for (int ni=0;ni<4;++ni)
    #pragma unroll
    for (int oi=0;oi<4;++oi){
      const int oc = o0 + wo*64 + oi*16 + lr;
      const float bi = bias[oc];
      #pragma unroll
      for (int i=0;i<4;++i){
        const int nn = n0 + wn*64 + ni*16 + lg*4 + i;
        float v = acc[ni][oi][i] + bi;
        if constexpr (RELU) v = fmaxf(v, 0.f);
        OUT[(long)b*NPT*ors + (long)nn*ors + oc] = (f16)v;
      }
    }
}

// ---------------------------------------------------------------------------
// mlp3 layer1 with fused max, 128x128 tile. grid (16, 8, B). K=512.
// ---------------------------------------------------------------------------
__global__ __launch_bounds__(256, 4) void k_gemmax128(
    const f16* __restrict__ W, const float* __restrict__ bias,
    const f16* __restrict__ XT, float* __restrict__ part)
{
  __shared__ __align__(16) f16 Xs[128][72];
  __shared__ __align__(16) f16 Wsh[128][72];
  __shared__ float red[2][128];
  const int b  = blockIdx.z;
  const int n0 = blockIdx.x * 128;
  const int o0 = blockIdx.y * 128;
  const int tid = threadIdx.x, lane = tid & 63, w = tid >> 6;
  const int lr = lane & 15, lg = lane >> 4;
  const int wn = w >> 1, wo = w & 1;
  const f16* Xb = XT + (long)b*NPT*512;
  f32x4 acc[4][4];
  #pragma unroll
  for (int ni=0;ni<4;++ni)
    #pragma unroll
    for (int oi=0;oi<4;++oi) acc[ni][oi] = (f32x4){0,0,0,0};

  for (int k0=0; k0<512; k0+=64){
    #pragma unroll
    for (int g = tid; g < 1024; g += 256){
      int r = g>>3, s = g&7;
      *(float4*)&Xs[r][s*8]  = *(const float4*)(Xb + (long)(n0+r)*512 + k0 + s*8);
      *(float4*)&Wsh[r][s*8] = *(const float4*)(W + (long)(o0+r)*512 + k0 + s*8);
    }
    __syncthreads();
    #pragma unroll
    for (int ks=0; ks<2; ++ks){
      f16x8 a[4], bf[4];
      #pragma unroll
      for (int ni=0;ni<4;++ni) a[ni]  = *(const f16x8*)&Xs[wn*64 + ni*16 + lr][ks*32 + lg*8];
      #pragma unroll
      for (int oi=0;oi<4;++oi) bf[oi] = *(const f16x8*)&Wsh[wo*64 + oi*16 + lr][ks*32 + lg*8];
      #pragma unroll
      for (int ni=0;ni<4;++ni)
        #pragma unroll
        for (int oi=0;oi<4;++oi) acc[ni][oi] = mfma16(a[ni], bf[oi], acc[ni][oi]);
    }
    __syncthreads();
  }
  #pragma unroll
  for (int oi=0;oi<4;++oi){
    const int oc128 = wo*64 + oi*16 + lr;
    const float bi = bias[o0 + oc128];
    float mv = -1e30f;
    #pragma unroll
    for (int ni=0;ni<4;++ni)
      #pragma unroll
      for (int i=0;i<4;++i) mv = fmaxf(mv, acc[ni][oi][i] + bi);
    mv = fmaxf(mv, __shfl_xor(mv, 16, 64));
    mv = fmaxf(mv, __shfl_xor(mv, 32, 64));
    if (lg == 0) red[wn][oc128] = mv;
  }
  __syncthreads();
  if (tid < 128)
    part[((long)b*1024 + o0 + tid)*16 + blockIdx.x] = fmaxf(red[0][tid], red[1][tid]);
}

// ---------------------------------------------------------------------------
// FUSED v+q GEMM: x = prev + lfT computed in staging.
// v16[b][c][n] for all blocks; c0==0 blocks compute qT (o<32, Wq direct from
// global); c0!=0 blocks write staged x to xT (r20: balances the q work that
// lives on the c0==0 half). grid (32, 2, B).
// ---------------------------------------------------------------------------
__global__ __launch_bounds__(256) void k_vqgemmF(
    const f16* __restrict__ Wv, const float* __restrict__ bv,
    const f16* __restrict__ Wq,
    const f16* __restrict__ prev, int prs,
    const f16* __restrict__ lfT,
    f16* __restrict__ v16, f16* __restrict__ xT, f16* __restrict__ qT)
{
  __shared__ __align__(16) f16 Xs[64][72];
  __shared__ __align__(16) f16 Wsh[64][72];
  const int b  = blockIdx.z;
  const int n0 = blockIdx.x * 64;
  const int c0 = blockIdx.y * 64;
  const int tid = threadIdx.x, lane = tid & 63, w = tid >> 6;
  const int lr = lane & 15, lg = lane >> 4;
  const int wc = w>>1, wn = w&1;
  f32x4 acc[2][2];
  #pragma unroll
  for (int ci=0;ci<2;++ci){ acc[ci][0]=(f32x4){0,0,0,0}; acc[ci][1]=(f32x4){0,0,0,0}; }
  f32x4 accq[2];
  accq[0] = (f32x4){0,0,0,0}; accq[1] = (f32x4){0,0,0,0};

  for (int k0=0; k0<128; k0+=64){
    #pragma unroll
    for (int g = tid; g < 512; g += 256){
      int r = g>>3, s = g&7;
      const long bn = (long)b*NPT + n0 + r;
      f16x8 xa = *(const f16x8*)(prev + bn*prs + k0 + s*8);
      f16x8 l  = *(const f16x8*)(lfT + bn*128 + k0 + s*8);
      f16x8 xv = xa + l;
      *(f16x8*)&Xs[r][s*8] = xv;
      if (c0 != 0) *(f16x8*)(xT + bn*128 + k0 + s*8) = xv;   // x for safin (balanced half)
      *(float4*)&Wsh[r][s*8] = *(const float4*)(Wv + (long)(c0+r)*128 + k0 + s*8);
    }
    __syncthreads();
    #pragma unroll
    for (int ks=0; ks<2; ++ks){
      f16x8 a[2], bf[2];
      #pragma unroll
      for (int ci=0;ci<2;++ci) a[ci] = *(const f16x8*)&Wsh[wc*32 + ci*16 + lr][ks*32 + lg*8];
      #pragma unroll
      for (int ni=0;ni<2;++ni) bf[ni] = *(const f16x8*)&Xs[wn*32 + ni*16 + lr][ks*32 + lg*8];
      #pragma unroll
      for (int ci=0;ci<2;++ci)
        #pragma unroll
        for (int ni=0;ni<2;++ni) acc[ci][ni] = mfma16(a[ci], bf[ni], acc[ci][ni]);
    }
    if (c0 == 0){
      // q: A = Xs rows n (wave w owns n0+w*16..+15), B = Wq direct from global
      #pragma unroll
      for (int ks=0; ks<2; ++ks){
        f16x8 aq = *(const f16x8*)&Xs[w*16 + lr][ks*32 + lg*8];
        #pragma unroll
        for (int oi=0;oi<2;++oi){
          f16x8 bq = *(const f16x8*)(Wq + (long)(oi*16 + lr)*128 + k0 + ks*32 + lg*8);
          accq[oi] = mfma16(aq, bq, accq[oi]);
        }
      }
    }
    __syncthreads();
  }
  #pragma unroll
  for (int ci=0;ci<2;++ci)
    #pragma unroll
    for (int i=0;i<4;++i){
      const int c = c0 + wc*32 + ci*16 + lg*4 + i;
      const float bi = bv[c];
      #pragma unroll
      for (int ni=0;ni<2;++ni){
        const int n = n0 + wn*32 + ni*16 + lr;
        v16[(long)b*128*NPT + (long)c*NPT + n] = (f16)(acc[ci][ni][i] + bi);
      }
    }
  if (c0 == 0){
    #pragma unroll
    for (int oi=0;oi<2;++oi){
      const int oc = oi*16 + lr;
      #pragma unroll
      for (int i=0;i<4;++i){
        const int nn = n0 + w*16 + lg*4 + i;
        qT[((long)b*NPT + nn)*32 + oc] = (f16)accq[oi][i];
      }
    }
  }
}

// ---------------------------------------------------------------------------
// rowstats via MFMA: ralpha[n] = rmax + log(rsum) over m of e[m,n]
// (folded stats: p = exp(e - ralpha)).
// ---------------------------------------------------------------------------
__global__ __launch_bounds__(256) void k_rowstats2(const f16* __restrict__ qT,
                                                   float* __restrict__ ralpha)
{
  const int b = blockIdx.y, n0 = blockIdx.x*64;
  const int tid = threadIdx.x, lane = tid & 63, w = tid >> 6;
  const int lr = lane & 15, lg = lane >> 4;
  const f16* qb = qT + (long)b*NPT*32;
  const f16x8 bfr = *(const f16x8*)(qb + (long)(n0 + w*16 + lr)*32 + lg*8);
  float mx = -1e30f, sm = 0.f;
  for (int m0=0; m0<NPT; m0+=32){
    f16x8 af0 = *(const f16x8*)(qb + (long)(m0+lr)*32 + lg*8);
    f16x8 af1 = *(const f16x8*)(qb + (long)(m0+16+lr)*32 + lg*8);
    f32x4 e0 = mfma16(af0, bfr, (f32x4){0,0,0,0});
    f32x4 e1 = mfma16(af1, bfr, (f32x4){0,0,0,0});
    float t0 = fmaxf(fmaxf(e0[0],e0[1]), fmaxf(e0[2],e0[3]));
    float t1 = fmaxf(fmaxf(e1[0],e1[1]), fmaxf(e1[2],e1[3]));
    float nm = fmaxf(mx, fmaxf(t0, t1));
    sm *= __expf(mx - nm);
    mx = nm;
    sm += __expf(e0[0]-mx) + __expf(e0[1]-mx) + __expf(e0[2]-mx) + __expf(e0[3]-mx)
        + __expf(e1[0]-mx) + __expf(e1[1]-mx) + __expf(e1[2]-mx) + __expf(e1[3]-mx);
  }
  #pragma unroll
  for (int d=16; d<64; d<<=1){
    float omx = __shfl_xor(mx, d, 64);
    float osm = __shfl_xor(sm, d, 64);
    float nm = fmaxf(mx, omx);
    sm = sm*__expf(mx-nm) + osm*__expf(omx-nm);
    mx = nm;
  }
  if (lane < 16)
    ralpha[(long)b*NPT + n0 + w*16 + lr] = mx + __logf(sm);
}

// ---------------------------------------------------------------------------
// pass2 PARTIAL [proven kernel: 64-m blocks, 2-deep pipelined V staging,
// one barrier/tile, ones-MFMA colsum, folded stats]. NSEG=2. grid (32,NSEG,B).
// ---------------------------------------------------------------------------
__global__ __launch_bounds__(256) void k_pass2p(const f16* __restrict__ qT,
                                                const f16* __restrict__ v16,
                                                const float* __restrict__ ralpha,
                                                f16* __restrict__ xrpart,
                                                float* __restrict__ cspart)
{
  __shared__ __align__(16) f16 ps[64][40];      // pT[m][n-tile]; rows wave-private
  __shared__ __align__(16) f16 vs[2][128][40];  // double-buffered v-tile [c][n-tile]
  const int b = blockIdx.z, seg = blockIdx.y, m0 = blockIdx.x*64;
  const int tid = threadIdx.x, lane = tid & 63, w = tid >> 6;
  const int lr = lane & 15, lg = lane >> 4;
  const f16* qb = qT + (long)b*NPT*32;
  const f16* vb = v16 + (long)b*128*NPT;
  const float* ral = ralpha + (long)b*NPT;
  const f16x8 afe = *(const f16x8*)(qb + (long)(m0 + w*16 + lr)*32 + lg*8);  // E A-frag (rows m)
  f16x8 ones;
  #pragma unroll
  for (int j=0;j<8;++j) ones[j] = (f16)1.0f;
  f32x4 acc[8];
  #pragma unroll
  for (int cg=0; cg<8; ++cg) acc[cg] = (f32x4){0,0,0,0};
  f32x4 acc_cs = (f32x4){0,0,0,0};

  const int ntBeg = seg*(NPT/NSEG), ntEnd = ntBeg + NPT/NSEG;
  // prologue: stage first tile into vs[0]
  #pragma unroll
  for (int g = tid; g < 512; g += 256){
    int c = g>>2, s = g&3;
    *(float4*)&vs[0][c][s*8] = *(const float4*)(vb + (long)c*NPT + ntBeg + s*8);
  }
  __syncthreads();
  int cur = 0;

  for (int nt=ntBeg; nt<ntEnd; nt+=32){
    // issue next tile's staging into vs[cur^1] (loads fly under E+PV compute)
    if (nt + 32 < ntEnd){
      #pragma unroll
      for (int g = tid; g < 512; g += 256){
        int c = g>>2, s = g&3;
        *(float4*)&vs[cur^1][c][s*8] = *(const float4*)(vb + (long)c*NPT + nt + 32 + s*8);
      }
    }
    // E phase: 2 col-groups; lane col n fixed, 4 m-rows (ps wave-private)
    #pragma unroll
    for (int ng=0; ng<2; ++ng){
      f16x8 bfe = *(const f16x8*)(qb + (long)(nt + ng*16 + lr)*32 + lg*8);
      f32x4 e = mfma16(afe, bfe, (f32x4){0,0,0,0});
      const float ra = ral[nt + ng*16 + lr];
      #pragma unroll
      for (int i=0;i<4;++i){
        float p = __expf(e[i] - ra);
        ps[w*16 + lg*4 + i][ng*16 + lr] = (f16)p;
      }
    }
    // PV phase: A = pT rows m (wave-private), B = current v-tile
    f16x8 ap = *(const f16x8*)&ps[w*16 + lr][lg*8];
    #pragma unroll
    for (int cg=0; cg<8; ++cg){
      f16x8 bp = *(const f16x8*)&vs[cur][cg*16 + lr][lg*8];
      acc[cg] = mfma16(ap, bp, acc[cg]);
    }
    acc_cs = mfma16(ap, ones, acc_cs);   // colsum on matrix pipe
    __syncthreads();                      // drains staging; protects vs[cur] reuse
    cur ^= 1;
  }
  const long row = (long)(b*NSEG + seg);
  // acc_cs[i] = cs[m0 + w*16 + lg*4 + i], duplicated across lr
  if (lr == 0){
    #pragma unroll
    for (int i=0;i<4;++i)
      cspart[row*NPT + m0 + w*16 + lg*4 + i] = acc_cs[i];
  }
  // raw partial store (no renorm)
  f16* xb = xrpart + row*NPT*128;
  #pragma unroll
  for (int cg=0; cg<8; ++cg)
    #pragma unroll
    for (int i=0;i<4;++i)
      xb[(long)(m0 + w*16 + lg*4 + i)*128 + cg*16 + lr] = (f16)acc[cg][i];
}

// ---------------------------------------------------------------------------
// gmax over n per (b,c): WIDENED (r20) grid (B*8) blocks of 1024; block h
// covers n in [h*256,(h+1)*256); partials to gmax8[b][h][c].
// ---------------------------------------------------------------------------
__global__ __launch_bounds__(1024) void k_gmaxT(const f16* __restrict__ lfT,
                                                float* __restrict__ gmax8)
{
  __shared__ float red[8][128];
  const int b = blockIdx.x >> 3, h = blockIdx.x & 7;
  const int c = threadIdx.x & 127, r = threadIdx.x >> 7;   // r: 0..7
  const f16* p = lfT + (long)b*NPT*128;
  float m = -1e30f;
  for (int n = h*256 + r; n < (h+1)*256; n += 8) m = fmaxf(m, (float)p[(long)n*128 + c]);
  red[r][c] = m; __syncthreads();
  if (threadIdx.x < 128){
    float mm = red[0][c];
    #pragma unroll
    for (int j=1;j<8;++j) mm = fmaxf(mm, red[j][c]);
    gmax8[((long)b*8 + h)*128 + c] = mm;
  }
}

// gc[b][o] = b0[o] + sum_c w0[o][128+c]*gmax[b][c]; gmax folded from 8 partials
__global__ __launch_bounds__(128) void k_gvec(const float* __restrict__ w0,
                                              const float* __restrict__ b0,
                                              const float* __restrict__ gmax8,
                                              float* __restrict__ gc)
{
  const int b = blockIdx.x, o = threadIdx.x;
  __shared__ float g[128];
  float mm = gmax8[((long)b*8 + 0)*128 + o];
  #pragma unroll
  for (int h=1;h<8;++h) mm = fmaxf(mm, gmax8[((long)b*8 + h)*128 + o]);
  g[o] = mm; __syncthreads();
  float acc = b0[o];
  for (int c = 0; c < 128; ++c) acc = fmaf(w0[o*256 + 128 + c], g[c], acc);
  gc[b*128+o] = acc;
}

// ---------------------------------------------------------------------------
// SA epilogue GEMM with FUSED partial merge (NSEG=2):
// xr[n][c] = (p0+p1)*inv computed inline from xrpart/cspart.
// cat[b][n][Lcol+o] = x[n][o] + relu(g'*(wt@(x-xr))+..). grid (32,2,B).
// ---------------------------------------------------------------------------
__global__ __launch_bounds__(256) void k_safin2(
    const f16* __restrict__ Wt, const float* __restrict__ bt,
    const float* __restrict__ g, const float* __restrict__ be,
    const f16* __restrict__ xT,
    const f16* __restrict__ xrpart, const float* __restrict__ cspart,
    f16* __restrict__ cat, int Lcol)
{
  __shared__ __align__(16) f16 Xs[64][72];
  __shared__ __align__(16) f16 Wsh[64][72];
  const int b  = blockIdx.z;
  const int n0 = blockIdx.x * 64;
  const int o0 = blockIdx.y * 64;
  const int tid = threadIdx.x, lane = tid & 63, w = tid >> 6;
  const int lr = lane & 15, lg = lane >> 4;
  const int wn = w>>1, wo = w&1;
  const f16* xb = xT + (long)b*NPT*128;
  f32x4 acc[2][2];
  #pragma unroll
  for (int ni=0;ni<2;++ni){ acc[ni][0]=(f32x4){0,0,0,0}; acc[ni][1]=(f32x4){0,0,0,0}; }

  for (int k0=0; k0<128; k0+=64){
    #pragma unroll
    for (int gidx = tid; gidx < 512; gidx += 256){
      int r = gidx>>3, s = gidx&7;
      const long nn = n0 + r;
      const long r0 = ((long)b*NSEG + 0)*NPT + nn;
      const long r1 = r0 + NPT;
      const float inv = 1.f/(1e-9f + cspart[r0] + cspart[r1]);
      f16x8 xa = *(const f16x8*)(xb + nn*128 + k0 + s*8);
      f16x8 p0 = *(const f16x8*)(xrpart + r0*128 + k0 + s*8);
      f16x8 p1 = *(const f16x8*)(xrpart + r1*128 + k0 + s*8);
      f16x8 xs;
      #pragma unroll
      for (int j=0;j<8;++j)
        xs[j] = (f16)((float)xa[j] - ((float)p0[j] + (float)p1[j]) * inv);
      *(f16x8*)&Xs[r][s*8] = xs;
      *(float4*)&Wsh[r][s*8] = *(const float4*)(Wt + (long)(o0+r)*128 + k0 + s*8);
    }
    __syncthreads();
    #pragma unroll
    for (int ks=0; ks<2; ++ks){
      f16x8 a[2], bf[2];
      #pragma unroll
      for (int ni=0;ni<2;++ni) a[ni] = *(const f16x8*)&Xs[wn*32 + ni*16 + lr][ks*32 + lg*8];
      #pragma unroll
      for (int oi=0;oi<2;++oi) bf[oi] = *(const f16x8*)&Wsh[wo*32 + oi*16 + lr][ks*32 + lg*8];
      #pragma unroll
      for (int ni=0;ni<2;++ni)
        #pragma unroll
        for (int oi=0;oi<2;++oi) acc[ni][oi] = mfma16(a[ni], bf[oi], acc[ni][oi]);
    }
    __syncthreads();
  }
  const float bnsc = rsqrtf(1.f + 1e-5f);
  #pragma unroll
  for (int ni=0;ni<2;++ni)
    #pragma unroll
    for (int oi=0;oi<2;++oi){
      const int oc = o0 + wo*32 + oi*16 + lr;
      const float bti = bt[oc], gi = g[oc]*bnsc, bei = be[oc];
      #pragma unroll
      for (int i=0;i<4;++i){
        const int nn = n0 + wn*32 + ni*16 + lg*4 + i;
        float t = acc[ni][oi][i] + bti;
        float val = fmaxf(fmaf(gi, t, bei), 0.f);
        float res = (float)xb[(long)nn*128 + oc];
        cat[(long)b*NPT*384 + (long)nn*384 + Lcol + oc] = (f16)(res + val);
      }
    }
}

__global__ __launch_bounds__(256) void k_maxfinal(const float* __restrict__ part,
                                                  float* __restrict__ out)
{
  const int t = blockIdx.x*256 + threadIdx.x;   // 0..16383
  float m = -1e30f;
  #pragma unroll
  for (int j=0;j<16;++j) m = fmaxf(m, part[(long)t*16 + j]);
  out[t] = m;
}

// ---------------------------------------------------------------------------
extern "C" void kernel_launch(void* const* d_in, const int* in_sizes, int n_in,
                              void* d_out, int out_size, void* d_ws, size_t ws_size,
                              hipStream_t stream)
{
  const float* in   = (const float*)d_in[0];
  const float* m1w0 = (const float*)d_in[1];
  const float* m1b0 = (const float*)d_in[2];
  const float* m1w1 = (const float*)d_in[3];
  const float* m1b1 = (const float*)d_in[4];
  const float* m2w0 = (const float*)d_in[5];
  const float* m2b0 = (const float*)d_in[6];
  const float* m2w1 = (const float*)d_in[7];
  const float* m2b1 = (const float*)d_in[8];
  const float* m3w0 = (const float*)d_in[9];
  const float* m3b0 = (const float*)d_in[10];
  const float* m3w1 = (const float*)d_in[11];
  const float* m3b1 = (const float*)d_in[12];

  // ws layout (halfs)
  f16* ws16 = (f16*)d_ws;
  f16* W16  = ws16;                       // 880,640
  f16* lfT  = ws16 + 880640;              // [B][N][128]
  f16* xT   = ws16 + 5074944;             // [B][N][128]
  f16* qT   = ws16 + 9269248;             // [B][N][32]
  f16* vbuf = ws16 + 10317824;            // [B][128][N]
  f16* xrT  = ws16 + 14512128;            // [B][N][128] (mlp2 features; never clobbered)
  f16* hT   = ws16 + 18706432;            // [B][N][512] (mlp hidden)
  f16* xrpart = hT;                       // [B*NSEG][N][128] — aliases hT (dead during SA)
  f16* catT = ws16 + 35483648;            // [B][N][384]
  float* fb = (float*)(ws16 + 48066560);
  float* ralpha = fb;                     // [B,N] (folded rmax+log(rsum))
  float* gc     = fb + 67584;             // [B,128]
  float* part   = fb + 69632;             // [B,1024,16]
  float* cspart = fb + 593920;            // [B*NSEG][N] = 65536 floats
  float* gmax8  = fb + 659456;            // [B][8][128] = 16384 floats

  const dim3 blk(256);

  k_wconv<<<dim3((WTOT+255)/256), blk, 0, stream>>>(
      m1w1, m2w0, m2w1, m3w0, m3w1,
      (const float*)d_in[13], (const float*)d_in[14], (const float*)d_in[16],
      (const float*)d_in[20], (const float*)d_in[21], (const float*)d_in[23],
      (const float*)d_in[27], (const float*)d_in[28], (const float*)d_in[30],
      W16);

  // mlp1
  k_mlp1aT<<<dim3(NBAT*NPT*32/256), blk, 0, stream>>>(in, m1w0, m1b0, hT);
  gemmT<64,false,false><<<dim3(32,2,NBAT), blk, 0, stream>>>(
      W16+OFF_M1W1, m1b1, nullptr, hT, 128, lfT, 128, 0, 128);
  // global max (widened, 128 blocks) + mlp2
  k_gmaxT<<<dim3(NBAT*8), dim3(1024), 0, stream>>>(lfT, gmax8);
  k_gvec<<<dim3(NBAT), dim3(128), 0, stream>>>(m2w0, m2b0, gmax8, gc);
  gemmT<64,true,true><<<dim3(32,2,NBAT), blk, 0, stream>>>(
      W16+OFF_M2W0A, nullptr, gc, lfT, 128, hT, 128, 0, 128);
  gemmT<64,false,false><<<dim3(32,2,NBAT), blk, 0, stream>>>(
      W16+OFF_M2W1, m2b1, nullptr, hT, 128, xrT, 128, 0, 128);   // features -> xrT

  // 3 SA layers (addT, qgemm, pmerge all fused away; folded softmax stats)
  for (int L = 0; L < 3; ++L){
    const float* bv = (const float*)d_in[13 + L*7 + 2];
    const float* bt = (const float*)d_in[13 + L*7 + 4];
    const float* gg = (const float*)d_in[13 + L*7 + 5];
    const float* be = (const float*)d_in[13 + L*7 + 6];
    const f16* wq16 = W16 + OFF_SA + L*SA_STRIDE;
    const f16* wv16 = wq16 + 4096;
    const f16* wt16 = wq16 + 20480;

    const f16* prev = (L==0) ? xrT : (catT + (long)(L-1)*128);
    const int  prs  = (L==0) ? 128 : 384;

    k_vqgemmF<<<dim3(32,2,NBAT), blk, 0, stream>>>(
        wv16, bv, wq16, prev, prs, lfT, vbuf, xT, qT);
    k_rowstats2<<<dim3(32,NBAT), blk, 0, stream>>>(qT, ralpha);
    k_pass2p<<<dim3(32,NSEG,NBAT), blk, 0, stream>>>(qT, vbuf, ralpha, xrpart, cspart);
    k_safin2<<<dim3(32,2,NBAT), blk, 0, stream>>>(
        wt16, bt, gg, be, xT, xrpart, cspart, catT, L*128);
  }

  // mlp3: layer0 (384->512 relu) 128x128 tile, layer1 fused-max 128x128
  gemm128<true><<<dim3(16,4,NBAT), blk, 0, stream>>>(
      W16+OFF_M3W0, m3b0, catT, 384, hT, 512, 384);
  k_gemmax128<<<dim3(16,8,NBAT), blk, 0, stream>>>(W16+OFF_M3W1, m3b1, hT, part);
  k_maxfinal<<<dim3(64), blk, 0, stream>>>(part, (float*)d_out);
}

// Round 21
// 392.316 us; speedup vs baseline: 1.2840x; 1.0402x over previous
//
#include <hip/hip_runtime.h>
#include <hip/hip_bf16.h>
#include <cfloat>

static constexpr int NBAT = 16;
static constexpr int NPT  = 2048;
static constexpr int NSEG = 2;     // pass2 n-split segments
static constexpr int NRS  = 4;     // rowstats m-split segments (r21)

typedef _Float16 f16;
typedef _Float16 f16x8 __attribute__((ext_vector_type(8)));
typedef float    f32x4 __attribute__((ext_vector_type(4)));

static __device__ __forceinline__ f32x4 mfma16(f16x8 a, f16x8 b, f32x4 c){
  return __builtin_amdgcn_mfma_f32_16x16x32_f16(a, b, c, 0, 0, 0);
}
// MFMA 16x16x32 f16 layouts (gfx950, e2e-verified by round-4 pass):
//  A[16r x 32k]: lane l -> row l&15, k = (l>>4)*8 + j (16B contiguous)
//  B[32k x 16c]: lane l -> col l&15, k = (l>>4)*8 + j (16B contiguous)
//  D[16r x 16c]: lane l -> col l&15, rows (l>>4)*4 + i

// ---- weight arena offsets (halfs) ----
static constexpr long OFF_M1W1 = 0;              // [128][128]
static constexpr long OFF_M2W0A= 16384;          // [128][128] (cols 0..127 of [128][256])
static constexpr long OFF_M2W1 = 32768;          // [128][128]
static constexpr long OFF_M3W0 = 49152;          // [512][384]
static constexpr long OFF_M3W1 = 245760;         // [1024][512]
static constexpr long OFF_SA   = 770048;         // per-L: wq[32][128], wv[128][128], wt[128][128]
static constexpr long SA_STRIDE= 36864;
static constexpr long WTOT     = OFF_SA + 3*SA_STRIDE;   // 880,640 halfs

// ---------------------------------------------------------------------------
// weight fp32 -> fp16 conversion into arena (one launch)
// ---------------------------------------------------------------------------
__global__ __launch_bounds__(256) void k_wconv(
    const float* m1w1, const float* m2w0, const float* m2w1,
    const float* m3w0, const float* m3w1,
    const float* wq0, const float* wv0, const float* wt0,
    const float* wq1, const float* wv1, const float* wt1,
    const float* wq2, const float* wv2, const float* wt2,
    f16* W)
{
  long t = (long)blockIdx.x*256 + threadIdx.x;
  if (t >= WTOT) return;
  float v;
  if      (t < OFF_M2W0A) v = m1w1[t];
  else if (t < OFF_M2W1) { long u = t-OFF_M2W0A; v = m2w0[(u>>7)*256 + (u&127)]; }
  else if (t < OFF_M3W0)  v = m2w1[t-OFF_M2W1];
  else if (t < OFF_M3W1)  v = m3w0[t-OFF_M3W0];
  else if (t < OFF_SA)    v = m3w1[t-OFF_M3W1];
  else {
    long u = t - OFF_SA; int L = (int)(u / SA_STRIDE); long r = u % SA_STRIDE;
    const float* wq = (L==0)?wq0:(L==1)?wq1:wq2;
    const float* wv = (L==0)?wv0:(L==1)?wv1:wv2;
    const float* wt = (L==0)?wt0:(L==1)?wt1:wt2;
    if (r < 4096) v = wq[r]; else if (r < 20480) v = wv[r-4096]; else v = wt[r-20480];
  }
  W[t] = (f16)v;
}

// ---------------------------------------------------------------------------
// mlp1 layer0 (K=3): h1T[b][n][o] = relu(b0[o] + sum_c w0[o][c]*in[b][n][c])
// ---------------------------------------------------------------------------
__global__ __launch_bounds__(256) void k_mlp1aT(const float* __restrict__ in,
                                                const float* __restrict__ w0,
                                                const float* __restrict__ b0,
                                                f16* __restrict__ h1T)
{
  long idx = (long)blockIdx.x*256 + threadIdx.x;
  int og = idx & 31; long bn = idx >> 5;
  const float* ip = in + bn*3;
  float x0=ip[0], x1=ip[1], x2=ip[2];
  f16* op = h1T + bn*128 + og*4;
  #pragma unroll
  for (int i=0;i<4;++i){
    int o = og*4+i;
    float v = b0[o] + w0[o*3]*x0 + w0[o*3+1]*x1 + w0[o*3+2]*x2;
    op[i] = (f16)fmaxf(v, 0.f);
  }
}

// ---------------------------------------------------------------------------
// generic transposed conv GEMM: OUTT[b][n][ocol+o] = act(bias + sum_k XT[b][n][k]*W[o][k])
// ---------------------------------------------------------------------------
template<int OT, bool RELU, bool B2D>
__global__ __launch_bounds__(256) void gemmT(
    const f16* __restrict__ W, const float* __restrict__ bias,
    const float* __restrict__ bias2d,
    const f16* __restrict__ XT, int xrs,
    f16* __restrict__ OUT, int ors, int ocol, int K)
{
  __shared__ __align__(16) f16 Xs[64][72];
  __shared__ __align__(16) f16 Wsh[OT][72];
  const int b  = blockIdx.z;
  const int n0 = blockIdx.x * 64;
  const int o0 = blockIdx.y * OT;
  const int tid = threadIdx.x, lane = tid & 63, w = tid >> 6;
  const int lr = lane & 15, lg = lane >> 4;
  constexpr int NSUB = (OT==64)?2:1;
  const int wn = (OT==64)? (w>>1) : w;
  const int wo = (OT==64)? (w&1) : 0;
  const int nbase = wn*(16*NSUB);
  const f16* Xb = XT + (long)b*NPT*xrs;
  f32x4 acc[NSUB][2];
  #pragma unroll
  for (int ni=0;ni<NSUB;++ni){ acc[ni][0]=(f32x4){0,0,0,0}; acc[ni][1]=(f32x4){0,0,0,0}; }

  for (int k0=0; k0<K; k0+=64){
    #pragma unroll
    for (int g = tid; g < 512; g += 256){
      int r = g>>3, s = g&7;
      *(float4*)&Xs[r][s*8] = *(const float4*)(Xb + (long)(n0+r)*xrs + k0 + s*8);
    }
    for (int g = tid; g < OT*8; g += 256){
      int r = g>>3, s = g&7;
      *(float4*)&Wsh[r][s*8] = *(const float4*)(W + (long)(o0+r)*K + k0 + s*8);
    }
    __syncthreads();
    #pragma unroll
    for (int ks=0; ks<2; ++ks){
      f16x8 a[NSUB], bf[2];
      #pragma unroll
      for (int ni=0;ni<NSUB;++ni) a[ni] = *(const f16x8*)&Xs[nbase + ni*16 + lr][ks*32 + lg*8];
      #pragma unroll
      for (int oi=0;oi<2;++oi)   bf[oi] = *(const f16x8*)&Wsh[wo*32 + oi*16 + lr][ks*32 + lg*8];
      #pragma unroll
      for (int ni=0;ni<NSUB;++ni)
        #pragma unroll
        for (int oi=0;oi<2;++oi) acc[ni][oi] = mfma16(a[ni], bf[oi], acc[ni][oi]);
    }
    __syncthreads();
  }
  #pragma unroll
  for (int ni=0;ni<NSUB;++ni)
    #pragma unroll
    for (int oi=0;oi<2;++oi){
      const int oc = o0 + wo*32 + oi*16 + lr;
      float bi = bias ? bias[oc] : 0.f;
      if constexpr (B2D) bi += bias2d[b*128 + oc];
      #pragma unroll
      for (int i=0;i<4;++i){
        const int nn = n0 + nbase + ni*16 + lg*4 + i;
        float v = acc[ni][oi][i] + bi;
        if constexpr (RELU) v = fmaxf(v, 0.f);
        OUT[(long)b*NPT*ors + (long)nn*ors + ocol + oc] = (f16)v;
      }
    }
}

// ---------------------------------------------------------------------------
// 128x128-tile GEMM (4 waves as 2x2, each wave 64x64, acc[4][4]):
// __launch_bounds__(256,4): cap regs at 128/thread -> 4 blocks/CU.
// ---------------------------------------------------------------------------
template<bool RELU>
__global__ __launch_bounds__(256, 4) void gemm128(
    const f16* __restrict__ W, const float* __restrict__ bias,
    const f16* __restrict__ XT, int xrs,
    f16* __restrict__ OUT, int ors, int K)
{
  __shared__ __align__(16) f16 Xs[128][72];
  __shared__ __align__(16) f16 Wsh[128][72];
  const int b  = blockIdx.z;
  const int n0 = blockIdx.x * 128;
  const int o0 = blockIdx.y * 128;
  const int tid = threadIdx.x, lane = tid & 63, w = tid >> 6;
  const int lr = lane & 15, lg = lane >> 4;
  const int wn = w >> 1, wo = w & 1;
  const f16* Xb = XT + (long)b*NPT*xrs;
  f32x4 acc[4][4];
  #pragma unroll
  for (int ni=0;ni<4;++ni)
    #pragma unroll
    for (int oi=0;oi<4;++oi) acc[ni][oi] = (f32x4){0,0,0,0};

  for (int k0=0; k0<K; k0+=64){
    #pragma unroll
    for (int g = tid; g < 1024; g += 256){
      int r = g>>3, s = g&7;
      *(float4*)&Xs[r][s*8]  = *(const float4*)(Xb + (long)(n0+r)*xrs + k0 + s*8);
      *(float4*)&Wsh[r][s*8] = *(const float4*)(W + (long)(o0+r)*K + k0 + s*8);
    }
    __syncthreads();
    #pragma unroll
    for (int ks=0; ks<2; ++ks){
      f16x8 a[4], bf[4];
      #pragma unroll
      for (int ni=0;ni<4;++ni) a[ni]  = *(const f16x8*)&Xs[wn*64 + ni*16 + lr][ks*32 + lg*8];
      #pragma unroll
      for (int oi=0;oi<4;++oi) bf[oi] = *(const f16x8*)&Wsh[wo*64 + oi*16 + lr][ks*32 + lg*8];
      #pragma unroll
      for (int ni=0;ni<4;++ni)
        #pragma unroll
        for (int oi=0;oi<4;++oi) acc[ni][oi] = mfma16(a[ni], bf[oi], acc[ni][oi]);
    }
    __syncthreads();
  }
  #pragma unroll
  for (int ni=0;ni<4;++ni)
    #pragma unroll
    for (int oi=0;oi<4;++oi){
      const int oc = o0 + wo*64 + oi*16 + lr;
      const float bi = bias[oc];
      #pragma unroll
      for (int i=0;i<4;++i){
        const int nn = n0 + wn*64 + ni*16 + lg*4 + i;
        float v = acc[ni][oi][i] + bi;
        if constexpr (RELU) v = fmaxf(v, 0.f);
        OUT[(long)b*NPT*ors + (long)nn*ors + oc] = (f16)v;
      }
    }
}

// ---------------------------------------------------------------------------
// mlp3 layer1 with fused max, 128x128 tile. grid (16, 8, B). K=512.
// ---------------------------------------------------------------------------
__global__ __launch_bounds__(256, 4) void k_gemmax128(
    const f16* __restrict__ W, const float* __restrict__ bias,
    const f16* __restrict__ XT, float* __restrict__ part)
{
  __shared__ __align__(16) f16 Xs[128][72];
  __shared__ __align__(16) f16 Wsh[128][72];
  __shared__ float red[2][128];
  const int b  = blockIdx.z;
  const int n0 = blockIdx.x * 128;
  const int o0 = blockIdx.y * 128;
  const int tid = threadIdx.x, lane = tid & 63, w = tid >> 6;
  const int lr = lane & 15, lg = lane >> 4;
  const int wn = w >> 1, wo = w & 1;
  const f16* Xb = XT + (long)b*NPT*512;
  f32x4 acc[4][4];
  #pragma unroll
  for (int ni=0;ni<4;++ni)
    #pragma unroll
    for (int oi=0;oi<4;++oi) acc[ni][oi] = (f32x4){0,0,0,0};

  for (int k0=0; k0<512; k0+=64){
    #pragma unroll
    for (int g = tid; g < 1024; g += 256){
      int r = g>>3, s = g&7;
      *(float4*)&Xs[r][s*8]  = *(const float4*)(Xb + (long)(n0+r)*512 + k0 + s*8);
      *(float4*)&Wsh[r][s*8] = *(const float4*)(W + (long)(o0+r)*512 + k0 + s*8);
    }
    __syncthreads();
    #pragma unroll
    for (int ks=0; ks<2; ++ks){
      f16x8 a[4], bf[4];
      #pragma unroll
      for (int ni=0;ni<4;++ni) a[ni]  = *(const f16x8*)&Xs[wn*64 + ni*16 + lr][ks*32 + lg*8];
      #pragma unroll
      for (int oi=0;oi<4;++oi) bf[oi] = *(const f16x8*)&Wsh[wo*64 + oi*16 + lr][ks*32 + lg*8];
      #pragma unroll
      for (int ni=0;ni<4;++ni)
        #pragma unroll
        for (int oi=0;oi<4;++oi) acc[ni][oi] = mfma16(a[ni], bf[oi], acc[ni][oi]);
    }
    __syncthreads();
  }
  #pragma unroll
  for (int oi=0;oi<4;++oi){
    const int oc128 = wo*64 + oi*16 + lr;
    const float bi = bias[o0 + oc128];
    float mv = -1e30f;
    #pragma unroll
    for (int ni=0;ni<4;++ni)
      #pragma unroll
      for (int i=0;i<4;++i) mv = fmaxf(mv, acc[ni][oi][i] + bi);
    mv = fmaxf(mv, __shfl_xor(mv, 16, 64));
    mv = fmaxf(mv, __shfl_xor(mv, 32, 64));
    if (lg == 0) red[wn][oc128] = mv;
  }
  __syncthreads();
  if (tid < 128)
    part[((long)b*1024 + o0 + tid)*16 + blockIdx.x] = fmaxf(red[0][tid], red[1][tid]);
}

// ---------------------------------------------------------------------------
// FUSED v+q GEMM: x = prev + lfT computed in staging.
// v16[b][c][n] for all blocks; c0==0 blocks compute qT (o<32, Wq direct from
// global); c0!=0 blocks write staged x to xT. grid (32, 2, B).
// ---------------------------------------------------------------------------
__global__ __launch_bounds__(256) void k_vqgemmF(
    const f16* __restrict__ Wv, const float* __restrict__ bv,
    const f16* __restrict__ Wq,
    const f16* __restrict__ prev, int prs,
    const f16* __restrict__ lfT,
    f16* __restrict__ v16, f16* __restrict__ xT, f16* __restrict__ qT)
{
  __shared__ __align__(16) f16 Xs[64][72];
  __shared__ __align__(16) f16 Wsh[64][72];
  const int b  = blockIdx.z;
  const int n0 = blockIdx.x * 64;
  const int c0 = blockIdx.y * 64;
  const int tid = threadIdx.x, lane = tid & 63, w = tid >> 6;
  const int lr = lane & 15, lg = lane >> 4;
  const int wc = w>>1, wn = w&1;
  f32x4 acc[2][2];
  #pragma unroll
  for (int ci=0;ci<2;++ci){ acc[ci][0]=(f32x4){0,0,0,0}; acc[ci][1]=(f32x4){0,0,0,0}; }
  f32x4 accq[2];
  accq[0] = (f32x4){0,0,0,0}; accq[1] = (f32x4){0,0,0,0};

  for (int k0=0; k0<128; k0+=64){
    #pragma unroll
    for (int g = tid; g < 512; g += 256){
      int r = g>>3, s = g&7;
      const long bn = (long)b*NPT + n0 + r;
      f16x8 xa = *(const f16x8*)(prev + bn*prs + k0 + s*8);
      f16x8 l  = *(const f16x8*)(lfT + bn*128 + k0 + s*8);
      f16x8 xv = xa + l;
      *(f16x8*)&Xs[r][s*8] = xv;
      if (c0 != 0) *(f16x8*)(xT + bn*128 + k0 + s*8) = xv;   // x for safin (balanced half)
      *(float4*)&Wsh[r][s*8] = *(const float4*)(Wv + (long)(c0+r)*128 + k0 + s*8);
    }
    __syncthreads();
    #pragma unroll
    for (int ks=0; ks<2; ++ks){
      f16x8 a[2], bf[2];
      #pragma unroll
      for (int ci=0;ci<2;++ci) a[ci] = *(const f16x8*)&Wsh[wc*32 + ci*16 + lr][ks*32 + lg*8];
      #pragma unroll
      for (int ni=0;ni<2;++ni) bf[ni] = *(const f16x8*)&Xs[wn*32 + ni*16 + lr][ks*32 + lg*8];
      #pragma unroll
      for (int ci=0;ci<2;++ci)
        #pragma unroll
        for (int ni=0;ni<2;++ni) acc[ci][ni] = mfma16(a[ci], bf[ni], acc[ci][ni]);
    }
    if (c0 == 0){
      // q: A = Xs rows n (wave w owns n0+w*16..+15), B = Wq direct from global
      #pragma unroll
      for (int ks=0; ks<2; ++ks){
        f16x8 aq = *(const f16x8*)&Xs[w*16 + lr][ks*32 + lg*8];
        #pragma unroll
        for (int oi=0;oi<2;++oi){
          f16x8 bq = *(const f16x8*)(Wq + (long)(oi*16 + lr)*128 + k0 + ks*32 + lg*8);
          accq[oi] = mfma16(aq, bq, accq[oi]);
        }
      }
    }
    __syncthreads();
  }
  #pragma unroll
  for (int ci=0;ci<2;++ci)
    #pragma unroll
    for (int i=0;i<4;++i){
      const int c = c0 + wc*32 + ci*16 + lg*4 + i;
      const float bi = bv[c];
      #pragma unroll
      for (int ni=0;ni<2;++ni){
        const int n = n0 + wn*32 + ni*16 + lr;
        v16[(long)b*128*NPT + (long)c*NPT + n] = (f16)(acc[ci][ni][i] + bi);
      }
    }
  if (c0 == 0){
    #pragma unroll
    for (int oi=0;oi<2;++oi){
      const int oc = oi*16 + lr;
      #pragma unroll
      for (int i=0;i<4;++i){
        const int nn = n0 + w*16 + lg*4 + i;
        qT[((long)b*NPT + nn)*32 + oc] = (f16)accq[oi][i];
      }
    }
  }
}

// ---------------------------------------------------------------------------
// rowstats PARTIAL (r21: m-split 4-way, proven global-partials pattern):
// block (bx, my, b): n-cols n0=bx*64, m in [my*512, my*512+512).
// Writes mxpart/smpart[(b*NRS+my)*NPT + n]. grid (32, NRS, B) = 2048 blocks.
// Loop body + shuffle merge byte-identical to the green rowstats2.
// ---------------------------------------------------------------------------
__global__ __launch_bounds__(256) void k_rowstats2(const f16* __restrict__ qT,
                                                   float* __restrict__ mxpart,
                                                   float* __restrict__ smpart)
{
  const int b = blockIdx.z, my = blockIdx.y, n0 = blockIdx.x*64;
  const int tid = threadIdx.x, lane = tid & 63, w = tid >> 6;
  const int lr = lane & 15, lg = lane >> 4;
  const f16* qb = qT + (long)b*NPT*32;
  const f16x8 bfr = *(const f16x8*)(qb + (long)(n0 + w*16 + lr)*32 + lg*8);
  float mx = -1e30f, sm = 0.f;
  const int mBeg = my*(NPT/NRS), mEnd = mBeg + NPT/NRS;
  for (int m0=mBeg; m0<mEnd; m0+=32){
    f16x8 af0 = *(const f16x8*)(qb + (long)(m0+lr)*32 + lg*8);
    f16x8 af1 = *(const f16x8*)(qb + (long)(m0+16+lr)*32 + lg*8);
    f32x4 e0 = mfma16(af0, bfr, (f32x4){0,0,0,0});
    f32x4 e1 = mfma16(af1, bfr, (f32x4){0,0,0,0});
    float t0 = fmaxf(fmaxf(e0[0],e0[1]), fmaxf(e0[2],e0[3]));
    float t1 = fmaxf(fmaxf(e1[0],e1[1]), fmaxf(e1[2],e1[3]));
    float nm = fmaxf(mx, fmaxf(t0, t1));
    sm *= __expf(mx - nm);
    mx = nm;
    sm += __expf(e0[0]-mx) + __expf(e0[1]-mx) + __expf(e0[2]-mx) + __expf(e0[3]-mx)
        + __expf(e1[0]-mx) + __expf(e1[1]-mx) + __expf(e1[2]-mx) + __expf(e1[3]-mx);
  }
  #pragma unroll
  for (int d=16; d<64; d<<=1){
    float omx = __shfl_xor(mx, d, 64);
    float osm = __shfl_xor(sm, d, 64);
    float nm = fmaxf(mx, omx);
    sm = sm*__expf(mx-nm) + osm*__expf(omx-nm);
    mx = nm;
  }
  if (lane < 16){
    const long row = (long)(b*NRS + my);
    mxpart[row*NPT + n0 + w*16 + lr] = mx;
    smpart[row*NPT + n0 + w*16 + lr] = sm;
  }
}

// ---------------------------------------------------------------------------
// fold NRS rowstats partials -> ralpha[b][n] = gm + log(gs). 32768 threads.
// ---------------------------------------------------------------------------
__global__ __launch_bounds__(256) void k_rsfold(const float* __restrict__ mxpart,
                                                const float* __restrict__ smpart,
                                                float* __restrict__ ralpha)
{
  const long idx = (long)blockIdx.x*256 + threadIdx.x;  // 0..B*NPT-1
  const long b = idx >> 11, n = idx & 2047;
  const long r0 = (b*NRS)*NPT + n;
  float gm = mxpart[r0];
  #pragma unroll
  for (int s=1;s<NRS;++s) gm = fmaxf(gm, mxpart[r0 + (long)s*NPT]);
  float gs = 0.f;
  #pragma unroll
  for (int s=0;s<NRS;++s) gs += smpart[r0 + (long)s*NPT] * __expf(mxpart[r0 + (long)s*NPT] - gm);
  ralpha[idx] = gm + __logf(gs);
}

// ---------------------------------------------------------------------------
// pass2 PARTIAL [proven kernel: 64-m blocks, 2-deep pipelined V staging,
// one barrier/tile, ones-MFMA colsum, folded stats]. NSEG=2. grid (32,NSEG,B).
// ---------------------------------------------------------------------------
__global__ __launch_bounds__(256) void k_pass2p(const f16* __restrict__ qT,
                                                const f16* __restrict__ v16,
                                                const float* __restrict__ ralpha,
                                                f16* __restrict__ xrpart,
                                                float* __restrict__ cspart)
{
  __shared__ __align__(16) f16 ps[64][40];      // pT[m][n-tile]; rows wave-private
  __shared__ __align__(16) f16 vs[2][128][40];  // double-buffered v-tile [c][n-tile]
  const int b = blockIdx.z, seg = blockIdx.y, m0 = blockIdx.x*64;
  const int tid = threadIdx.x, lane = tid & 63, w = tid >> 6;
  const int lr = lane & 15, lg = lane >> 4;
  const f16* qb = qT + (long)b*NPT*32;
  const f16* vb = v16 + (long)b*128*NPT;
  const float* ral = ralpha + (long)b*NPT;
  const f16x8 afe = *(const f16x8*)(qb + (long)(m0 + w*16 + lr)*32 + lg*8);  // E A-frag (rows m)
  f16x8 ones;
  #pragma unroll
  for (int j=0;j<8;++j) ones[j] = (f16)1.0f;
  f32x4 acc[8];
  #pragma unroll
  for (int cg=0; cg<8; ++cg) acc[cg] = (f32x4){0,0,0,0};
  f32x4 acc_cs = (f32x4){0,0,0,0};

  const int ntBeg = seg*(NPT/NSEG), ntEnd = ntBeg + NPT/NSEG;
  // prologue: stage first tile into vs[0]
  #pragma unroll
  for (int g = tid; g < 512; g += 256){
    int c = g>>2, s = g&3;
    *(float4*)&vs[0][c][s*8] = *(const float4*)(vb + (long)c*NPT + ntBeg + s*8);
  }
  __syncthreads();
  int cur = 0;

  for (int nt=ntBeg; nt<ntEnd; nt+=32){
    // issue next tile's staging into vs[cur^1] (loads fly under E+PV compute)
    if (nt + 32 < ntEnd){
      #pragma unroll
      for (int g = tid; g < 512; g += 256){
        int c = g>>2, s = g&3;
        *(float4*)&vs[cur^1][c][s*8] = *(const float4*)(vb + (long)c*NPT + nt + 32 + s*8);
      }
    }
    // E phase: 2 col-groups; lane col n fixed, 4 m-rows (ps wave-private)
    #pragma unroll
    for (int ng=0; ng<2; ++ng){
      f16x8 bfe = *(const f16x8*)(qb + (long)(nt + ng*16 + lr)*32 + lg*8);
      f32x4 e = mfma16(afe, bfe, (f32x4){0,0,0,0});
      const float ra = ral[nt + ng*16 + lr];
      #pragma unroll
      for (int i=0;i<4;++i){
        float p = __expf(e[i] - ra);
        ps[w*16 + lg*4 + i][ng*16 + lr] = (f16)p;
      }
    }
    // PV phase: A = pT rows m (wave-private), B = current v-tile
    f16x8 ap = *(const f16x8*)&ps[w*16 + lr][lg*8];
    #pragma unroll
    for (int cg=0; cg<8; ++cg){
      f16x8 bp = *(const f16x8*)&vs[cur][cg*16 + lr][lg*8];
      acc[cg] = mfma16(ap, bp, acc[cg]);
    }
    acc_cs = mfma16(ap, ones, acc_cs);   // colsum on matrix pipe
    __syncthreads();                      // drains staging; protects vs[cur] reuse
    cur ^= 1;
  }
  const long row = (long)(b*NSEG + seg);
  // acc_cs[i] = cs[m0 + w*16 + lg*4 + i], duplicated across lr
  if (lr == 0){
    #pragma unroll
    for (int i=0;i<4;++i)
      cspart[row*NPT + m0 + w*16 + lg*4 + i] = acc_cs[i];
  }
  // raw partial store (no renorm)
  f16* xb = xrpart + row*NPT*128;
  #pragma unroll
  for (int cg=0; cg<8; ++cg)
    #pragma unroll
    for (int i=0;i<4;++i)
      xb[(long)(m0 + w*16 + lg*4 + i)*128 + cg*16 + lr] = (f16)acc[cg][i];
}

// ---------------------------------------------------------------------------
// gmax over n per (b,c): widened grid (B*8) blocks of 1024; block h covers
// n in [h*256,(h+1)*256); partials to gmax8[b][h][c].
// ---------------------------------------------------------------------------
__global__ __launch_bounds__(1024) void k_gmaxT(const f16* __restrict__ lfT,
                                                float* __restrict__ gmax8)
{
  __shared__ float red[8][128];
  const int b = blockIdx.x >> 3, h = blockIdx.x & 7;
  const int c = threadIdx.x & 127, r = threadIdx.x >> 7;   // r: 0..7
  const f16* p = lfT + (long)b*NPT*128;
  float m = -1e30f;
  for (int n = h*256 + r; n < (h+1)*256; n += 8) m = fmaxf(m, (float)p[(long)n*128 + c]);
  red[r][c] = m; __syncthreads();
  if (threadIdx.x < 128){
    float mm = red[0][c];
    #pragma unroll
    for (int j=1;j<8;++j) mm = fmaxf(mm, red[j][c]);
    gmax8[((long)b*8 + h)*128 + c] = mm;
  }
}

// gc[b][o] = b0[o] + sum_c w0[o][128+c]*gmax[b][c]; gmax folded from 8 partials
__global__ __launch_bounds__(128) void k_gvec(const float* __restrict__ w0,
                                              const float* __restrict__ b0,
                                              const float* __restrict__ gmax8,
                                              float* __restrict__ gc)
{
  const int b = blockIdx.x, o = threadIdx.x;
  __shared__ float g[128];
  float mm = gmax8[((long)b*8 + 0)*128 + o];
  #pragma unroll
  for (int h=1;h<8;++h) mm = fmaxf(mm, gmax8[((long)b*8 + h)*128 + o]);
  g[o] = mm; __syncthreads();
  float acc = b0[o];
  for (int c = 0; c < 128; ++c) acc = fmaf(w0[o*256 + 128 + c], g[c], acc);
  gc[b*128+o] = acc;
}

// ---------------------------------------------------------------------------
// SA epilogue GEMM with FUSED partial merge (NSEG=2):
// xr[n][c] = (p0+p1)*inv computed inline from xrpart/cspart.
// cat[b][n][Lcol+o] = x[n][o] + relu(g'*(wt@(x-xr))+..). grid (32,2,B).
// ---------------------------------------------------------------------------
__global__ __launch_bounds__(256) void k_safin2(
    const f16* __restrict__ Wt, const float* __restrict__ bt,
    const float* __restrict__ g, const float* __restrict__ be,
    const f16* __restrict__ xT,
    const f16* __restrict__ xrpart, const float* __restrict__ cspart,
    f16* __restrict__ cat, int Lcol)
{
  __shared__ __align__(16) f16 Xs[64][72];
  __shared__ __align__(16) f16 Wsh[64][72];
  const int b  = blockIdx.z;
  const int n0 = blockIdx.x * 64;
  const int o0 = blockIdx.y * 64;
  const int tid = threadIdx.x, lane = tid & 63, w = tid >> 6;
  const int lr = lane & 15, lg = lane >> 4;
  const int wn = w>>1, wo = w&1;
  const f16* xb = xT + (long)b*NPT*128;
  f32x4 acc[2][2];
  #pragma unroll
  for (int ni=0;ni<2;++ni){ acc[ni][0]=(f32x4){0,0,0,0}; acc[ni][1]=(f32x4){0,0,0,0}; }

  for (int k0=0; k0<128; k0+=64){
    #pragma unroll
    for (int gidx = tid; gidx < 512; gidx += 256){
      int r = gidx>>3, s = gidx&7;
      const long nn = n0 + r;
      const long r0 = ((long)b*NSEG + 0)*NPT + nn;
      const long r1 = r0 + NPT;
      const float inv = 1.f/(1e-9f + cspart[r0] + cspart[r1]);
      f16x8 xa = *(const f16x8*)(xb + nn*128 + k0 + s*8);
      f16x8 p0 = *(const f16x8*)(xrpart + r0*128 + k0 + s*8);
      f16x8 p1 = *(const f16x8*)(xrpart + r1*128 + k0 + s*8);
      f16x8 xs;
      #pragma unroll
      for (int j=0;j<8;++j)
        xs[j] = (f16)((float)xa[j] - ((float)p0[j] + (float)p1[j]) * inv);
      *(f16x8*)&Xs[r][s*8] = xs;
      *(float4*)&Wsh[r][s*8] = *(const float4*)(Wt + (long)(o0+r)*128 + k0 + s*8);
    }
    __syncthreads();
    #pragma unroll
    for (int ks=0; ks<2; ++ks){
      f16x8 a[2], bf[2];
      #pragma unroll
      for (int ni=0;ni<2;++ni) a[ni] = *(const f16x8*)&Xs[wn*32 + ni*16 + lr][ks*32 + lg*8];
      #pragma unroll
      for (int oi=0;oi<2;++oi) bf[oi] = *(const f16x8*)&Wsh[wo*32 + oi*16 + lr][ks*32 + lg*8];
      #pragma unroll
      for (int ni=0;ni<2;++ni)
        #pragma unroll
        for (int oi=0;oi<2;++oi) acc[ni][oi] = mfma16(a[ni], bf[oi], acc[ni][oi]);
    }
    __syncthreads();
  }
  const float bnsc = rsqrtf(1.f + 1e-5f);
  #pragma unroll
  for (int ni=0;ni<2;++ni)
    #pragma unroll
    for (int oi=0;oi<2;++oi){
      const int oc = o0 + wo*32 + oi*16 + lr;
      const float bti = bt[oc], gi = g[oc]*bnsc, bei = be[oc];
      #pragma unroll
      for (int i=0;i<4;++i){
        const int nn = n0 + wn*32 + ni*16 + lg*4 + i;
        float t = acc[ni][oi][i] + bti;
        float val = fmaxf(fmaf(gi, t, bei), 0.f);
        float res = (float)xb[(long)nn*128 + oc];
        cat[(long)b*NPT*384 + (long)nn*384 + Lcol + oc] = (f16)(res + val);
      }
    }
}

__global__ __launch_bounds__(256) void k_maxfinal(const float* __restrict__ part,
                                                  float* __restrict__ out)
{
  const int t = blockIdx.x*256 + threadIdx.x;   // 0..16383
  float m = -1e30f;
  #pragma unroll
  for (int j=0;j<16;++j) m = fmaxf(m, part[(long)t*16 + j]);
  out[t] = m;
}

// ---------------------------------------------------------------------------
extern "C" void kernel_launch(void* const* d_in, const int* in_sizes, int n_in,
                              void* d_out, int out_size, void* d_ws, size_t ws_size,
                              hipStream_t stream)
{
  const float* in   = (const float*)d_in[0];
  const float* m1w0 = (const float*)d_in[1];
  const float* m1b0 = (const float*)d_in[2];
  const float* m1w1 = (const float*)d_in[3];
  const float* m1b1 = (const float*)d_in[4];
  const float* m2w0 = (const float*)d_in[5];
  const float* m2b0 = (const float*)d_in[6];
  const float* m2w1 = (const float*)d_in[7];
  const float* m2b1 = (const float*)d_in[8];
  const float* m3w0 = (const float*)d_in[9];
  const float* m3b0 = (const float*)d_in[10];
  const float* m3w1 = (const float*)d_in[11];
  const float* m3b1 = (const float*)d_in[12];

  // ws layout (halfs)
  f16* ws16 = (f16*)d_ws;
  f16* W16  = ws16;                       // 880,640
  f16* lfT  = ws16 + 880640;              // [B][N][128]
  f16* xT   = ws16 + 5074944;             // [B][N][128]
  f16* qT   = ws16 + 9269248;             // [B][N][32]
  f16* vbuf = ws16 + 10317824;            // [B][128][N]
  f16* xrT  = ws16 + 14512128;            // [B][N][128] (mlp2 features; never clobbered)
  f16* hT   = ws16 + 18706432;            // [B][N][512] (mlp hidden)
  f16* xrpart = hT;                       // [B*NSEG][N][128] — aliases hT (dead during SA)
  f16* catT = ws16 + 35483648;            // [B][N][384]
  float* fb = (float*)(ws16 + 48066560);
  float* ralpha = fb;                     // [B,N] (folded rmax+log(rsum))
  float* gc     = fb + 67584;             // [B,128]
  float* part   = fb + 69632;             // [B,1024,16]
  float* cspart = fb + 593920;            // [B*NSEG][N] = 65536 floats
  float* gmax8  = fb + 659456;            // [B][8][128] = 16384 floats
  float* mxpart = fb + 675840;            // [B*NRS][N] = 131072 floats
  float* smpart = fb + 806912;            // [B*NRS][N] = 131072 floats

  const dim3 blk(256);

  k_wconv<<<dim3((WTOT+255)/256), blk, 0, stream>>>(
      m1w1, m2w0, m2w1, m3w0, m3w1,
      (const float*)d_in[13], (const float*)d_in[14], (const float*)d_in[16],
      (const float*)d_in[20], (const float*)d_in[21], (const float*)d_in[23],
      (const float*)d_in[27], (const float*)d_in[28], (const float*)d_in[30],
      W16);

  // mlp1
  k_mlp1aT<<<dim3(NBAT*NPT*32/256), blk, 0, stream>>>(in, m1w0, m1b0, hT);
  gemmT<64,false,false><<<dim3(32,2,NBAT), blk, 0, stream>>>(
      W16+OFF_M1W1, m1b1, nullptr, hT, 128, lfT, 128, 0, 128);
  // global max (widened) + mlp2
  k_gmaxT<<<dim3(NBAT*8), dim3(1024), 0, stream>>>(lfT, gmax8);
  k_gvec<<<dim3(NBAT), dim3(128), 0, stream>>>(m2w0, m2b0, gmax8, gc);
  gemmT<64,true,true><<<dim3(32,2,NBAT), blk, 0, stream>>>(
      W16+OFF_M2W0A, nullptr, gc, lfT, 128, hT, 128, 0, 128);
  gemmT<64,false,false><<<dim3(32,2,NBAT), blk, 0, stream>>>(
      W16+OFF_M2W1, m2b1, nullptr, hT, 128, xrT, 128, 0, 128);   // features -> xrT

  // 3 SA layers (addT, qgemm, pmerge fused away; rowstats m-split 4-way)
  for (int L = 0; L < 3; ++L){
    const float* bv = (const float*)d_in[13 + L*7 + 2];
    const float* bt = (const float*)d_in[13 + L*7 + 4];
    const float* gg = (const float*)d_in[13 + L*7 + 5];
    const float* be = (const float*)d_in[13 + L*7 + 6];
    const f16* wq16 = W16 + OFF_SA + L*SA_STRIDE;
    const f16* wv16 = wq16 + 4096;
    const f16* wt16 = wq16 + 20480;

    const f16* prev = (L==0) ? xrT : (catT + (long)(L-1)*128);
    const int  prs  = (L==0) ? 128 : 384;

    k_vqgemmF<<<dim3(32,2,NBAT), blk, 0, stream>>>(
        wv16, bv, wq16, prev, prs, lfT, vbuf, xT, qT);
    k_rowstats2<<<dim3(32,NRS,NBAT), blk, 0, stream>>>(qT, mxpart, smpart);
    k_rsfold<<<dim3(NBAT*NPT/256), blk, 0, stream>>>(mxpart, smpart, ralpha);
    k_pass2p<<<dim3(32,NSEG,NBAT), blk, 0, stream>>>(qT, vbuf, ralpha, xrpart, cspart);
    k_safin2<<<dim3(32,2,NBAT), blk, 0, stream>>>(
        wt16, bt, gg, be, xT, xrpart, cspart, catT, L*128);
  }

  // mlp3: layer0 (384->512 relu) 128x128 tile, layer1 fused-max 128x128
  gemm128<true><<<dim3(16,4,NBAT), blk, 0, stream>>>(
      W16+OFF_M3W0, m3b0, catT, 384, hT, 512, 384);
  k_gemmax128<<<dim3(16,8,NBAT), blk, 0, stream>>>(W16+OFF_M3W1, m3b1, hT, part);
  k_maxfinal<<<dim3(64), blk, 0, stream>>>(part, (float*)d_out);
}

// Round 22
// 386.296 us; speedup vs baseline: 1.3041x; 1.0156x over previous
//
#include <hip/hip_runtime.h>
#include <hip/hip_bf16.h>
#include <cfloat>

static constexpr int NBAT = 16;
static constexpr int NPT  = 2048;
static constexpr int NSEG = 2;     // pass2 n-split segments
static constexpr int NRS  = 4;     // rowstats m-split segments

typedef _Float16 f16;
typedef _Float16 f16x8 __attribute__((ext_vector_type(8)));
typedef float    f32x4 __attribute__((ext_vector_type(4)));

static __device__ __forceinline__ f32x4 mfma16(f16x8 a, f16x8 b, f32x4 c){
  return __builtin_amdgcn_mfma_f32_16x16x32_f16(a, b, c, 0, 0, 0);
}
// MFMA 16x16x32 f16 layouts (gfx950, e2e-verified by round-4 pass):
//  A[16r x 32k]: lane l -> row l&15, k = (l>>4)*8 + j (16B contiguous)
//  B[32k x 16c]: lane l -> col l&15, k = (l>>4)*8 + j (16B contiguous)
//  D[16r x 16c]: lane l -> col l&15, rows (l>>4)*4 + i

// ---- weight arena offsets (halfs) ----
static constexpr long OFF_M1W1 = 0;              // [128][128]
static constexpr long OFF_M2W0A= 16384;          // [128][128] (cols 0..127 of [128][256])
static constexpr long OFF_M2W1 = 32768;          // [128][128]
static constexpr long OFF_M3W0 = 49152;          // [512][384]
static constexpr long OFF_M3W1 = 245760;         // [1024][512]
static constexpr long OFF_SA   = 770048;         // per-L: wq[32][128], wv[128][128], wt[128][128]
static constexpr long SA_STRIDE= 36864;
static constexpr long WTOT     = OFF_SA + 3*SA_STRIDE;   // 880,640 halfs

// ---------------------------------------------------------------------------
// weight fp32 -> fp16 conversion into arena (one launch)
// ---------------------------------------------------------------------------
__global__ __launch_bounds__(256) void k_wconv(
    const float* m1w1, const float* m2w0, const float* m2w1,
    const float* m3w0, const float* m3w1,
    const float* wq0, const float* wv0, const float* wt0,
    const float* wq1, const float* wv1, const float* wt1,
    const float* wq2, const float* wv2, const float* wt2,
    f16* W)
{
  long t = (long)blockIdx.x*256 + threadIdx.x;
  if (t >= WTOT) return;
  float v;
  if      (t < OFF_M2W0A) v = m1w1[t];
  else if (t < OFF_M2W1) { long u = t-OFF_M2W0A; v = m2w0[(u>>7)*256 + (u&127)]; }
  else if (t < OFF_M3W0)  v = m2w1[t-OFF_M2W1];
  else if (t < OFF_M3W1)  v = m3w0[t-OFF_M3W0];
  else if (t < OFF_SA)    v = m3w1[t-OFF_M3W1];
  else {
    long u = t - OFF_SA; int L = (int)(u / SA_STRIDE); long r = u % SA_STRIDE;
    const float* wq = (L==0)?wq0:(L==1)?wq1:wq2;
    const float* wv = (L==0)?wv0:(L==1)?wv1:wv2;
    const float* wt = (L==0)?wt0:(L==1)?wt1:wt2;
    if (r < 4096) v = wq[r]; else if (r < 20480) v = wv[r-4096]; else v = wt[r-20480];
  }
  W[t] = (f16)v;
}

// ---------------------------------------------------------------------------
// FUSED mlp1 (r22): h1 tile computed in LDS (K=3 pointwise), then l1 GEMM.
// lfT[b][n][o] = b1[o] + sum_k W1[o][k] * relu(b0[k] + w0[k]@in[n])
// grid (32, B), block 256. Bit-identical to old k_mlp1aT->gemmT path.
// ---------------------------------------------------------------------------
__global__ __launch_bounds__(256) void k_mlp1f(
    const float* __restrict__ in, const float* __restrict__ w0,
    const float* __restrict__ b0,
    const f16* __restrict__ W1, const float* __restrict__ b1,
    f16* __restrict__ lfT)
{
  __shared__ __align__(16) f16 Hs[64][136];   // hidden tile, full K=128
  __shared__ __align__(16) f16 Wsh[64][72];
  const int b = blockIdx.y, n0 = blockIdx.x*64;
  const int tid = threadIdx.x, lane = tid & 63, w = tid >> 6;
  const int lr = lane & 15, lg = lane >> 4;
  const int wn = w>>1, wo = w&1;
  // stage-A: h1 = relu(b0 + w0 @ in) into Hs
  for (int e = tid; e < 64*128; e += 256){
    int r = e >> 7, o = e & 127;
    const float* ip = in + ((long)b*NPT + n0 + r)*3;
    float v = b0[o] + w0[o*3]*ip[0] + w0[o*3+1]*ip[1] + w0[o*3+2]*ip[2];
    Hs[r][o] = (f16)fmaxf(v, 0.f);
  }
  __syncthreads();
  f32x4 acc[2][2][2];   // [oh][ni][oi]
  #pragma unroll
  for (int oh=0;oh<2;++oh)
    #pragma unroll
    for (int ni=0;ni<2;++ni)
      #pragma unroll
      for (int oi=0;oi<2;++oi) acc[oh][ni][oi] = (f32x4){0,0,0,0};

  #pragma unroll
  for (int k0=0;k0<128;k0+=64){
    #pragma unroll
    for (int oh=0;oh<2;++oh){
      for (int g=tid; g<512; g+=256){
        int r=g>>3, s=g&7;
        *(float4*)&Wsh[r][s*8] = *(const float4*)(W1 + (long)(oh*64+r)*128 + k0 + s*8);
      }
      __syncthreads();
      #pragma unroll
      for (int ks=0;ks<2;++ks){
        f16x8 a[2], bf[2];
        #pragma unroll
        for (int ni=0;ni<2;++ni) a[ni] = *(const f16x8*)&Hs[wn*32+ni*16+lr][k0+ks*32+lg*8];
        #pragma unroll
        for (int oi=0;oi<2;++oi) bf[oi] = *(const f16x8*)&Wsh[wo*32+oi*16+lr][ks*32+lg*8];
        #pragma unroll
        for (int ni=0;ni<2;++ni)
          #pragma unroll
          for (int oi=0;oi<2;++oi) acc[oh][ni][oi] = mfma16(a[ni], bf[oi], acc[oh][ni][oi]);
      }
      __syncthreads();
    }
  }
  #pragma unroll
  for (int oh=0;oh<2;++oh)
    #pragma unroll
    for (int ni=0;ni<2;++ni)
      #pragma unroll
      for (int oi=0;oi<2;++oi){
        const int oc = oh*64 + wo*32 + oi*16 + lr;
        const float bi = b1[oc];
        #pragma unroll
        for (int i=0;i<4;++i){
          const int nn = n0 + wn*32 + ni*16 + lg*4 + i;
          lfT[((long)b*NPT + nn)*128 + oc] = (f16)(acc[oh][ni][oi][i] + bi);
        }
      }
}

// ---------------------------------------------------------------------------
// FUSED mlp2 (r22): GEMM0 (lfT -> h, relu, gc bias) into LDS, then GEMM1.
// featT[b][n][o] = b1[o] + sum_k W1[o][k] * relu(gc[b][k] + W0[k]@lf[n])
// grid (32, B), block 256. Bit-identical to old gemmT->gemmT path.
// ---------------------------------------------------------------------------
__global__ __launch_bounds__(256) void k_mlp2f(
    const f16* __restrict__ W0, const float* __restrict__ gc,
    const f16* __restrict__ W1, const float* __restrict__ b1,
    const f16* __restrict__ lfT, f16* __restrict__ featT)
{
  __shared__ __align__(16) f16 Xs[64][72];
  __shared__ __align__(16) f16 Hs[64][136];
  __shared__ __align__(16) f16 Wsh[64][72];
  const int b = blockIdx.y, n0 = blockIdx.x*64;
  const int tid = threadIdx.x, lane = tid & 63, w = tid >> 6;
  const int lr = lane & 15, lg = lane >> 4;
  const int wn = w>>1, wo = w&1;
  const f16* Xb = lfT + (long)b*NPT*128;
  f32x4 acc[2][2][2];   // [oh][ni][oi]
  #pragma unroll
  for (int oh=0;oh<2;++oh)
    #pragma unroll
    for (int ni=0;ni<2;++ni)
      #pragma unroll
      for (int oi=0;oi<2;++oi) acc[oh][ni][oi] = (f32x4){0,0,0,0};

  // GEMM0: h = relu(gc + W0 @ lf)
  #pragma unroll
  for (int k0=0;k0<128;k0+=64){
    for (int g=tid; g<512; g+=256){
      int r=g>>3, s=g&7;
      *(float4*)&Xs[r][s*8] = *(const float4*)(Xb + (long)(n0+r)*128 + k0 + s*8);
    }
    #pragma unroll
    for (int oh=0;oh<2;++oh){
      for (int g=tid; g<512; g+=256){
        int r=g>>3, s=g&7;
        *(float4*)&Wsh[r][s*8] = *(const float4*)(W0 + (long)(oh*64+r)*128 + k0 + s*8);
      }
      __syncthreads();
      #pragma unroll
      for (int ks=0;ks<2;++ks){
        f16x8 a[2], bf[2];
        #pragma unroll
        for (int ni=0;ni<2;++ni) a[ni] = *(const f16x8*)&Xs[wn*32+ni*16+lr][ks*32+lg*8];
        #pragma unroll
        for (int oi=0;oi<2;++oi) bf[oi] = *(const f16x8*)&Wsh[wo*32+oi*16+lr][ks*32+lg*8];
        #pragma unroll
        for (int ni=0;ni<2;++ni)
          #pragma unroll
          for (int oi=0;oi<2;++oi) acc[oh][ni][oi] = mfma16(a[ni], bf[oi], acc[oh][ni][oi]);
      }
      __syncthreads();
    }
  }
  // h -> Hs (relu + gc bias), f16 (same rounding as old HBM round-trip)
  #pragma unroll
  for (int oh=0;oh<2;++oh)
    #pragma unroll
    for (int ni=0;ni<2;++ni)
      #pragma unroll
      for (int oi=0;oi<2;++oi){
        const int oc = oh*64 + wo*32 + oi*16 + lr;
        const float bi = gc[b*128 + oc];
        #pragma unroll
        for (int i=0;i<4;++i){
          const int rl = wn*32 + ni*16 + lg*4 + i;
          Hs[rl][oc] = (f16)fmaxf(acc[oh][ni][oi][i] + bi, 0.f);
        }
      }
  __syncthreads();

  // GEMM1: feat = b1 + W1 @ h (A from Hs, full K=128)
  #pragma unroll
  for (int oh=0;oh<2;++oh)
    #pragma unroll
    for (int ni=0;ni<2;++ni)
      #pragma unroll
      for (int oi=0;oi<2;++oi) acc[oh][ni][oi] = (f32x4){0,0,0,0};
  #pragma unroll
  for (int k0=0;k0<128;k0+=64){
    #pragma unroll
    for (int oh=0;oh<2;++oh){
      for (int g=tid; g<512; g+=256){
        int r=g>>3, s=g&7;
        *(float4*)&Wsh[r][s*8] = *(const float4*)(W1 + (long)(oh*64+r)*128 + k0 + s*8);
      }
      __syncthreads();
      #pragma unroll
      for (int ks=0;ks<2;++ks){
        f16x8 a[2], bf[2];
        #pragma unroll
        for (int ni=0;ni<2;++ni) a[ni] = *(const f16x8*)&Hs[wn*32+ni*16+lr][k0+ks*32+lg*8];
        #pragma unroll
        for (int oi=0;oi<2;++oi) bf[oi] = *(const f16x8*)&Wsh[wo*32+oi*16+lr][ks*32+lg*8];
        #pragma unroll
        for (int ni=0;ni<2;++ni)
          #pragma unroll
          for (int oi=0;oi<2;++oi) acc[oh][ni][oi] = mfma16(a[ni], bf[oi], acc[oh][ni][oi]);
      }
      __syncthreads();
    }
  }
  #pragma unroll
  for (int oh=0;oh<2;++oh)
    #pragma unroll
    for (int ni=0;ni<2;++ni)
      #pragma unroll
      for (int oi=0;oi<2;++oi){
        const int oc = oh*64 + wo*32 + oi*16 + lr;
        const float bi = b1[oc];
        #pragma unroll
        for (int i=0;i<4;++i){
          const int nn = n0 + wn*32 + ni*16 + lg*4 + i;
          featT[((long)b*NPT + nn)*128 + oc] = (f16)(acc[oh][ni][oi][i] + bi);
        }
      }
}

// ---------------------------------------------------------------------------
// 128x128-tile GEMM (4 waves as 2x2, each wave 64x64, acc[4][4]):
// __launch_bounds__(256,4): cap regs at 128/thread -> 4 blocks/CU.
// ---------------------------------------------------------------------------
template<bool RELU>
__global__ __launch_bounds__(256, 4) void gemm128(
    const f16* __restrict__ W, const float* __restrict__ bias,
    const f16* __restrict__ XT, int xrs,
    f16* __restrict__ OUT, int ors, int K)
{
  __shared__ __align__(16) f16 Xs[128][72];
  __shared__ __align__(16) f16 Wsh[128][72];
  const int b  = blockIdx.z;
  const int n0 = blockIdx.x * 128;
  const int o0 = blockIdx.y * 128;
  const int tid = threadIdx.x, lane = tid & 63, w = tid >> 6;
  const int lr = lane & 15, lg = lane >> 4;
  const int wn = w >> 1, wo = w & 1;
  const f16* Xb = XT + (long)b*NPT*xrs;
  f32x4 acc[4][4];
  #pragma unroll
  for (int ni=0;ni<4;++ni)
    #pragma unroll
    for (int oi=0;oi<4;++oi) acc[ni][oi] = (f32x4){0,0,0,0};

  for (int k0=0; k0<K; k0+=64){
    #pragma unroll
    for (int g = tid; g < 1024; g += 256){
      int r = g>>3, s = g&7;
      *(float4*)&Xs[r][s*8]  = *(const float4*)(Xb + (long)(n0+r)*xrs + k0 + s*8);
      *(float4*)&Wsh[r][s*8] = *(const float4*)(W + (long)(o0+r)*K + k0 + s*8);
    }
    __syncthreads();
    #pragma unroll
    for (int ks=0; ks<2; ++ks){
      f16x8 a[4], bf[4];
      #pragma unroll
      for (int ni=0;ni<4;++ni) a[ni]  = *(const f16x8*)&Xs[wn*64 + ni*16 + lr][ks*32 + lg*8];
      #pragma unroll
      for (int oi=0;oi<4;++oi) bf[oi] = *(const f16x8*)&Wsh[wo*64 + oi*16 + lr][ks*32 + lg*8];
      #pragma unroll
      for (int ni=0;ni<4;++ni)
        #pragma unroll
        for (int oi=0;oi<4;++oi) acc[ni][oi] = mfma16(a[ni], bf[oi], acc[ni][oi]);
    }
    __syncthreads();
  }
  #pragma unroll
  for (int ni=0;ni<4;++ni)
    #pragma unroll
    for (int oi=0;oi<4;++oi){
      const int oc = o0 + wo*64 + oi*16 + lr;
      const float bi = bias[oc];
      #pragma unroll
      for (int i=0;i<4;++i){
        const int nn = n0 + wn*64 + ni*16 + lg*4 + i;
        float v = acc[ni][oi][i] + bi;
        if constexpr (RELU) v = fmaxf(v, 0.f);
        OUT[(long)b*NPT*ors + (long)nn*ors + oc] = (f16)v;
      }
    }
}

// ---------------------------------------------------------------------------
// mlp3 layer1 with fused max, 128x128 tile. grid (16, 8, B). K=512.
// ---------------------------------------------------------------------------
__global__ __launch_bounds__(256, 4) void k_gemmax128(
    const f16* __restrict__ W, const float* __restrict__ bias,
    const f16* __restrict__ XT, float* __restrict__ part)
{
  __shared__ __align__(16) f16 Xs[128][72];
  __shared__ __align__(16) f16 Wsh[128][72];
  __shared__ float red[2][128];
  const int b  = blockIdx.z;
  const int n0 = blockIdx.x * 128;
  const int o0 = blockIdx.y * 128;
  const int tid = threadIdx.x, lane = tid & 63, w = tid >> 6;
  const int lr = lane & 15, lg = lane >> 4;
  const int wn = w >> 1, wo = w & 1;
  const f16* Xb = XT + (long)b*NPT*512;
  f32x4 acc[4][4];
  #pragma unroll
  for (int ni=0;ni<4;++ni)
    #pragma unroll
    for (int oi=0;oi<4;++oi) acc[ni][oi] = (f32x4){0,0,0,0};

  for (int k0=0; k0<512; k0+=64){
    #pragma unroll
    for (int g = tid; g < 1024; g += 256){
      int r = g>>3, s = g&7;
      *(float4*)&Xs[r][s*8]  = *(const float4*)(Xb + (long)(n0+r)*512 + k0 + s*8);
      *(float4*)&Wsh[r][s*8] = *(const float4*)(W + (long)(o0+r)*512 + k0 + s*8);
    }
    __syncthreads();
    #pragma unroll
    for (int ks=0; ks<2; ++ks){
      f16x8 a[4], bf[4];
      #pragma unroll
      for (int ni=0;ni<4;++ni) a[ni]  = *(const f16x8*)&Xs[wn*64 + ni*16 + lr][ks*32 + lg*8];
      #pragma unroll
      for (int oi=0;oi<4;++oi) bf[oi] = *(const f16x8*)&Wsh[wo*64 + oi*16 + lr][ks*32 + lg*8];
      #pragma unroll
      for (int ni=0;ni<4;++ni)
        #pragma unroll
        for (int oi=0;oi<4;++oi) acc[ni][oi] = mfma16(a[ni], bf[oi], acc[ni][oi]);
    }
    __syncthreads();
  }
  #pragma unroll
  for (int oi=0;oi<4;++oi){
    const int oc128 = wo*64 + oi*16 + lr;
    const float bi = bias[o0 + oc128];
    float mv = -1e30f;
    #pragma unroll
    for (int ni=0;ni<4;++ni)
      #pragma unroll
      for (int i=0;i<4;++i) mv = fmaxf(mv, acc[ni][oi][i] + bi);
    mv = fmaxf(mv, __shfl_xor(mv, 16, 64));
    mv = fmaxf(mv, __shfl_xor(mv, 32, 64));
    if (lg == 0) red[wn][oc128] = mv;
  }
  __syncthreads();
  if (tid < 128)
    part[((long)b*1024 + o0 + tid)*16 + blockIdx.x] = fmaxf(red[0][tid], red[1][tid]);
}

// ---------------------------------------------------------------------------
// FUSED v+q GEMM: x = prev + lfT computed in staging.
// v16[b][c][n] for all blocks; c0==0 blocks compute qT (o<32, Wq direct from
// global); c0!=0 blocks write staged x to xT. grid (32, 2, B).
// ---------------------------------------------------------------------------
__global__ __launch_bounds__(256) void k_vqgemmF(
    const f16* __restrict__ Wv, const float* __restrict__ bv,
    const f16* __restrict__ Wq,
    const f16* __restrict__ prev, int prs,
    const f16* __restrict__ lfT,
    f16* __restrict__ v16, f16* __restrict__ xT, f16* __restrict__ qT)
{
  __shared__ __align__(16) f16 Xs[64][72];
  __shared__ __align__(16) f16 Wsh[64][72];
  const int b  = blockIdx.z;
  const int n0 = blockIdx.x * 64;
  const int c0 = blockIdx.y * 64;
  const int tid = threadIdx.x, lane = tid & 63, w = tid >> 6;
  const int lr = lane & 15, lg = lane >> 4;
  const int wc = w>>1, wn = w&1;
  f32x4 acc[2][2];
  #pragma unroll
  for (int ci=0;ci<2;++ci){ acc[ci][0]=(f32x4){0,0,0,0}; acc[ci][1]=(f32x4){0,0,0,0}; }
  f32x4 accq[2];
  accq[0] = (f32x4){0,0,0,0}; accq[1] = (f32x4){0,0,0,0};

  for (int k0=0; k0<128; k0+=64){
    #pragma unroll
    for (int g = tid; g < 512; g += 256){
      int r = g>>3, s = g&7;
      const long bn = (long)b*NPT + n0 + r;
      f16x8 xa = *(const f16x8*)(prev + bn*prs + k0 + s*8);
      f16x8 l  = *(const f16x8*)(lfT + bn*128 + k0 + s*8);
      f16x8 xv = xa + l;
      *(f16x8*)&Xs[r][s*8] = xv;
      if (c0 != 0) *(f16x8*)(xT + bn*128 + k0 + s*8) = xv;   // x for safin (balanced half)
      *(float4*)&Wsh[r][s*8] = *(const float4*)(Wv + (long)(c0+r)*128 + k0 + s*8);
    }
    __syncthreads();
    #pragma unroll
    for (int ks=0; ks<2; ++ks){
      f16x8 a[2], bf[2];
      #pragma unroll
      for (int ci=0;ci<2;++ci) a[ci] = *(const f16x8*)&Wsh[wc*32 + ci*16 + lr][ks*32 + lg*8];
      #pragma unroll
      for (int ni=0;ni<2;++ni) bf[ni] = *(const f16x8*)&Xs[wn*32 + ni*16 + lr][ks*32 + lg*8];
      #pragma unroll
      for (int ci=0;ci<2;++ci)
        #pragma unroll
        for (int ni=0;ni<2;++ni) acc[ci][ni] = mfma16(a[ci], bf[ni], acc[ci][ni]);
    }
    if (c0 == 0){
      // q: A = Xs rows n (wave w owns n0+w*16..+15), B = Wq direct from global
      #pragma unroll
      for (int ks=0; ks<2; ++ks){
        f16x8 aq = *(const f16x8*)&Xs[w*16 + lr][ks*32 + lg*8];
        #pragma unroll
        for (int oi=0;oi<2;++oi){
          f16x8 bq = *(const f16x8*)(Wq + (long)(oi*16 + lr)*128 + k0 + ks*32 + lg*8);
          accq[oi] = mfma16(aq, bq, accq[oi]);
        }
      }
    }
    __syncthreads();
  }
  #pragma unroll
  for (int ci=0;ci<2;++ci)
    #pragma unroll
    for (int i=0;i<4;++i){
      const int c = c0 + wc*32 + ci*16 + lg*4 + i;
      const float bi = bv[c];
      #pragma unroll
      for (int ni=0;ni<2;++ni){
        const int n = n0 + wn*32 + ni*16 + lr;
        v16[(long)b*128*NPT + (long)c*NPT + n] = (f16)(acc[ci][ni][i] + bi);
      }
    }
  if (c0 == 0){
    #pragma unroll
    for (int oi=0;oi<2;++oi){
      const int oc = oi*16 + lr;
      #pragma unroll
      for (int i=0;i<4;++i){
        const int nn = n0 + w*16 + lg*4 + i;
        qT[((long)b*NPT + nn)*32 + oc] = (f16)accq[oi][i];
      }
    }
  }
}

// ---------------------------------------------------------------------------
// rowstats PARTIAL (m-split 4-way): block (bx, my, b): n-cols n0=bx*64,
// m in [my*512, my*512+512). grid (32, NRS, B) = 2048 blocks.
// ---------------------------------------------------------------------------
__global__ __launch_bounds__(256) void k_rowstats2(const f16* __restrict__ qT,
                                                   float* __restrict__ mxpart,
                                                   float* __restrict__ smpart)
{
  const int b = blockIdx.z, my = blockIdx.y, n0 = blockIdx.x*64;
  const int tid = threadIdx.x, lane = tid & 63, w = tid >> 6;
  const int lr = lane & 15, lg = lane >> 4;
  const f16* qb = qT + (long)b*NPT*32;
  const f16x8 bfr = *(const f16x8*)(qb + (long)(n0 + w*16 + lr)*32 + lg*8);
  float mx = -1e30f, sm = 0.f;
  const int mBeg = my*(NPT/NRS), mEnd = mBeg + NPT/NRS;
  for (int m0=mBeg; m0<mEnd; m0+=32){
    f16x8 af0 = *(const f16x8*)(qb + (long)(m0+lr)*32 + lg*8);
    f16x8 af1 = *(const f16x8*)(qb + (long)(m0+16+lr)*32 + lg*8);
    f32x4 e0 = mfma16(af0, bfr, (f32x4){0,0,0,0});
    f32x4 e1 = mfma16(af1, bfr, (f32x4){0,0,0,0});
    float t0 = fmaxf(fmaxf(e0[0],e0[1]), fmaxf(e0[2],e0[3]));
    float t1 = fmaxf(fmaxf(e1[0],e1[1]), fmaxf(e1[2],e1[3]));
    float nm = fmaxf(mx, fmaxf(t0, t1));
    sm *= __expf(mx - nm);
    mx = nm;
    sm += __expf(e0[0]-mx) + __expf(e0[1]-mx) + __expf(e0[2]-mx) + __expf(e0[3]-mx)
        + __expf(e1[0]-mx) + __expf(e1[1]-mx) + __expf(e1[2]-mx) + __expf(e1[3]-mx);
  }
  #pragma unroll
  for (int d=16; d<64; d<<=1){
    float omx = __shfl_xor(mx, d, 64);
    float osm = __shfl_xor(sm, d, 64);
    float nm = fmaxf(mx, omx);
    sm = sm*__expf(mx-nm) + osm*__expf(omx-nm);
    mx = nm;
  }
  if (lane < 16){
    const long row = (long)(b*NRS + my);
    mxpart[row*NPT + n0 + w*16 + lr] = mx;
    smpart[row*NPT + n0 + w*16 + lr] = sm;
  }
}

// ---------------------------------------------------------------------------
// fold NRS rowstats partials -> ralpha[b][n] = gm + log(gs). 32768 threads.
// ---------------------------------------------------------------------------
__global__ __launch_bounds__(256) void k_rsfold(const float* __restrict__ mxpart,
                                                const float* __restrict__ smpart,
                                                float* __restrict__ ralpha)
{
  const long idx = (long)blockIdx.x*256 + threadIdx.x;  // 0..B*NPT-1
  const long b = idx >> 11, n = idx & 2047;
  const long r0 = (b*NRS)*NPT + n;
  float gm = mxpart[r0];
  #pragma unroll
  for (int s=1;s<NRS;++s) gm = fmaxf(gm, mxpart[r0 + (long)s*NPT]);
  float gs = 0.f;
  #pragma unroll
  for (int s=0;s<NRS;++s) gs += smpart[r0 + (long)s*NPT] * __expf(mxpart[r0 + (long)s*NPT] - gm);
  ralpha[idx] = gm + __logf(gs);
}

// ---------------------------------------------------------------------------
// pass2 PARTIAL [proven kernel: 64-m blocks, 2-deep pipelined V staging,
// one barrier/tile, ones-MFMA colsum, folded stats]. NSEG=2. grid (32,NSEG,B).
// ---------------------------------------------------------------------------
__global__ __launch_bounds__(256) void k_pass2p(const f16* __restrict__ qT,
                                                const f16* __restrict__ v16,
                                                const float* __restrict__ ralpha,
                                                f16* __restrict__ xrpart,
                                                float* __restrict__ cspart)
{
  __shared__ __align__(16) f16 ps[64][40];      // pT[m][n-tile]; rows wave-private
  __shared__ __align__(16) f16 vs[2][128][40];  // double-buffered v-tile [c][n-tile]
  const int b = blockIdx.z, seg = blockIdx.y, m0 = blockIdx.x*64;
  const int tid = threadIdx.x, lane = tid & 63, w = tid >> 6;
  const int lr = lane & 15, lg = lane >> 4;
  const f16* qb = qT + (long)b*NPT*32;
  const f16* vb = v16 + (long)b*128*NPT;
  const float* ral = ralpha + (long)b*NPT;
  const f16x8 afe = *(const f16x8*)(qb + (long)(m0 + w*16 + lr)*32 + lg*8);  // E A-frag (rows m)
  f16x8 ones;
  #pragma unroll
  for (int j=0;j<8;++j) ones[j] = (f16)1.0f;
  f32x4 acc[8];
  #pragma unroll
  for (int cg=0; cg<8; ++cg) acc[cg] = (f32x4){0,0,0,0};
  f32x4 acc_cs = (f32x4){0,0,0,0};

  const int ntBeg = seg*(NPT/NSEG), ntEnd = ntBeg + NPT/NSEG;
  // prologue: stage first tile into vs[0]
  #pragma unroll
  for (int g = tid; g < 512; g += 256){
    int c = g>>2, s = g&3;
    *(float4*)&vs[0][c][s*8] = *(const float4*)(vb + (long)c*NPT + ntBeg + s*8);
  }
  __syncthreads();
  int cur = 0;

  for (int nt=ntBeg; nt<ntEnd; nt+=32){
    // issue next tile's staging into vs[cur^1] (loads fly under E+PV compute)
    if (nt + 32 < ntEnd){
      #pragma unroll
      for (int g = tid; g < 512; g += 256){
        int c = g>>2, s = g&3;
        *(float4*)&vs[cur^1][c][s*8] = *(const float4*)(vb + (long)c*NPT + nt + 32 + s*8);
      }
    }
    // E phase: 2 col-groups; lane col n fixed, 4 m-rows (ps wave-private)
    #pragma unroll
    for (int ng=0; ng<2; ++ng){
      f16x8 bfe = *(const f16x8*)(qb + (long)(nt + ng*16 + lr)*32 + lg*8);
      f32x4 e = mfma16(afe, bfe, (f32x4){0,0,0,0});
      const float ra = ral[nt + ng*16 + lr];
      #pragma unroll
      for (int i=0;i<4;++i){
        float p = __expf(e[i] - ra);
        ps[w*16 + lg*4 + i][ng*16 + lr] = (f16)p;
      }
    }
    // PV phase: A = pT rows m (wave-private), B = current v-tile
    f16x8 ap = *(const f16x8*)&ps[w*16 + lr][lg*8];
    #pragma unroll
    for (int cg=0; cg<8; ++cg){
      f16x8 bp = *(const f16x8*)&vs[cur][cg*16 + lr][lg*8];
      acc[cg] = mfma16(ap, bp, acc[cg]);
    }
    acc_cs = mfma16(ap, ones, acc_cs);   // colsum on matrix pipe
    __syncthreads();                      // drains staging; protects vs[cur] reuse
    cur ^= 1;
  }
  const long row = (long)(b*NSEG + seg);
  // acc_cs[i] = cs[m0 + w*16 + lg*4 + i], duplicated across lr
  if (lr == 0){
    #pragma unroll
    for (int i=0;i<4;++i)
      cspart[row*NPT + m0 + w*16 + lg*4 + i] = acc_cs[i];
  }
  // raw partial store (no renorm)
  f16* xb = xrpart + row*NPT*128;
  #pragma unroll
  for (int cg=0; cg<8; ++cg)
    #pragma unroll
    for (int i=0;i<4;++i)
      xb[(long)(m0 + w*16 + lg*4 + i)*128 + cg*16 + lr] = (f16)acc[cg][i];
}

// ---------------------------------------------------------------------------
// gmax over n per (b,c): widened grid (B*8) blocks of 1024; block h covers
// n in [h*256,(h+1)*256); partials to gmax8[b][h][c].
// ---------------------------------------------------------------------------
__global__ __launch_bounds__(1024) void k_gmaxT(const f16* __restrict__ lfT,
                                                float* __restrict__ gmax8)
{
  __shared__ float red[8][128];
  const int b = blockIdx.x >> 3, h = blockIdx.x & 7;
  const int c = threadIdx.x & 127, r = threadIdx.x >> 7;   // r: 0..7
  const f16* p = lfT + (long)b*NPT*128;
  float m = -1e30f;
  for (int n = h*256 + r; n < (h+1)*256; n += 8) m = fmaxf(m, (float)p[(long)n*128 + c]);
  red[r][c] = m; __syncthreads();
  if (threadIdx.x < 128){
    float mm = red[0][c];
    #pragma unroll
    for (int j=1;j<8;++j) mm = fmaxf(mm, red[j][c]);
    gmax8[((long)b*8 + h)*128 + c] = mm;
  }
}

// gc[b][o] = b0[o] + sum_c w0[o][128+c]*gmax[b][c]; gmax folded from 8 partials
__global__ __launch_bounds__(128) void k_gvec(const float* __restrict__ w0,
                                              const float* __restrict__ b0,
                                              const float* __restrict__ gmax8,
                                              float* __restrict__ gc)
{
  const int b = blockIdx.x, o = threadIdx.x;
  __shared__ float g[128];
  float mm = gmax8[((long)b*8 + 0)*128 + o];
  #pragma unroll
  for (int h=1;h<8;++h) mm = fmaxf(mm, gmax8[((long)b*8 + h)*128 + o]);
  g[o] = mm; __syncthreads();
  float acc = b0[o];
  for (int c = 0; c < 128; ++c) acc = fmaf(w0[o*256 + 128 + c], g[c], acc);
  gc[b*128+o] = acc;
}

// ---------------------------------------------------------------------------
// SA epilogue GEMM with FUSED partial merge (NSEG=2):
// xr[n][c] = (p0+p1)*inv computed inline from xrpart/cspart.
// cat[b][n][Lcol+o] = x[n][o] + relu(g'*(wt@(x-xr))+..). grid (32,2,B).
// ---------------------------------------------------------------------------
__global__ __launch_bounds__(256) void k_safin2(
    const f16* __restrict__ Wt, const float* __restrict__ bt,
    const float* __restrict__ g, const float* __restrict__ be,
    const f16* __restrict__ xT,
    const f16* __restrict__ xrpart, const float* __restrict__ cspart,
    f16* __restrict__ cat, int Lcol)
{
  __shared__ __align__(16) f16 Xs[64][72];
  __shared__ __align__(16) f16 Wsh[64][72];
  const int b  = blockIdx.z;
  const int n0 = blockIdx.x * 64;
  const int o0 = blockIdx.y * 64;
  const int tid = threadIdx.x, lane = tid & 63, w = tid >> 6;
  const int lr = lane & 15, lg = lane >> 4;
  const int wn = w>>1, wo = w&1;
  const f16* xb = xT + (long)b*NPT*128;
  f32x4 acc[2][2];
  #pragma unroll
  for (int ni=0;ni<2;++ni){ acc[ni][0]=(f32x4){0,0,0,0}; acc[ni][1]=(f32x4){0,0,0,0}; }

  for (int k0=0; k0<128; k0+=64){
    #pragma unroll
    for (int gidx = tid; gidx < 512; gidx += 256){
      int r = gidx>>3, s = gidx&7;
      const long nn = n0 + r;
      const long r0 = ((long)b*NSEG + 0)*NPT + nn;
      const long r1 = r0 + NPT;
      const float inv = 1.f/(1e-9f + cspart[r0] + cspart[r1]);
      f16x8 xa = *(const f16x8*)(xb + nn*128 + k0 + s*8);
      f16x8 p0 = *(const f16x8*)(xrpart + r0*128 + k0 + s*8);
      f16x8 p1 = *(const f16x8*)(xrpart + r1*128 + k0 + s*8);
      f16x8 xs;
      #pragma unroll
      for (int j=0;j<8;++j)
        xs[j] = (f16)((float)xa[j] - ((float)p0[j] + (float)p1[j]) * inv);
      *(f16x8*)&Xs[r][s*8] = xs;
      *(float4*)&Wsh[r][s*8] = *(const float4*)(Wt + (long)(o0+r)*128 + k0 + s*8);
    }
    __syncthreads();
    #pragma unroll
    for (int ks=0; ks<2; ++ks){
      f16x8 a[2], bf[2];
      #pragma unroll
      for (int ni=0;ni<2;++ni) a[ni] = *(const f16x8*)&Xs[wn*32 + ni*16 + lr][ks*32 + lg*8];
      #pragma unroll
      for (int oi=0;oi<2;++oi) bf[oi] = *(const f16x8*)&Wsh[wo*32 + oi*16 + lr][ks*32 + lg*8];
      #pragma unroll
      for (int ni=0;ni<2;++ni)
        #pragma unroll
        for (int oi=0;oi<2;++oi) acc[ni][oi] = mfma16(a[ni], bf[oi], acc[ni][oi]);
    }
    __syncthreads();
  }
  const float bnsc = rsqrtf(1.f + 1e-5f);
  #pragma unroll
  for (int ni=0;ni<2;++ni)
    #pragma unroll
    for (int oi=0;oi<2;++oi){
      const int oc = o0 + wo*32 + oi*16 + lr;
      const float bti = bt[oc], gi = g[oc]*bnsc, bei = be[oc];
      #pragma unroll
      for (int i=0;i<4;++i){
        const int nn = n0 + wn*32 + ni*16 + lg*4 + i;
        float t = acc[ni][oi][i] + bti;
        float val = fmaxf(fmaf(gi, t, bei), 0.f);
        float res = (float)xb[(long)nn*128 + oc];
        cat[(long)b*NPT*384 + (long)nn*384 + Lcol + oc] = (f16)(res + val);
      }
    }
}

__global__ __launch_bounds__(256) void k_maxfinal(const float* __restrict__ part,
                                                  float* __restrict__ out)
{
  const int t = blockIdx.x*256 + threadIdx.x;   // 0..16383
  float m = -1e30f;
  #pragma unroll
  for (int j=0;j<16;++j) m = fmaxf(m, part[(long)t*16 + j]);
  out[t] = m;
}

// ---------------------------------------------------------------------------
extern "C" void kernel_launch(void* const* d_in, const int* in_sizes, int n_in,
                              void* d_out, int out_size, void* d_ws, size_t ws_size,
                              hipStream_t stream)
{
  const float* in   = (const float*)d_in[0];
  const float* m1w0 = (const float*)d_in[1];
  const float* m1b0 = (const float*)d_in[2];
  const float* m1w1 = (const float*)d_in[3];
  const float* m1b1 = (const float*)d_in[4];
  const float* m2w0 = (const float*)d_in[5];
  const float* m2b0 = (const float*)d_in[6];
  const float* m2w1 = (const float*)d_in[7];
  const float* m2b1 = (const float*)d_in[8];
  const float* m3w0 = (const float*)d_in[9];
  const float* m3b0 = (const float*)d_in[10];
  const float* m3w1 = (const float*)d_in[11];
  const float* m3b1 = (const float*)d_in[12];

  // ws layout (halfs)
  f16* ws16 = (f16*)d_ws;
  f16* W16  = ws16;                       // 880,640
  f16* lfT  = ws16 + 880640;              // [B][N][128]
  f16* xT   = ws16 + 5074944;             // [B][N][128]
  f16* qT   = ws16 + 9269248;             // [B][N][32]
  f16* vbuf = ws16 + 10317824;            // [B][128][N]
  f16* xrT  = ws16 + 14512128;            // [B][N][128] (mlp2 features)
  f16* hT   = ws16 + 18706432;            // [B][N][512] (mlp3 hidden)
  f16* xrpart = hT;                       // [B*NSEG][N][128] — aliases hT (dead during SA)
  f16* catT = ws16 + 35483648;            // [B][N][384]
  float* fb = (float*)(ws16 + 48066560);
  float* ralpha = fb;                     // [B,N] (folded rmax+log(rsum))
  float* gc     = fb + 67584;             // [B,128]
  float* part   = fb + 69632;             // [B,1024,16]
  float* cspart = fb + 593920;            // [B*NSEG][N]
  float* gmax8  = fb + 659456;            // [B][8][128]
  float* mxpart = fb + 675840;            // [B*NRS][N]
  float* smpart = fb + 806912;            // [B*NRS][N]

  const dim3 blk(256);

  k_wconv<<<dim3((WTOT+255)/256), blk, 0, stream>>>(
      m1w1, m2w0, m2w1, m3w0, m3w1,
      (const float*)d_in[13], (const float*)d_in[14], (const float*)d_in[16],
      (const float*)d_in[20], (const float*)d_in[21], (const float*)d_in[23],
      (const float*)d_in[27], (const float*)d_in[28], (const float*)d_in[30],
      W16);

  // mlp1 (fused l0+l1, r22)
  k_mlp1f<<<dim3(32,NBAT), blk, 0, stream>>>(in, m1w0, m1b0, W16+OFF_M1W1, m1b1, lfT);
  // global max (widened) + mlp2 (fused l0+l1, r22) -> features in xrT
  k_gmaxT<<<dim3(NBAT*8), dim3(1024), 0, stream>>>(lfT, gmax8);
  k_gvec<<<dim3(NBAT), dim3(128), 0, stream>>>(m2w0, m2b0, gmax8, gc);
  k_mlp2f<<<dim3(32,NBAT), blk, 0, stream>>>(
      W16+OFF_M2W0A, gc, W16+OFF_M2W1, m2b1, lfT, xrT);

  // 3 SA layers (addT, qgemm, pmerge fused away; rowstats m-split 4-way)
  for (int L = 0; L < 3; ++L){
    const float* bv = (const float*)d_in[13 + L*7 + 2];
    const float* bt = (const float*)d_in[13 + L*7 + 4];
    const float* gg = (const float*)d_in[13 + L*7 + 5];
    const float* be = (const float*)d_in[13 + L*7 + 6];
    const f16* wq16 = W16 + OFF_SA + L*SA_STRIDE;
    const f16* wv16 = wq16 + 4096;
    const f16* wt16 = wq16 + 20480;

    const f16* prev = (L==0) ? xrT : (catT + (long)(L-1)*128);
    const int  prs  = (L==0) ? 128 : 384;

    k_vqgemmF<<<dim3(32,2,NBAT), blk, 0, stream>>>(
        wv16, bv, wq16, prev, prs, lfT, vbuf, xT, qT);
    k_rowstats2<<<dim3(32,NRS,NBAT), blk, 0, stream>>>(qT, mxpart, smpart);
    k_rsfold<<<dim3(NBAT*NPT/256), blk, 0, stream>>>(mxpart, smpart, ralpha);
    k_pass2p<<<dim3(32,NSEG,NBAT), blk, 0, stream>>>(qT, vbuf, ralpha, xrpart, cspart);
    k_safin2<<<dim3(32,2,NBAT), blk, 0, stream>>>(
        wt16, bt, gg, be, xT, xrpart, cspart, catT, L*128);
  }

  // mlp3: layer0 (384->512 relu) 128x128 tile, layer1 fused-max 128x128
  gemm128<true><<<dim3(16,4,NBAT), blk, 0, stream>>>(
      W16+OFF_M3W0, m3b0, catT, 384, hT, 512, 384);
  k_gemmax128<<<dim3(16,8,NBAT), blk, 0, stream>>>(W16+OFF_M3W1, m3b1, hT, part);
  k_maxfinal<<<dim3(64), blk, 0, stream>>>(part, (float*)d_out);
}